// Round 6
// baseline (990.826 us; speedup 1.0000x reference)
//
#include <hip/hip_runtime.h>
#include <cstdint>
#include <cstddef>

// ---------------- constants ----------------
#define BATCH 8
#define NPTS 2048
#define KNN 20
#define M1 327680   // BATCH*NPTS*KNN
#define M2 16384    // BATCH*NPTS

typedef unsigned short ushort_t;
typedef __attribute__((ext_vector_type(8))) short bf16x8;   // 8 bf16 = 4 VGPRs
typedef __attribute__((ext_vector_type(4))) float f32x4;    // MFMA acc

// ws layout (bytes) — total 145,469,440
#define OFF_XT    0UL          // 196608   float xt[b*n][3]
#define OFF_XX    196608UL     // 65536    float xx[b*n]
#define OFF_IDX   262144UL     // 1310720  int idx[b*n][20]
#define OFF_WH2   1572864UL    // 8192   bf16 [64][64]
#define OFF_WL2   1581056UL    // 8192
#define OFF_WH3   1589248UL    // 16384  bf16 [128][64]
#define OFF_WL3   1605632UL    // 16384
#define OFF_WH4   1622016UL    // 65536  bf16 [256][128]
#define OFF_WL4   1687552UL    // 65536
#define OFF_WH5   1753088UL    // 524288 bf16 [512][512]
#define OFF_WL5   2277376UL    // 524288
#define OFF_STATS 2801664UL    // 40960   5 x (512 sum + 512 sumsq) double
#define OFF_SS    2842624UL    // 20480   5 x (512 scale + 512 shift) float
// REG0: y1 [M1][64] (41.9MB) -> y3 [M1][128] (83.9MB) -> y5 [M2][512] (16.8MB)
#define OFF_REG0  2863104UL    // 83886080
// REG1: y2 [M1][64] (41.9MB) -> rawmax+rawmin [M2][256] f32 (33.5MB) + sp4 (2MB)
#define OFF_REG1  86749184UL   // 41943040
#define OFF_XCAT  128692224UL  // 16777216 xcat[M2][512] bf16
#define WS_NEEDED 145469440UL

// ---------------- helpers ----------------
__device__ __forceinline__ float bf2f(unsigned short u) {
    union { unsigned int i; float f; } c; c.i = ((unsigned int)u) << 16; return c.f;
}
__device__ __forceinline__ unsigned short f2bf(float f) {
    union { float f; unsigned int i; } c; c.f = f;
    unsigned int x = c.i;
    unsigned int r = (x + 0x7fffu + ((x >> 16) & 1u)) >> 16;  // RNE
    return (unsigned short)r;
}
__device__ __forceinline__ unsigned int pack2(float a, float b) {
    return (unsigned int)f2bf(a) | ((unsigned int)f2bf(b) << 16);
}
__device__ __forceinline__ void unpack8(uint4 u, float* v) {
    v[0] = bf2f((unsigned short)(u.x & 0xffffu)); v[1] = bf2f((unsigned short)(u.x >> 16));
    v[2] = bf2f((unsigned short)(u.y & 0xffffu)); v[3] = bf2f((unsigned short)(u.y >> 16));
    v[4] = bf2f((unsigned short)(u.z & 0xffffu)); v[5] = bf2f((unsigned short)(u.z >> 16));
    v[6] = bf2f((unsigned short)(u.w & 0xffffu)); v[7] = bf2f((unsigned short)(u.w >> 16));
}

// ---------------- prep: transpose x, compute xx ----------------
__global__ void prep_k(const float* __restrict__ x, float* __restrict__ xt, float* __restrict__ xx) {
    int t = blockIdx.x * 256 + threadIdx.x;   // 16384
    int b = t >> 11, n = t & 2047;
    float v0 = x[((size_t)b * 3 + 0) * NPTS + n];
    float v1 = x[((size_t)b * 3 + 1) * NPTS + n];
    float v2 = x[((size_t)b * 3 + 2) * NPTS + n];
    xt[(size_t)t * 3 + 0] = v0; xt[(size_t)t * 3 + 1] = v1; xt[(size_t)t * 3 + 2] = v2;
    xx[t] = __fadd_rn(__fadd_rn(__fmul_rn(v0, v0), __fmul_rn(v1, v1)), __fmul_rn(v2, v2));
}

// ---------------- weight split: fp32 -> bf16 hi + bf16 lo ----------------
__global__ void wsplit_k(const float* __restrict__ w, ushort_t* __restrict__ hi,
                         ushort_t* __restrict__ lo, int n) {
    int t = blockIdx.x * 256 + threadIdx.x;
    if (t < n) {
        float f = w[t];
        ushort_t h = f2bf(f);
        hi[t] = h;
        lo[t] = f2bf(f - bf2f(h));
    }
}

// ---------------- knn: wave-per-point top-20 ----------------
__launch_bounds__(256)
__global__ void knn_k(const float* __restrict__ xt, const float* __restrict__ xx, int* __restrict__ idx) {
    int tid = threadIdx.x;
    int l = tid & 63;
    int pid = blockIdx.x * 4 + (tid >> 6);
    int b = pid >> 11;
    const float* xb  = xt + (size_t)b * NPTS * 3;
    const float* xxb = xx + (size_t)b * NPTS;
    int i = pid & 2047;
    float xi0 = xb[i * 3 + 0], xi1 = xb[i * 3 + 1], xi2 = xb[i * 3 + 2];
    float xxi = xxb[i];
    float v[32];
#pragma unroll
    for (int q = 0; q < 32; q++) {
        int j = l + q * 64;
        float dot = __fadd_rn(__fadd_rn(__fmul_rn(xi0, xb[j * 3 + 0]),
                                        __fmul_rn(xi1, xb[j * 3 + 1])),
                              __fmul_rn(xi2, xb[j * 3 + 2]));
        v[q] = __fsub_rn(__fsub_rn(-xxi, __fmul_rn(-2.0f, dot)), xxb[j]);
    }
    int* out = idx + (size_t)pid * KNN;
    for (int t = 0; t < KNN; t++) {
        float bv = -3.0e38f; int bi = 0x7fffffff;
#pragma unroll
        for (int q = 0; q < 32; q++) {
            int j = l + q * 64;
            if (v[q] > bv) { bv = v[q]; bi = j; }
        }
#pragma unroll
        for (int off = 1; off < 64; off <<= 1) {
            float ov = __shfl_xor(bv, off);
            int   oi = __shfl_xor(bi, off);
            if (ov > bv || (ov == bv && oi < bi)) { bv = ov; bi = oi; }
        }
        if (l == 0) out[t] = bi;
        int owner = bi & 63, qw = bi >> 6;
        bool isown = (l == owner);
#pragma unroll
        for (int q = 0; q < 32; q++)
            if (isown && q == qw) v[q] = -3.4e38f;
    }
}

// ---------------- conv1: graph feature (6ch) x w1(64x6) -> y1 NHWC [m][64] bf16 ----------------
__launch_bounds__(256)
__global__ void conv1_k(const float* __restrict__ xt, const int* __restrict__ idx,
                        const float* __restrict__ w1, ushort_t* __restrict__ y1) {
    __shared__ float w[384];
    int tid = threadIdx.x;
    for (int t = tid; t < 384; t += 256) w[t] = w1[t];
    __syncthreads();
    int m = blockIdx.x * 256 + tid;        // < M1; idx flat index == m
    int nb = m / KNN;                      // b*N + n
    int b = nb >> 11;
    int j = idx[m];
    const float* pi = xt + (size_t)nb * 3;
    const float* pj = xt + ((size_t)(b * NPTS + j)) * 3;
    float f0 = pj[0] - pi[0], f1 = pj[1] - pi[1], f2 = pj[2] - pi[2];
    float f3 = pi[0], f4 = pi[1], f5 = pi[2];
#pragma unroll
    for (int o8 = 0; o8 < 8; o8++) {
        uint4 u;
        unsigned int* up = (unsigned int*)&u;
#pragma unroll
        for (int e2 = 0; e2 < 4; e2++) {
            const float* wa = w + (o8 * 8 + e2 * 2) * 6;
            const float* wb = wa + 6;
            float r0 = wa[0]*f0 + wa[1]*f1 + wa[2]*f2 + wa[3]*f3 + wa[4]*f4 + wa[5]*f5;
            float r1 = wb[0]*f0 + wb[1]*f1 + wb[2]*f2 + wb[3]*f3 + wb[4]*f4 + wb[5]*f5;
            up[e2] = pack2(r0, r1);
        }
        *(uint4*)(y1 + (size_t)m * 64 + o8 * 8) = u;
    }
}

// ---------------- generic MFMA conv (layers 2,3,5) ----------------
// yout[m][o] = sum_c act(yin[m][c]) * w[o][c], NHWC. Block: 128m x 64o, 4 waves (32m each).
template<int CIN, int COUT, bool BN>
__launch_bounds__(256)
__global__ void conv_mfma_k(const ushort_t* __restrict__ yin,
                            const ushort_t* __restrict__ whi,
                            const ushort_t* __restrict__ wlo,
                            const float* __restrict__ scale,
                            const float* __restrict__ shift,
                            ushort_t* __restrict__ yout) {
    constexpr int SMEM = 28672 + (BN ? CIN * 8 : 0);
    __shared__ char smem[SMEM];
    ushort_t* hA = (ushort_t*)smem;             // [128][56] bf16 (rows 112B, 16B aligned)
    ushort_t* wH = (ushort_t*)(smem + 14336);   // [64][56]
    ushort_t* wL = (ushort_t*)(smem + 21504);   // [64][56]
    float* scl = (float*)(smem + 28672);
    float* shf = scl + CIN;
    const int tid = threadIdx.x;
    const int m0 = blockIdx.x * 128;
    const int o0 = blockIdx.y * 64;
    if constexpr (BN) {
        for (int c = tid; c < CIN; c += 256) { scl[c] = scale[c]; shf[c] = shift[c]; }
    }
    f32x4 acc[2][4];
#pragma unroll
    for (int mt = 0; mt < 2; mt++)
#pragma unroll
        for (int ot = 0; ot < 4; ot++) acc[mt][ot] = (f32x4){0.f, 0.f, 0.f, 0.f};
    const int lane = tid & 63, wv = tid >> 6;
    const int l15 = lane & 15, quad = lane >> 4;
    for (int kc = 0; kc < CIN; kc += 32) {
        __syncthreads();
        // stage activations: 128 rows x 32c, straight copy (BN applied in f32, re-round bf16)
#pragma unroll
        for (int i = 0; i < 2; i++) {
            int tt = tid + 256 * i;
            int mr = tt >> 2, cq = (tt & 3) * 8;
            uint4 u = *(const uint4*)(yin + (size_t)(m0 + mr) * CIN + kc + cq);
            if constexpr (BN) {
                float vv[8]; unpack8(u, vv);
#pragma unroll
                for (int e = 0; e < 8; e++)
                    vv[e] = fmaxf(fmaf(vv[e], scl[kc + cq + e], shf[kc + cq + e]), 0.0f);
                u.x = pack2(vv[0], vv[1]); u.y = pack2(vv[2], vv[3]);
                u.z = pack2(vv[4], vv[5]); u.w = pack2(vv[6], vv[7]);
            }
            *(uint4*)&hA[mr * 56 + cq] = u;
        }
        // stage weights hi/lo: 64 rows x 32c
        {
            int orow = tid >> 2, cq = (tid & 3) * 8;
            *(uint4*)&wH[orow * 56 + cq] = *(const uint4*)(whi + (size_t)(o0 + orow) * CIN + kc + cq);
            *(uint4*)&wL[orow * 56 + cq] = *(const uint4*)(wlo + (size_t)(o0 + orow) * CIN + kc + cq);
        }
        __syncthreads();
        bf16x8 a0 = *(bf16x8*)&hA[(wv * 32 + l15) * 56 + quad * 8];
        bf16x8 a1 = *(bf16x8*)&hA[(wv * 32 + 16 + l15) * 56 + quad * 8];
#pragma unroll
        for (int ot = 0; ot < 4; ot++) {
            bf16x8 bh = *(bf16x8*)&wH[(ot * 16 + l15) * 56 + quad * 8];
            bf16x8 bl = *(bf16x8*)&wL[(ot * 16 + l15) * 56 + quad * 8];
            acc[0][ot] = __builtin_amdgcn_mfma_f32_16x16x32_bf16(a0, bh, acc[0][ot], 0, 0, 0);
            acc[0][ot] = __builtin_amdgcn_mfma_f32_16x16x32_bf16(a0, bl, acc[0][ot], 0, 0, 0);
            acc[1][ot] = __builtin_amdgcn_mfma_f32_16x16x32_bf16(a1, bh, acc[1][ot], 0, 0, 0);
            acc[1][ot] = __builtin_amdgcn_mfma_f32_16x16x32_bf16(a1, bl, acc[1][ot], 0, 0, 0);
        }
    }
    // epilogue: LDS transpose -> coalesced NHWC stores
    __syncthreads();
    ushort_t* outT = (ushort_t*)smem;   // [128][72] (rows 144B, 16B aligned)
#pragma unroll
    for (int mt = 0; mt < 2; mt++)
#pragma unroll
        for (int ot = 0; ot < 4; ot++)
#pragma unroll
            for (int r = 0; r < 4; r++)
                outT[(wv * 32 + mt * 16 + quad * 4 + r) * 72 + ot * 16 + l15] = f2bf(acc[mt][ot][r]);
    __syncthreads();
    int row = tid >> 1, half = tid & 1;
#pragma unroll
    for (int g = 0; g < 4; g++) {
        uint4 u = *(uint4*)&outT[row * 72 + half * 32 + g * 8];
        *(uint4*)(yout + (size_t)(m0 + row) * COUT + o0 + half * 32 + g * 8) = u;
    }
}

// ---------------- conv4 fused MFMA: 320m (16 k-windows) x 32o, K=128.
// acc[5][2]=40 f32/thread (was 80 -> scratch spill, 1.68GB phantom writes; round 5 lesson).
// Epilogue: per-window raw max/min + per-block stats partials (no global atomics).
__launch_bounds__(256, 2)
__global__ void conv4_mfma_k(const ushort_t* __restrict__ y3,
                             const ushort_t* __restrict__ whi,
                             const ushort_t* __restrict__ wlo,
                             const float* __restrict__ scale,
                             const float* __restrict__ shift,
                             float* __restrict__ rawmax, float* __restrict__ rawmin,
                             float* __restrict__ sp) {
    __shared__ char smem[45056];
    ushort_t* hA = (ushort_t*)smem;             // [320][56] = 35840
    ushort_t* wH = (ushort_t*)(smem + 35840);   // [32][56]  = 3584
    ushort_t* wL = (ushort_t*)(smem + 39424);   // [32][56]  = 3584
    float* scl = (float*)(smem + 43008);        // [128]
    float* shf = (float*)(smem + 43520);        // [128]
    float* sw  = (float*)(smem + 44032);        // [4][32][2] per-wave stat partials
    const int tid = threadIdx.x;
    const int m0 = blockIdx.x * 320;            // 1024 m-tiles
    const int o0 = blockIdx.y * 32;             // 8 o-tiles
    for (int c = tid; c < 128; c += 256) { scl[c] = scale[c]; shf[c] = shift[c]; }
    for (int i = tid; i < 256; i += 256) sw[i] = 0.0f;
    f32x4 acc[5][2];
#pragma unroll
    for (int mt = 0; mt < 5; mt++)
#pragma unroll
        for (int ot = 0; ot < 2; ot++) acc[mt][ot] = (f32x4){0.f, 0.f, 0.f, 0.f};
    const int lane = tid & 63, wv = tid >> 6;
    const int l15 = lane & 15, quad = lane >> 4;
    for (int kc = 0; kc < 128; kc += 32) {
        __syncthreads();
        // stage activations: 320 rows x 32c (BN+ReLU applied)
#pragma unroll
        for (int i = 0; i < 5; i++) {
            int tt = tid + 256 * i;
            int mr = tt >> 2, cq = (tt & 3) * 8;
            uint4 u = *(const uint4*)(y3 + (size_t)(m0 + mr) * 128 + kc + cq);
            float vv[8]; unpack8(u, vv);
#pragma unroll
            for (int e = 0; e < 8; e++)
                vv[e] = fmaxf(fmaf(vv[e], scl[kc + cq + e], shf[kc + cq + e]), 0.0f);
            u.x = pack2(vv[0], vv[1]); u.y = pack2(vv[2], vv[3]);
            u.z = pack2(vv[4], vv[5]); u.w = pack2(vv[6], vv[7]);
            *(uint4*)&hA[mr * 56 + cq] = u;
        }
        // stage weights hi/lo: 32 rows x 32c (128 uint4 each; threads 0-127 hi, 128-255 lo)
        {
            int t = tid & 127, sel = tid >> 7;
            int row = t >> 2, cq = (t & 3) * 8;
            const ushort_t* src = (sel ? wlo : whi) + (size_t)(o0 + row) * 128 + kc + cq;
            ushort_t* dst = (sel ? wL : wH) + row * 56 + cq;
            *(uint4*)dst = *(const uint4*)src;
        }
        __syncthreads();
        bf16x8 a[5];
#pragma unroll
        for (int mt = 0; mt < 5; mt++)
            a[mt] = *(bf16x8*)&hA[(wv * 80 + mt * 16 + l15) * 56 + quad * 8];
#pragma unroll
        for (int ot = 0; ot < 2; ot++) {
            bf16x8 bh = *(bf16x8*)&wH[(ot * 16 + l15) * 56 + quad * 8];
            bf16x8 bl = *(bf16x8*)&wL[(ot * 16 + l15) * 56 + quad * 8];
#pragma unroll
            for (int mt = 0; mt < 5; mt++) {
                acc[mt][ot] = __builtin_amdgcn_mfma_f32_16x16x32_bf16(a[mt], bh, acc[mt][ot], 0, 0, 0);
                acc[mt][ot] = __builtin_amdgcn_mfma_f32_16x16x32_bf16(a[mt], bl, acc[mt][ot], 0, 0, 0);
            }
        }
    }
    __syncthreads();   // waves may still be reading hA/wH/wL; wreg below overlays hA
    // epilogue: per wave, 80m x 16o f32 wave-private scratch, one o-tile at a time
    float* wreg = (float*)(smem + wv * 5440);   // [80][17]
#pragma unroll 1
    for (int ot = 0; ot < 2; ot++) {
#pragma unroll
        for (int mt = 0; mt < 5; mt++)
#pragma unroll
            for (int r = 0; r < 4; r++)
                wreg[(mt * 16 + quad * 4 + r) * 17 + l15] = acc[mt][ot][r];
        // wave-private region: no block barrier needed (compiler inserts lgkm wait)
        {
            int pp = quad;                      // 4 points per wave (80m = 4x20)
            const float* rr = wreg + (pp * 20) * 17 + l15;
            float mx = rr[0], mn = rr[0], sm = 0.0f, ss = 0.0f;
#pragma unroll
            for (int q = 0; q < 20; q++) {
                float v = rr[q * 17];
                mx = fmaxf(mx, v); mn = fminf(mn, v);
                sm += v; ss = fmaf(v, v, ss);
            }
            int pt = blockIdx.x * 16 + wv * 4 + pp;
            int o = o0 + ot * 16 + l15;
            rawmax[(size_t)pt * 256 + o] = mx;
            rawmin[(size_t)pt * 256 + o] = mn;
            sm += __shfl_xor(sm, 16); sm += __shfl_xor(sm, 32);
            ss += __shfl_xor(ss, 16); ss += __shfl_xor(ss, 32);
            if (lane < 16) {
                sw[(wv * 32 + ot * 16 + l15) * 2 + 0] += sm;
                sw[(wv * 32 + ot * 16 + l15) * 2 + 1] += ss;
            }
        }
    }
    __syncthreads();
    if (tid < 64) {
        int ol = tid >> 1, st = tid & 1;
        float v = 0.0f;
#pragma unroll
        for (int w2 = 0; w2 < 4; w2++) v += sw[(w2 * 32 + ol) * 2 + st];
        size_t bid = (size_t)blockIdx.y * 1024 + blockIdx.x;
        sp[bid * 64 + ol * 2 + st] = v;
    }
}

// ---------------- reduce conv4 stat partials -> sum/sumsq doubles ----------------
__launch_bounds__(256)
__global__ void stats4red_k(const float* __restrict__ sp, double* __restrict__ sum,
                            double* __restrict__ sumsq) {
    __shared__ double rs[256], rss[256];
    int o = blockIdx.x, tid = threadIdx.x;
    int oy = o >> 5, ol = o & 31;
    double s = 0.0, ss = 0.0;
    for (int mb = tid; mb < 1024; mb += 256) {
        size_t bid = (size_t)oy * 1024 + mb;
        s  += (double)sp[bid * 64 + ol * 2 + 0];
        ss += (double)sp[bid * 64 + ol * 2 + 1];
    }
    rs[tid] = s; rss[tid] = ss;
    __syncthreads();
    for (int st = 128; st; st >>= 1) {
        if (tid < st) { rs[tid] += rs[tid + st]; rss[tid] += rss[tid + st]; }
        __syncthreads();
    }
    if (tid == 0) { sum[o] = rs[0]; sumsq[o] = rss[0]; }
}

// ---------------- per-channel sum/sumsq over NHWC y ----------------
template<int C8>
__launch_bounds__(256)
__global__ void stats_nhwc_k(const ushort_t* __restrict__ y, double* __restrict__ sum,
                             double* __restrict__ sumsq, int rpb) {
    constexpr int C = C8 * 8;
    constexpr int STRIDE = 256 / C8;
    __shared__ float ls[C][2];
    int tid = threadIdx.x;
    for (int i = tid; i < C * 2; i += 256) ((float*)ls)[i] = 0.0f;
    int cg = tid % C8, mr = tid / C8;
    size_t r0 = (size_t)blockIdx.x * rpb;
    float s[8], ss[8];
#pragma unroll
    for (int e = 0; e < 8; e++) { s[e] = 0.0f; ss[e] = 0.0f; }
    for (int r = mr; r < rpb; r += STRIDE) {
        uint4 u = *(const uint4*)(y + (r0 + r) * C + cg * 8);
        float vv[8]; unpack8(u, vv);
#pragma unroll
        for (int e = 0; e < 8; e++) { s[e] += vv[e]; ss[e] = fmaf(vv[e], vv[e], ss[e]); }
    }
    __syncthreads();
#pragma unroll
    for (int e = 0; e < 8; e++) {
        atomicAdd(&ls[cg * 8 + e][0], s[e]);
        atomicAdd(&ls[cg * 8 + e][1], ss[e]);
    }
    __syncthreads();
    // strided (C can exceed blockDim; round-4 bug)
    for (int c = tid; c < C; c += 256) {
        atomicAdd(&sum[c], (double)ls[c][0]);
        atomicAdd(&sumsq[c], (double)ls[c][1]);
    }
}

// ---------------- finalize BN ----------------
__global__ void fin_k(const double* __restrict__ sum, const double* __restrict__ sumsq,
                      const float* __restrict__ g, const float* __restrict__ bb,
                      float* __restrict__ scale, float* __restrict__ shift, int C, double invcnt) {
    int c = blockIdx.x * blockDim.x + threadIdx.x;
    if (c < C) {
        double m = sum[c] * invcnt;
        double v = sumsq[c] * invcnt - m * m;
        if (v < 0.0) v = 0.0;
        float sc = g[c] / sqrtf((float)v + 1e-5f);
        scale[c] = sc;
        shift[c] = bb[c] - (float)m * sc;
    }
}

// ---------------- maxpool over k (BN+ReLU) NHWC -> xcat (layers 1-3) ----------------
template<int C8>
__launch_bounds__(256)
__global__ void maxpool_nhwc_k(const ushort_t* __restrict__ y, const float* __restrict__ scale,
                               const float* __restrict__ shift, ushort_t* __restrict__ xcat,
                               int coff) {
    constexpr int C = C8 * 8;
    constexpr int PB = 256 / C8;
    int tid = threadIdx.x;
    int cg = tid % C8, pl = tid / C8;
    int p = blockIdx.x * PB + pl;
    float sc[8], sh[8];
    *(float4*)&sc[0] = *(const float4*)(scale + cg * 8);
    *(float4*)&sc[4] = *(const float4*)(scale + cg * 8 + 4);
    *(float4*)&sh[0] = *(const float4*)(shift + cg * 8);
    *(float4*)&sh[4] = *(const float4*)(shift + cg * 8 + 4);
    float mx[8];
#pragma unroll
    for (int e = 0; e < 8; e++) mx[e] = 0.0f;   // relu floor
    size_t base = (size_t)p * KNN * C + cg * 8;
#pragma unroll
    for (int q = 0; q < KNN; q++) {
        uint4 u = *(const uint4*)(y + base + (size_t)q * C);
        float vv[8]; unpack8(u, vv);
#pragma unroll
        for (int e = 0; e < 8; e++) mx[e] = fmaxf(mx[e], fmaf(vv[e], sc[e], sh[e]));
    }
    uint4 u;
    u.x = pack2(mx[0], mx[1]); u.y = pack2(mx[2], mx[3]);
    u.z = pack2(mx[4], mx[5]); u.w = pack2(mx[6], mx[7]);
    *(uint4*)(xcat + (size_t)p * 512 + coff + cg * 8) = u;
}

// ---------------- pool4 finalize: BN of raw max/min + ReLU -> xcat[.][256..512) ----------------
__launch_bounds__(256)
__global__ void pool4_k(const float* __restrict__ rawmax, const float* __restrict__ rawmin,
                        const float* __restrict__ scale, const float* __restrict__ shift,
                        ushort_t* __restrict__ xcat) {
    int gid = blockIdx.x * 256 + threadIdx.x;   // 524288
    int p = gid >> 5, og = gid & 31;
    float sc[8], sh[8], mxv[8], mnv[8];
    *(float4*)&sc[0]  = *(const float4*)(scale + og * 8);
    *(float4*)&sc[4]  = *(const float4*)(scale + og * 8 + 4);
    *(float4*)&sh[0]  = *(const float4*)(shift + og * 8);
    *(float4*)&sh[4]  = *(const float4*)(shift + og * 8 + 4);
    *(float4*)&mxv[0] = *(const float4*)(rawmax + (size_t)p * 256 + og * 8);
    *(float4*)&mxv[4] = *(const float4*)(rawmax + (size_t)p * 256 + og * 8 + 4);
    *(float4*)&mnv[0] = *(const float4*)(rawmin + (size_t)p * 256 + og * 8);
    *(float4*)&mnv[4] = *(const float4*)(rawmin + (size_t)p * 256 + og * 8 + 4);
    float v[8];
#pragma unroll
    for (int e = 0; e < 8; e++) {
        float raw = (sc[e] >= 0.0f) ? mxv[e] : mnv[e];
        v[e] = fmaxf(fmaf(raw, sc[e], sh[e]), 0.0f);
    }
    uint4 u;
    u.x = pack2(v[0], v[1]); u.y = pack2(v[2], v[3]);
    u.z = pack2(v[4], v[5]); u.w = pack2(v[6], v[7]);
    *(uint4*)(xcat + (size_t)p * 512 + 256 + og * 8) = u;
}

// ---------------- output: BN5+ReLU + transpose NHWC -> [b][c][n] fp32 ----------------
__launch_bounds__(256)
__global__ void out_k(const ushort_t* __restrict__ y5, const float* __restrict__ scale,
                      const float* __restrict__ shift, float* __restrict__ out) {
    __shared__ float tr[64 * 65];
    int tid = threadIdx.x;
    int n0 = blockIdx.x * 64, c0 = blockIdx.y * 64, b = blockIdx.z;
    int nl = tid >> 2, cq = (tid & 3) * 16;
    const ushort_t* src = y5 + (size_t)(b * 2048 + n0 + nl) * 512 + c0 + cq;
#pragma unroll
    for (int h = 0; h < 2; h++) {
        uint4 u = *(const uint4*)(src + h * 8);
        float vv[8]; unpack8(u, vv);
#pragma unroll
        for (int e = 0; e < 8; e++) {
            int c = cq + h * 8 + e;
            tr[c * 65 + nl] = fmaxf(fmaf(vv[e], scale[c0 + c], shift[c0 + c]), 0.0f);
        }
    }
    __syncthreads();
    int cl = tid >> 2, ng = (tid & 3) * 16;
#pragma unroll
    for (int g = 0; g < 4; g++) {
        float4 v = *(float4*)&tr[cl * 65 + ng + g * 4];
        *(float4*)(out + ((size_t)b * 512 + c0 + cl) * 2048 + n0 + ng + g * 4) = v;
    }
}

// ---------------- host ----------------
extern "C" void kernel_launch(void* const* d_in, const int* in_sizes, int n_in,
                              void* d_out, int out_size, void* d_ws, size_t ws_size,
                              hipStream_t stream) {
    (void)in_sizes; (void)n_in; (void)out_size;
    if (ws_size < WS_NEEDED) return;
    const float* x  = (const float*)d_in[0];
    const float* w1 = (const float*)d_in[1];
    const float* g1 = (const float*)d_in[2];
    const float* b1 = (const float*)d_in[3];
    const float* w2 = (const float*)d_in[4];
    const float* g2 = (const float*)d_in[5];
    const float* b2 = (const float*)d_in[6];
    const float* w3 = (const float*)d_in[7];
    const float* g3 = (const float*)d_in[8];
    const float* b3 = (const float*)d_in[9];
    const float* w4 = (const float*)d_in[10];
    const float* g4 = (const float*)d_in[11];
    const float* b4 = (const float*)d_in[12];
    const float* w5 = (const float*)d_in[13];
    const float* g5 = (const float*)d_in[14];
    const float* b5 = (const float*)d_in[15];

    char* ws = (char*)d_ws;
    float* xt  = (float*)(ws + OFF_XT);
    float* xx  = (float*)(ws + OFF_XX);
    int*   idx = (int*)(ws + OFF_IDX);
    ushort_t* wh2 = (ushort_t*)(ws + OFF_WH2); ushort_t* wl2 = (ushort_t*)(ws + OFF_WL2);
    ushort_t* wh3 = (ushort_t*)(ws + OFF_WH3); ushort_t* wl3 = (ushort_t*)(ws + OFF_WL3);
    ushort_t* wh4 = (ushort_t*)(ws + OFF_WH4); ushort_t* wl4 = (ushort_t*)(ws + OFF_WL4);
    ushort_t* wh5 = (ushort_t*)(ws + OFF_WH5); ushort_t* wl5 = (ushort_t*)(ws + OFF_WL5);
    ushort_t* y1 = (ushort_t*)(ws + OFF_REG0);
    ushort_t* y2 = (ushort_t*)(ws + OFF_REG1);
    ushort_t* y3 = (ushort_t*)(ws + OFF_REG0);
    float* rawmax = (float*)(ws + OFF_REG1);
    float* rawmin = (float*)(ws + OFF_REG1 + 16777216UL);
    float* sp4    = (float*)(ws + OFF_REG1 + 33554432UL);  // 2 MB partials
    ushort_t* y5 = (ushort_t*)(ws + OFF_REG0);
    ushort_t* xcat = (ushort_t*)(ws + OFF_XCAT);

    double* sum[5]; double* sumsq[5]; float* scl[5]; float* shf[5];
    for (int l = 0; l < 5; l++) {
        sum[l]   = (double*)(ws + OFF_STATS + (size_t)l * 8192);
        sumsq[l] = sum[l] + 512;
        scl[l]   = (float*)(ws + OFF_SS + (size_t)l * 4096);
        shf[l]   = scl[l] + 512;
    }

    hipMemsetAsync(ws + OFF_STATS, 0, 40960, stream);
    prep_k<<<64, 256, 0, stream>>>(x, xt, xx);
    wsplit_k<<<16,   256, 0, stream>>>(w2, wh2, wl2, 4096);
    wsplit_k<<<32,   256, 0, stream>>>(w3, wh3, wl3, 8192);
    wsplit_k<<<128,  256, 0, stream>>>(w4, wh4, wl4, 32768);
    wsplit_k<<<1024, 256, 0, stream>>>(w5, wh5, wl5, 262144);
    knn_k<<<4096, 256, 0, stream>>>(xt, xx, idx);

    // layer 1
    conv1_k<<<1280, 256, 0, stream>>>(xt, idx, w1, y1);
    stats_nhwc_k<8><<<160, 256, 0, stream>>>(y1, sum[0], sumsq[0], 2048);
    fin_k<<<1, 512, 0, stream>>>(sum[0], sumsq[0], g1, b1, scl[0], shf[0], 64, 1.0 / 327680.0);
    maxpool_nhwc_k<8><<<512, 256, 0, stream>>>(y1, scl[0], shf[0], xcat, 0);

    // layer 2: 64 -> 64
    conv_mfma_k<64, 64, true><<<dim3(2560, 1), 256, 0, stream>>>(y1, wh2, wl2, scl[0], shf[0], y2);
    stats_nhwc_k<8><<<160, 256, 0, stream>>>(y2, sum[1], sumsq[1], 2048);
    fin_k<<<1, 512, 0, stream>>>(sum[1], sumsq[1], g2, b2, scl[1], shf[1], 64, 1.0 / 327680.0);
    maxpool_nhwc_k<8><<<512, 256, 0, stream>>>(y2, scl[1], shf[1], xcat, 64);

    // layer 3: 64 -> 128
    conv_mfma_k<64, 128, true><<<dim3(2560, 2), 256, 0, stream>>>(y2, wh3, wl3, scl[1], shf[1], y3);
    stats_nhwc_k<16><<<320, 256, 0, stream>>>(y3, sum[2], sumsq[2], 1024);
    fin_k<<<1, 512, 0, stream>>>(sum[2], sumsq[2], g3, b3, scl[2], shf[2], 128, 1.0 / 327680.0);
    maxpool_nhwc_k<16><<<1024, 256, 0, stream>>>(y3, scl[2], shf[2], xcat, 128);

    // layer 4: 128 -> 256 fused (no y4), partial stats; 320m x 32o tiles
    conv4_mfma_k<<<dim3(1024, 8), 256, 0, stream>>>(y3, wh4, wl4, scl[2], shf[2],
                                                    rawmax, rawmin, sp4);
    stats4red_k<<<256, 256, 0, stream>>>(sp4, sum[3], sumsq[3]);
    fin_k<<<1, 512, 0, stream>>>(sum[3], sumsq[3], g4, b4, scl[3], shf[3], 256, 1.0 / 327680.0);
    pool4_k<<<2048, 256, 0, stream>>>(rawmax, rawmin, scl[3], shf[3], xcat);

    // layer 5: 512 -> 512 (input already activated)
    conv_mfma_k<512, 512, false><<<dim3(128, 8), 256, 0, stream>>>(xcat, wh5, wl5,
                                                                   nullptr, nullptr, y5);
    stats_nhwc_k<64><<<128, 256, 0, stream>>>(y5, sum[4], sumsq[4], 128);
    fin_k<<<1, 512, 0, stream>>>(sum[4], sumsq[4], g5, b5, scl[4], shf[4], 512, 1.0 / 16384.0);
    out_k<<<dim3(32, 8, 8), 256, 0, stream>>>(y5, scl[4], shf[4], (float*)d_out);
}

// Round 8
// 667.175 us; speedup vs baseline: 1.4851x; 1.4851x over previous
//
#include <hip/hip_runtime.h>
#include <cstdint>
#include <cstddef>

// ---------------- constants ----------------
#define BATCH 8
#define NPTS 2048
#define KNN 20
#define M1 327680   // BATCH*NPTS*KNN
#define M2 16384    // BATCH*NPTS

typedef unsigned short ushort_t;
typedef __attribute__((ext_vector_type(8))) short bf16x8;   // 8 bf16 = 4 VGPRs
typedef __attribute__((ext_vector_type(4))) float f32x4;    // MFMA acc

// ws layout (bytes) — total 145,469,440
#define OFF_XT    0UL          // 196608   float xt[b*n][3]
#define OFF_XX    196608UL     // 65536    float xx[b*n]
#define OFF_IDX   262144UL     // 1310720  int idx[b*n][20]
#define OFF_WH2   1572864UL    // 8192   bf16 [64][64]
#define OFF_WL2   1581056UL    // 8192
#define OFF_WH3   1589248UL    // 16384  bf16 [128][64]
#define OFF_WL3   1605632UL    // 16384
#define OFF_WH4   1622016UL    // 65536  bf16 [256][128]
#define OFF_WL4   1687552UL    // 65536
#define OFF_WH5   1753088UL    // 524288 bf16 [512][512]
#define OFF_WL5   2277376UL    // 524288
#define OFF_STATS 2801664UL    // 40960   5 x (512 sum + 512 sumsq) double
#define OFF_SS    2842624UL    // 20480   5 x (512 scale + 512 shift) float
// REG0: y1 [M1][64] (41.9MB) -> y3 [M1][128] (83.9MB) -> y5 [M2][512] (16.8MB)
#define OFF_REG0  2863104UL    // 83886080
// REG1: y2 [M1][64] (41.9MB) -> rawmax+rawmin [M2][256] f32 (33.5MB) + sp4 (2MB)
#define OFF_REG1  86749184UL   // 41943040
#define OFF_XCAT  128692224UL  // 16777216 xcat[M2][512] bf16
#define WS_NEEDED 145469440UL

// ---------------- helpers ----------------
__device__ __forceinline__ float bf2f(unsigned short u) {
    union { unsigned int i; float f; } c; c.i = ((unsigned int)u) << 16; return c.f;
}
__device__ __forceinline__ unsigned short f2bf(float f) {
    union { float f; unsigned int i; } c; c.f = f;
    unsigned int x = c.i;
    unsigned int r = (x + 0x7fffu + ((x >> 16) & 1u)) >> 16;  // RNE
    return (unsigned short)r;
}
__device__ __forceinline__ unsigned int pack2(float a, float b) {
    return (unsigned int)f2bf(a) | ((unsigned int)f2bf(b) << 16);
}
__device__ __forceinline__ void unpack8(uint4 u, float* v) {
    v[0] = bf2f((unsigned short)(u.x & 0xffffu)); v[1] = bf2f((unsigned short)(u.x >> 16));
    v[2] = bf2f((unsigned short)(u.y & 0xffffu)); v[3] = bf2f((unsigned short)(u.y >> 16));
    v[4] = bf2f((unsigned short)(u.z & 0xffffu)); v[5] = bf2f((unsigned short)(u.z >> 16));
    v[6] = bf2f((unsigned short)(u.w & 0xffffu)); v[7] = bf2f((unsigned short)(u.w >> 16));
}

// ---------------- prep: transpose x, compute xx ----------------
__global__ void prep_k(const float* __restrict__ x, float* __restrict__ xt, float* __restrict__ xx) {
    int t = blockIdx.x * 256 + threadIdx.x;   // 16384
    int b = t >> 11, n = t & 2047;
    float v0 = x[((size_t)b * 3 + 0) * NPTS + n];
    float v1 = x[((size_t)b * 3 + 1) * NPTS + n];
    float v2 = x[((size_t)b * 3 + 2) * NPTS + n];
    xt[(size_t)t * 3 + 0] = v0; xt[(size_t)t * 3 + 1] = v1; xt[(size_t)t * 3 + 2] = v2;
    xx[t] = __fadd_rn(__fadd_rn(__fmul_rn(v0, v0), __fmul_rn(v1, v1)), __fmul_rn(v2, v2));
}

// ---------------- weight split: fp32 -> bf16 hi + bf16 lo ----------------
__global__ void wsplit_k(const float* __restrict__ w, ushort_t* __restrict__ hi,
                         ushort_t* __restrict__ lo, int n) {
    int t = blockIdx.x * 256 + threadIdx.x;
    if (t < n) {
        float f = w[t];
        ushort_t h = f2bf(f);
        hi[t] = h;
        lo[t] = f2bf(f - bf2f(h));
    }
}

// ---------------- knn: wave-per-point top-20 ----------------
__launch_bounds__(256)
__global__ void knn_k(const float* __restrict__ xt, const float* __restrict__ xx, int* __restrict__ idx) {
    int tid = threadIdx.x;
    int l = tid & 63;
    int pid = blockIdx.x * 4 + (tid >> 6);
    int b = pid >> 11;
    const float* xb  = xt + (size_t)b * NPTS * 3;
    const float* xxb = xx + (size_t)b * NPTS;
    int i = pid & 2047;
    float xi0 = xb[i * 3 + 0], xi1 = xb[i * 3 + 1], xi2 = xb[i * 3 + 2];
    float xxi = xxb[i];
    float v[32];
#pragma unroll
    for (int q = 0; q < 32; q++) {
        int j = l + q * 64;
        float dot = __fadd_rn(__fadd_rn(__fmul_rn(xi0, xb[j * 3 + 0]),
                                        __fmul_rn(xi1, xb[j * 3 + 1])),
                              __fmul_rn(xi2, xb[j * 3 + 2]));
        v[q] = __fsub_rn(__fsub_rn(-xxi, __fmul_rn(-2.0f, dot)), xxb[j]);
    }
    int* out = idx + (size_t)pid * KNN;
    for (int t = 0; t < KNN; t++) {
        float bv = -3.0e38f; int bi = 0x7fffffff;
#pragma unroll
        for (int q = 0; q < 32; q++) {
            int j = l + q * 64;
            if (v[q] > bv) { bv = v[q]; bi = j; }
        }
#pragma unroll
        for (int off = 1; off < 64; off <<= 1) {
            float ov = __shfl_xor(bv, off);
            int   oi = __shfl_xor(bi, off);
            if (ov > bv || (ov == bv && oi < bi)) { bv = ov; bi = oi; }
        }
        if (l == 0) out[t] = bi;
        int owner = bi & 63, qw = bi >> 6;
        bool isown = (l == owner);
#pragma unroll
        for (int q = 0; q < 32; q++)
            if (isown && q == qw) v[q] = -3.4e38f;
    }
}

// ---------------- conv1: graph feature (6ch) x w1(64x6) -> y1 NHWC [m][64] bf16 ----------------
__launch_bounds__(256)
__global__ void conv1_k(const float* __restrict__ xt, const int* __restrict__ idx,
                        const float* __restrict__ w1, ushort_t* __restrict__ y1) {
    __shared__ float w[384];
    int tid = threadIdx.x;
    for (int t = tid; t < 384; t += 256) w[t] = w1[t];
    __syncthreads();
    int m = blockIdx.x * 256 + tid;        // < M1; idx flat index == m
    int nb = m / KNN;                      // b*N + n
    int b = nb >> 11;
    int j = idx[m];
    const float* pi = xt + (size_t)nb * 3;
    const float* pj = xt + ((size_t)(b * NPTS + j)) * 3;
    float f0 = pj[0] - pi[0], f1 = pj[1] - pi[1], f2 = pj[2] - pi[2];
    float f3 = pi[0], f4 = pi[1], f5 = pi[2];
#pragma unroll
    for (int o8 = 0; o8 < 8; o8++) {
        uint4 u;
        unsigned int* up = (unsigned int*)&u;
#pragma unroll
        for (int e2 = 0; e2 < 4; e2++) {
            const float* wa = w + (o8 * 8 + e2 * 2) * 6;
            const float* wb = wa + 6;
            float r0 = wa[0]*f0 + wa[1]*f1 + wa[2]*f2 + wa[3]*f3 + wa[4]*f4 + wa[5]*f5;
            float r1 = wb[0]*f0 + wb[1]*f1 + wb[2]*f2 + wb[3]*f3 + wb[4]*f4 + wb[5]*f5;
            up[e2] = pack2(r0, r1);
        }
        *(uint4*)(y1 + (size_t)m * 64 + o8 * 8) = u;
    }
}

// ---------------- generic MFMA conv (layers 2,3,5) ----------------
// yout[m][o] = sum_c act(yin[m][c]) * w[o][c], NHWC. Block: 128m x 64o, 4 waves (32m each).
template<int CIN, int COUT, bool BN>
__launch_bounds__(256)
__global__ void conv_mfma_k(const ushort_t* __restrict__ yin,
                            const ushort_t* __restrict__ whi,
                            const ushort_t* __restrict__ wlo,
                            const float* __restrict__ scale,
                            const float* __restrict__ shift,
                            ushort_t* __restrict__ yout) {
    constexpr int SMEM = 28672 + (BN ? CIN * 8 : 0);
    __shared__ char smem[SMEM];
    ushort_t* hA = (ushort_t*)smem;             // [128][56] bf16 (rows 112B, 16B aligned)
    ushort_t* wH = (ushort_t*)(smem + 14336);   // [64][56]
    ushort_t* wL = (ushort_t*)(smem + 21504);   // [64][56]
    float* scl = (float*)(smem + 28672);
    float* shf = scl + CIN;
    const int tid = threadIdx.x;
    const int m0 = blockIdx.x * 128;
    const int o0 = blockIdx.y * 64;
    if constexpr (BN) {
        for (int c = tid; c < CIN; c += 256) { scl[c] = scale[c]; shf[c] = shift[c]; }
    }
    f32x4 acc[2][4];
#pragma unroll
    for (int mt = 0; mt < 2; mt++)
#pragma unroll
        for (int ot = 0; ot < 4; ot++) acc[mt][ot] = (f32x4){0.f, 0.f, 0.f, 0.f};
    const int lane = tid & 63, wv = tid >> 6;
    const int l15 = lane & 15, quad = lane >> 4;
    for (int kc = 0; kc < CIN; kc += 32) {
        __syncthreads();
        // stage activations: 128 rows x 32c, straight copy (BN applied in f32, re-round bf16)
#pragma unroll
        for (int i = 0; i < 2; i++) {
            int tt = tid + 256 * i;
            int mr = tt >> 2, cq = (tt & 3) * 8;
            uint4 u = *(const uint4*)(yin + (size_t)(m0 + mr) * CIN + kc + cq);
            if constexpr (BN) {
                float vv[8]; unpack8(u, vv);
#pragma unroll
                for (int e = 0; e < 8; e++)
                    vv[e] = fmaxf(fmaf(vv[e], scl[kc + cq + e], shf[kc + cq + e]), 0.0f);
                u.x = pack2(vv[0], vv[1]); u.y = pack2(vv[2], vv[3]);
                u.z = pack2(vv[4], vv[5]); u.w = pack2(vv[6], vv[7]);
            }
            *(uint4*)&hA[mr * 56 + cq] = u;
        }
        // stage weights hi/lo: 64 rows x 32c
        {
            int orow = tid >> 2, cq = (tid & 3) * 8;
            *(uint4*)&wH[orow * 56 + cq] = *(const uint4*)(whi + (size_t)(o0 + orow) * CIN + kc + cq);
            *(uint4*)&wL[orow * 56 + cq] = *(const uint4*)(wlo + (size_t)(o0 + orow) * CIN + kc + cq);
        }
        __syncthreads();
        bf16x8 a0 = *(bf16x8*)&hA[(wv * 32 + l15) * 56 + quad * 8];
        bf16x8 a1 = *(bf16x8*)&hA[(wv * 32 + 16 + l15) * 56 + quad * 8];
#pragma unroll
        for (int ot = 0; ot < 4; ot++) {
            bf16x8 bh = *(bf16x8*)&wH[(ot * 16 + l15) * 56 + quad * 8];
            bf16x8 bl = *(bf16x8*)&wL[(ot * 16 + l15) * 56 + quad * 8];
            acc[0][ot] = __builtin_amdgcn_mfma_f32_16x16x32_bf16(a0, bh, acc[0][ot], 0, 0, 0);
            acc[0][ot] = __builtin_amdgcn_mfma_f32_16x16x32_bf16(a0, bl, acc[0][ot], 0, 0, 0);
            acc[1][ot] = __builtin_amdgcn_mfma_f32_16x16x32_bf16(a1, bh, acc[1][ot], 0, 0, 0);
            acc[1][ot] = __builtin_amdgcn_mfma_f32_16x16x32_bf16(a1, bl, acc[1][ot], 0, 0, 0);
        }
    }
    // epilogue: LDS transpose -> coalesced NHWC stores
    __syncthreads();
    ushort_t* outT = (ushort_t*)smem;   // [128][72] (rows 144B, 16B aligned)
#pragma unroll
    for (int mt = 0; mt < 2; mt++)
#pragma unroll
        for (int ot = 0; ot < 4; ot++)
#pragma unroll
            for (int r = 0; r < 4; r++)
                outT[(wv * 32 + mt * 16 + quad * 4 + r) * 72 + ot * 16 + l15] = f2bf(acc[mt][ot][r]);
    __syncthreads();
    int row = tid >> 1, half = tid & 1;
#pragma unroll
    for (int g = 0; g < 4; g++) {
        uint4 u = *(uint4*)&outT[row * 72 + half * 32 + g * 8];
        *(uint4*)(yout + (size_t)(m0 + row) * COUT + o0 + half * 32 + g * 8) = u;
    }
}

// ---------------- conv4 fused MFMA: 320m (16 k-windows) x 64o, K=128.
// LESSONS: (r5/r6) epilogue `unroll 1` -> runtime acc index -> acc demoted to scratch
// -> 1.67 GB phantom HBM traffic. Must fully unroll (static indexing).
// (r7) full unroll WITHOUT barriers -> compiler reordered cross-lane LDS writes/reads
// in the wreg transpose (per-lane alias analysis can't see cross-lane deps) -> stale
// reads, absmax 7. Must keep __syncthreads() between write and read phases.
__launch_bounds__(256, 2)
__global__ void conv4_mfma_k(const ushort_t* __restrict__ y3,
                             const ushort_t* __restrict__ whi,
                             const ushort_t* __restrict__ wlo,
                             const float* __restrict__ scale,
                             const float* __restrict__ shift,
                             float* __restrict__ rawmax, float* __restrict__ rawmin,
                             float* __restrict__ sp) {
    __shared__ char smem[53248];
    ushort_t* hA = (ushort_t*)smem;             // [320][56] = 35840
    ushort_t* wH = (ushort_t*)(smem + 35840);   // [64][56]  = 7168
    ushort_t* wL = (ushort_t*)(smem + 43008);   // [64][56]  = 7168
    float* scl = (float*)(smem + 50176);        // [128]
    float* shf = (float*)(smem + 50688);        // [128]
    float* sw  = (float*)(smem + 51200);        // [4][64][2] per-wave stat partials
    const int tid = threadIdx.x;
    const int m0 = blockIdx.x * 320;            // 1024 m-tiles
    const int o0 = blockIdx.y * 64;             // 4 o-tiles
    for (int c = tid; c < 128; c += 256) { scl[c] = scale[c]; shf[c] = shift[c]; }
    for (int i = tid; i < 512; i += 256) sw[i] = 0.0f;
    f32x4 acc[5][4];
#pragma unroll
    for (int mt = 0; mt < 5; mt++)
#pragma unroll
        for (int ot = 0; ot < 4; ot++) acc[mt][ot] = (f32x4){0.f, 0.f, 0.f, 0.f};
    const int lane = tid & 63, wv = tid >> 6;
    const int l15 = lane & 15, quad = lane >> 4;
    for (int kc = 0; kc < 128; kc += 32) {
        __syncthreads();
        // stage activations: 320 rows x 32c (BN+ReLU applied)
#pragma unroll
        for (int i = 0; i < 5; i++) {
            int tt = tid + 256 * i;
            int mr = tt >> 2, cq = (tt & 3) * 8;
            uint4 u = *(const uint4*)(y3 + (size_t)(m0 + mr) * 128 + kc + cq);
            float vv[8]; unpack8(u, vv);
#pragma unroll
            for (int e = 0; e < 8; e++)
                vv[e] = fmaxf(fmaf(vv[e], scl[kc + cq + e], shf[kc + cq + e]), 0.0f);
            u.x = pack2(vv[0], vv[1]); u.y = pack2(vv[2], vv[3]);
            u.z = pack2(vv[4], vv[5]); u.w = pack2(vv[6], vv[7]);
            *(uint4*)&hA[mr * 56 + cq] = u;
        }
        // stage weights hi/lo: 64 rows x 32c (each thread: one hi + one lo uint4)
        {
            int row = tid >> 2, cq = (tid & 3) * 8;
            *(uint4*)&wH[row * 56 + cq] = *(const uint4*)(whi + (size_t)(o0 + row) * 128 + kc + cq);
            *(uint4*)&wL[row * 56 + cq] = *(const uint4*)(wlo + (size_t)(o0 + row) * 128 + kc + cq);
        }
        __syncthreads();
        bf16x8 a[5];
#pragma unroll
        for (int mt = 0; mt < 5; mt++)
            a[mt] = *(bf16x8*)&hA[(wv * 80 + mt * 16 + l15) * 56 + quad * 8];
#pragma unroll
        for (int ot = 0; ot < 4; ot++) {
            bf16x8 bh = *(bf16x8*)&wH[(ot * 16 + l15) * 56 + quad * 8];
            bf16x8 bl = *(bf16x8*)&wL[(ot * 16 + l15) * 56 + quad * 8];
#pragma unroll
            for (int mt = 0; mt < 5; mt++) {
                acc[mt][ot] = __builtin_amdgcn_mfma_f32_16x16x32_bf16(a[mt], bh, acc[mt][ot], 0, 0, 0);
                acc[mt][ot] = __builtin_amdgcn_mfma_f32_16x16x32_bf16(a[mt], bl, acc[mt][ot], 0, 0, 0);
            }
        }
    }
    __syncthreads();   // waves may still be reading hA/wH/wL; wreg below overlays hA
    // epilogue: per wave, 80m x 16o f32 scratch, one o-tile at a time.
    // Fully unrolled (static acc idx) + barriers around cross-lane LDS round-trip.
    float* wreg = (float*)(smem + wv * 5440);   // [80][17]
#pragma unroll
    for (int ot = 0; ot < 4; ot++) {
#pragma unroll
        for (int mt = 0; mt < 5; mt++)
#pragma unroll
            for (int r = 0; r < 4; r++)
                wreg[(mt * 16 + quad * 4 + r) * 17 + l15] = acc[mt][ot][r];
        __syncthreads();   // cross-lane: writes (all lanes) before reads (r7 race fix)
        {
            int pp = quad;                      // 4 points per wave (80m = 4x20)
            const float* rr = wreg + (pp * 20) * 17 + l15;
            float mx = rr[0], mn = rr[0], sm = 0.0f, ss = 0.0f;
#pragma unroll
            for (int q = 0; q < 20; q++) {
                float v = rr[q * 17];
                mx = fmaxf(mx, v); mn = fminf(mn, v);
                sm += v; ss = fmaf(v, v, ss);
            }
            int pt = blockIdx.x * 16 + wv * 4 + pp;
            int o = o0 + ot * 16 + l15;
            rawmax[(size_t)pt * 256 + o] = mx;
            rawmin[(size_t)pt * 256 + o] = mn;
            sm += __shfl_xor(sm, 16); sm += __shfl_xor(sm, 32);
            ss += __shfl_xor(ss, 16); ss += __shfl_xor(ss, 32);
            if (lane < 16) {
                sw[(wv * 64 + ot * 16 + l15) * 2 + 0] += sm;
                sw[(wv * 64 + ot * 16 + l15) * 2 + 1] += ss;
            }
        }
        __syncthreads();   // reads done before next iteration overwrites wreg
    }
    if (tid < 128) {
        int ol = tid >> 1, st = tid & 1;
        float v = 0.0f;
#pragma unroll
        for (int w2 = 0; w2 < 4; w2++) v += sw[(w2 * 64 + ol) * 2 + st];
        size_t bid = (size_t)blockIdx.y * 1024 + blockIdx.x;
        sp[bid * 128 + ol * 2 + st] = v;
    }
}

// ---------------- reduce conv4 stat partials -> sum/sumsq doubles ----------------
__launch_bounds__(256)
__global__ void stats4red_k(const float* __restrict__ sp, double* __restrict__ sum,
                            double* __restrict__ sumsq) {
    __shared__ double rs[256], rss[256];
    int o = blockIdx.x, tid = threadIdx.x;
    int oy = o >> 6, ol = o & 63;
    double s = 0.0, ss = 0.0;
    for (int mb = tid; mb < 1024; mb += 256) {
        size_t bid = (size_t)oy * 1024 + mb;
        s  += (double)sp[bid * 128 + ol * 2 + 0];
        ss += (double)sp[bid * 128 + ol * 2 + 1];
    }
    rs[tid] = s; rss[tid] = ss;
    __syncthreads();
    for (int st = 128; st; st >>= 1) {
        if (tid < st) { rs[tid] += rs[tid + st]; rss[tid] += rss[tid + st]; }
        __syncthreads();
    }
    if (tid == 0) { sum[o] = rs[0]; sumsq[o] = rss[0]; }
}

// ---------------- per-channel sum/sumsq over NHWC y ----------------
template<int C8>
__launch_bounds__(256)
__global__ void stats_nhwc_k(const ushort_t* __restrict__ y, double* __restrict__ sum,
                             double* __restrict__ sumsq, int rpb) {
    constexpr int C = C8 * 8;
    constexpr int STRIDE = 256 / C8;
    __shared__ float ls[C][2];
    int tid = threadIdx.x;
    for (int i = tid; i < C * 2; i += 256) ((float*)ls)[i] = 0.0f;
    int cg = tid % C8, mr = tid / C8;
    size_t r0 = (size_t)blockIdx.x * rpb;
    float s[8], ss[8];
#pragma unroll
    for (int e = 0; e < 8; e++) { s[e] = 0.0f; ss[e] = 0.0f; }
    for (int r = mr; r < rpb; r += STRIDE) {
        uint4 u = *(const uint4*)(y + (r0 + r) * C + cg * 8);
        float vv[8]; unpack8(u, vv);
#pragma unroll
        for (int e = 0; e < 8; e++) { s[e] += vv[e]; ss[e] = fmaf(vv[e], vv[e], ss[e]); }
    }
    __syncthreads();
#pragma unroll
    for (int e = 0; e < 8; e++) {
        atomicAdd(&ls[cg * 8 + e][0], s[e]);
        atomicAdd(&ls[cg * 8 + e][1], ss[e]);
    }
    __syncthreads();
    // strided (C can exceed blockDim; round-4 bug)
    for (int c = tid; c < C; c += 256) {
        atomicAdd(&sum[c], (double)ls[c][0]);
        atomicAdd(&sumsq[c], (double)ls[c][1]);
    }
}

// ---------------- finalize BN ----------------
__global__ void fin_k(const double* __restrict__ sum, const double* __restrict__ sumsq,
                      const float* __restrict__ g, const float* __restrict__ bb,
                      float* __restrict__ scale, float* __restrict__ shift, int C, double invcnt) {
    int c = blockIdx.x * blockDim.x + threadIdx.x;
    if (c < C) {
        double m = sum[c] * invcnt;
        double v = sumsq[c] * invcnt - m * m;
        if (v < 0.0) v = 0.0;
        float sc = g[c] / sqrtf((float)v + 1e-5f);
        scale[c] = sc;
        shift[c] = bb[c] - (float)m * sc;
    }
}

// ---------------- maxpool over k (BN+ReLU) NHWC -> xcat (layers 1-3) ----------------
template<int C8>
__launch_bounds__(256)
__global__ void maxpool_nhwc_k(const ushort_t* __restrict__ y, const float* __restrict__ scale,
                               const float* __restrict__ shift, ushort_t* __restrict__ xcat,
                               int coff) {
    constexpr int C = C8 * 8;
    constexpr int PB = 256 / C8;
    int tid = threadIdx.x;
    int cg = tid % C8, pl = tid / C8;
    int p = blockIdx.x * PB + pl;
    float sc[8], sh[8];
    *(float4*)&sc[0] = *(const float4*)(scale + cg * 8);
    *(float4*)&sc[4] = *(const float4*)(scale + cg * 8 + 4);
    *(float4*)&sh[0] = *(const float4*)(shift + cg * 8);
    *(float4*)&sh[4] = *(const float4*)(shift + cg * 8 + 4);
    float mx[8];
#pragma unroll
    for (int e = 0; e < 8; e++) mx[e] = 0.0f;   // relu floor
    size_t base = (size_t)p * KNN * C + cg * 8;
#pragma unroll
    for (int q = 0; q < KNN; q++) {
        uint4 u = *(const uint4*)(y + base + (size_t)q * C);
        float vv[8]; unpack8(u, vv);
#pragma unroll
        for (int e = 0; e < 8; e++) mx[e] = fmaxf(mx[e], fmaf(vv[e], sc[e], sh[e]));
    }
    uint4 u;
    u.x = pack2(mx[0], mx[1]); u.y = pack2(mx[2], mx[3]);
    u.z = pack2(mx[4], mx[5]); u.w = pack2(mx[6], mx[7]);
    *(uint4*)(xcat + (size_t)p * 512 + coff + cg * 8) = u;
}

// ---------------- pool4 finalize: BN of raw max/min + ReLU -> xcat[.][256..512) ----------------
__launch_bounds__(256)
__global__ void pool4_k(const float* __restrict__ rawmax, const float* __restrict__ rawmin,
                        const float* __restrict__ scale, const float* __restrict__ shift,
                        ushort_t* __restrict__ xcat) {
    int gid = blockIdx.x * 256 + threadIdx.x;   // 524288
    int p = gid >> 5, og = gid & 31;
    float sc[8], sh[8], mxv[8], mnv[8];
    *(float4*)&sc[0]  = *(const float4*)(scale + og * 8);
    *(float4*)&sc[4]  = *(const float4*)(scale + og * 8 + 4);
    *(float4*)&sh[0]  = *(const float4*)(shift + og * 8);
    *(float4*)&sh[4]  = *(const float4*)(shift + og * 8 + 4);
    *(float4*)&mxv[0] = *(const float4*)(rawmax + (size_t)p * 256 + og * 8);
    *(float4*)&mxv[4] = *(const float4*)(rawmax + (size_t)p * 256 + og * 8 + 4);
    *(float4*)&mnv[0] = *(const float4*)(rawmin + (size_t)p * 256 + og * 8);
    *(float4*)&mnv[4] = *(const float4*)(rawmin + (size_t)p * 256 + og * 8 + 4);
    float v[8];
#pragma unroll
    for (int e = 0; e < 8; e++) {
        float raw = (sc[e] >= 0.0f) ? mxv[e] : mnv[e];
        v[e] = fmaxf(fmaf(raw, sc[e], sh[e]), 0.0f);
    }
    uint4 u;
    u.x = pack2(v[0], v[1]); u.y = pack2(v[2], v[3]);
    u.z = pack2(v[4], v[5]); u.w = pack2(v[6], v[7]);
    *(uint4*)(xcat + (size_t)p * 512 + 256 + og * 8) = u;
}

// ---------------- output: BN5+ReLU + transpose NHWC -> [b][c][n] fp32 ----------------
__launch_bounds__(256)
__global__ void out_k(const ushort_t* __restrict__ y5, const float* __restrict__ scale,
                      const float* __restrict__ shift, float* __restrict__ out) {
    __shared__ float tr[64 * 65];
    int tid = threadIdx.x;
    int n0 = blockIdx.x * 64, c0 = blockIdx.y * 64, b = blockIdx.z;
    int nl = tid >> 2, cq = (tid & 3) * 16;
    const ushort_t* src = y5 + (size_t)(b * 2048 + n0 + nl) * 512 + c0 + cq;
#pragma unroll
    for (int h = 0; h < 2; h++) {
        uint4 u = *(const uint4*)(src + h * 8);
        float vv[8]; unpack8(u, vv);
#pragma unroll
        for (int e = 0; e < 8; e++) {
            int c = cq + h * 8 + e;
            tr[c * 65 + nl] = fmaxf(fmaf(vv[e], scale[c0 + c], shift[c0 + c]), 0.0f);
        }
    }
    __syncthreads();
    int cl = tid >> 2, ng = (tid & 3) * 16;
#pragma unroll
    for (int g = 0; g < 4; g++) {
        float4 v = *(float4*)&tr[cl * 65 + ng + g * 4];
        *(float4*)(out + ((size_t)b * 512 + c0 + cl) * 2048 + n0 + ng + g * 4) = v;
    }
}

// ---------------- host ----------------
extern "C" void kernel_launch(void* const* d_in, const int* in_sizes, int n_in,
                              void* d_out, int out_size, void* d_ws, size_t ws_size,
                              hipStream_t stream) {
    (void)in_sizes; (void)n_in; (void)out_size;
    if (ws_size < WS_NEEDED) return;
    const float* x  = (const float*)d_in[0];
    const float* w1 = (const float*)d_in[1];
    const float* g1 = (const float*)d_in[2];
    const float* b1 = (const float*)d_in[3];
    const float* w2 = (const float*)d_in[4];
    const float* g2 = (const float*)d_in[5];
    const float* b2 = (const float*)d_in[6];
    const float* w3 = (const float*)d_in[7];
    const float* g3 = (const float*)d_in[8];
    const float* b3 = (const float*)d_in[9];
    const float* w4 = (const float*)d_in[10];
    const float* g4 = (const float*)d_in[11];
    const float* b4 = (const float*)d_in[12];
    const float* w5 = (const float*)d_in[13];
    const float* g5 = (const float*)d_in[14];
    const float* b5 = (const float*)d_in[15];

    char* ws = (char*)d_ws;
    float* xt  = (float*)(ws + OFF_XT);
    float* xx  = (float*)(ws + OFF_XX);
    int*   idx = (int*)(ws + OFF_IDX);
    ushort_t* wh2 = (ushort_t*)(ws + OFF_WH2); ushort_t* wl2 = (ushort_t*)(ws + OFF_WL2);
    ushort_t* wh3 = (ushort_t*)(ws + OFF_WH3); ushort_t* wl3 = (ushort_t*)(ws + OFF_WL3);
    ushort_t* wh4 = (ushort_t*)(ws + OFF_WH4); ushort_t* wl4 = (ushort_t*)(ws + OFF_WL4);
    ushort_t* wh5 = (ushort_t*)(ws + OFF_WH5); ushort_t* wl5 = (ushort_t*)(ws + OFF_WL5);
    ushort_t* y1 = (ushort_t*)(ws + OFF_REG0);
    ushort_t* y2 = (ushort_t*)(ws + OFF_REG1);
    ushort_t* y3 = (ushort_t*)(ws + OFF_REG0);
    float* rawmax = (float*)(ws + OFF_REG1);
    float* rawmin = (float*)(ws + OFF_REG1 + 16777216UL);
    float* sp4    = (float*)(ws + OFF_REG1 + 33554432UL);  // 2 MB partials
    ushort_t* y5 = (ushort_t*)(ws + OFF_REG0);
    ushort_t* xcat = (ushort_t*)(ws + OFF_XCAT);

    double* sum[5]; double* sumsq[5]; float* scl[5]; float* shf[5];
    for (int l = 0; l < 5; l++) {
        sum[l]   = (double*)(ws + OFF_STATS + (size_t)l * 8192);
        sumsq[l] = sum[l] + 512;
        scl[l]   = (float*)(ws + OFF_SS + (size_t)l * 4096);
        shf[l]   = scl[l] + 512;
    }

    hipMemsetAsync(ws + OFF_STATS, 0, 40960, stream);
    prep_k<<<64, 256, 0, stream>>>(x, xt, xx);
    wsplit_k<<<16,   256, 0, stream>>>(w2, wh2, wl2, 4096);
    wsplit_k<<<32,   256, 0, stream>>>(w3, wh3, wl3, 8192);
    wsplit_k<<<128,  256, 0, stream>>>(w4, wh4, wl4, 32768);
    wsplit_k<<<1024, 256, 0, stream>>>(w5, wh5, wl5, 262144);
    knn_k<<<4096, 256, 0, stream>>>(xt, xx, idx);

    // layer 1
    conv1_k<<<1280, 256, 0, stream>>>(xt, idx, w1, y1);
    stats_nhwc_k<8><<<160, 256, 0, stream>>>(y1, sum[0], sumsq[0], 2048);
    fin_k<<<1, 512, 0, stream>>>(sum[0], sumsq[0], g1, b1, scl[0], shf[0], 64, 1.0 / 327680.0);
    maxpool_nhwc_k<8><<<512, 256, 0, stream>>>(y1, scl[0], shf[0], xcat, 0);

    // layer 2: 64 -> 64
    conv_mfma_k<64, 64, true><<<dim3(2560, 1), 256, 0, stream>>>(y1, wh2, wl2, scl[0], shf[0], y2);
    stats_nhwc_k<8><<<160, 256, 0, stream>>>(y2, sum[1], sumsq[1], 2048);
    fin_k<<<1, 512, 0, stream>>>(sum[1], sumsq[1], g2, b2, scl[1], shf[1], 64, 1.0 / 327680.0);
    maxpool_nhwc_k<8><<<512, 256, 0, stream>>>(y2, scl[1], shf[1], xcat, 64);

    // layer 3: 64 -> 128
    conv_mfma_k<64, 128, true><<<dim3(2560, 2), 256, 0, stream>>>(y2, wh3, wl3, scl[1], shf[1], y3);
    stats_nhwc_k<16><<<320, 256, 0, stream>>>(y3, sum[2], sumsq[2], 1024);
    fin_k<<<1, 512, 0, stream>>>(sum[2], sumsq[2], g3, b3, scl[2], shf[2], 128, 1.0 / 327680.0);
    maxpool_nhwc_k<16><<<1024, 256, 0, stream>>>(y3, scl[2], shf[2], xcat, 128);

    // layer 4: 128 -> 256 fused (no y4), partial stats; 320m x 64o tiles
    conv4_mfma_k<<<dim3(1024, 4), 256, 0, stream>>>(y3, wh4, wl4, scl[2], shf[2],
                                                    rawmax, rawmin, sp4);
    stats4red_k<<<256, 256, 0, stream>>>(sp4, sum[3], sumsq[3]);
    fin_k<<<1, 512, 0, stream>>>(sum[3], sumsq[3], g4, b4, scl[3], shf[3], 256, 1.0 / 327680.0);
    pool4_k<<<2048, 256, 0, stream>>>(rawmax, rawmin, scl[3], shf[3], xcat);

    // layer 5: 512 -> 512 (input already activated)
    conv_mfma_k<512, 512, false><<<dim3(128, 8), 256, 0, stream>>>(xcat, wh5, wl5,
                                                                   nullptr, nullptr, y5);
    stats_nhwc_k<64><<<128, 256, 0, stream>>>(y5, sum[4], sumsq[4], 128);
    fin_k<<<1, 512, 0, stream>>>(sum[4], sumsq[4], g5, b5, scl[4], shf[4], 512, 1.0 / 16384.0);
    out_k<<<dim3(32, 8, 8), 256, 0, stream>>>(y5, scl[4], shf[4], (float*)d_out);
}

// Round 9
// 565.380 us; speedup vs baseline: 1.7525x; 1.1800x over previous
//
#include <hip/hip_runtime.h>
#include <cstdint>
#include <cstddef>

// ---------------- constants ----------------
#define BATCH 8
#define NPTS 2048
#define KNN 20
#define M1 327680   // BATCH*NPTS*KNN
#define M2 16384    // BATCH*NPTS

typedef unsigned short ushort_t;
typedef __attribute__((ext_vector_type(8))) short bf16x8;   // 8 bf16 = 4 VGPRs
typedef __attribute__((ext_vector_type(4))) float f32x4;    // MFMA acc

// ws layout (bytes) — total 181,121,024 (< 256 MiB; r1 crash at 271MB => ws ~256MiB)
#define OFF_XT    0UL          // 196608   float xt[b*n][3]
#define OFF_XX    196608UL     // 65536    float xx[b*n]
#define OFF_IDX   262144UL     // 1310720  int idx[b*n][20]
#define OFF_WH2   1572864UL    // 8192   bf16 [64][64]
#define OFF_WL2   1581056UL    // 8192
#define OFF_WH3   1589248UL    // 16384  bf16 [128][64]
#define OFF_WL3   1605632UL    // 16384
#define OFF_WH4   1622016UL    // 65536  bf16 [256][128]
#define OFF_WL4   1687552UL    // 65536
#define OFF_WH5   1753088UL    // 524288 bf16 [512][512]
#define OFF_WL5   2277376UL    // 524288
#define OFF_STATS 2801664UL    // 40960   5 x (512 sum + 512 sumsq) double
#define OFF_SS    2842624UL    // 20480   5 x (512 scale + 512 shift) float
// REG0: y1 [M1][64] (41.9MB) -> y3 [M1][128] (83.9MB) -> y5 [M2][512] (16.8MB)
#define OFF_REG0  2863104UL    // 83886080
// REG1: y2 [M1][64] (41.9MB)
#define OFF_REG1  86749184UL   // 41943040
#define OFF_XCAT  128692224UL  // 16777216 xcat[M2][512] bf16
// dedicated raw-pool region (layers 2,3,4 sequentially; sized for COUT=256)
#define OFF_RAWMAX 145469440UL // 16777216 f32 [16384][<=256]
#define OFF_RAWMIN 162246656UL // 16777216
#define OFF_SP     179023872UL // 2097152  f32 partials [<=4096 blocks][128]
#define WS_NEEDED  181121024UL

// ---------------- helpers ----------------
__device__ __forceinline__ float bf2f(unsigned short u) {
    union { unsigned int i; float f; } c; c.i = ((unsigned int)u) << 16; return c.f;
}
__device__ __forceinline__ unsigned short f2bf(float f) {
    union { float f; unsigned int i; } c; c.f = f;
    unsigned int x = c.i;
    unsigned int r = (x + 0x7fffu + ((x >> 16) & 1u)) >> 16;  // RNE
    return (unsigned short)r;
}
__device__ __forceinline__ unsigned int pack2(float a, float b) {
    return (unsigned int)f2bf(a) | ((unsigned int)f2bf(b) << 16);
}
__device__ __forceinline__ void unpack8(uint4 u, float* v) {
    v[0] = bf2f((unsigned short)(u.x & 0xffffu)); v[1] = bf2f((unsigned short)(u.x >> 16));
    v[2] = bf2f((unsigned short)(u.y & 0xffffu)); v[3] = bf2f((unsigned short)(u.y >> 16));
    v[4] = bf2f((unsigned short)(u.z & 0xffffu)); v[5] = bf2f((unsigned short)(u.z >> 16));
    v[6] = bf2f((unsigned short)(u.w & 0xffffu)); v[7] = bf2f((unsigned short)(u.w >> 16));
}

// ---------------- prep: transpose x, compute xx ----------------
__global__ void prep_k(const float* __restrict__ x, float* __restrict__ xt, float* __restrict__ xx) {
    int t = blockIdx.x * 256 + threadIdx.x;   // 16384
    int b = t >> 11, n = t & 2047;
    float v0 = x[((size_t)b * 3 + 0) * NPTS + n];
    float v1 = x[((size_t)b * 3 + 1) * NPTS + n];
    float v2 = x[((size_t)b * 3 + 2) * NPTS + n];
    xt[(size_t)t * 3 + 0] = v0; xt[(size_t)t * 3 + 1] = v1; xt[(size_t)t * 3 + 2] = v2;
    xx[t] = __fadd_rn(__fadd_rn(__fmul_rn(v0, v0), __fmul_rn(v1, v1)), __fmul_rn(v2, v2));
}

// ---------------- weight split: fp32 -> bf16 hi + bf16 lo ----------------
__global__ void wsplit_k(const float* __restrict__ w, ushort_t* __restrict__ hi,
                         ushort_t* __restrict__ lo, int n) {
    int t = blockIdx.x * 256 + threadIdx.x;
    if (t < n) {
        float f = w[t];
        ushort_t h = f2bf(f);
        hi[t] = h;
        lo[t] = f2bf(f - bf2f(h));
    }
}

// ---------------- knn: wave-per-point top-20, tournament selection ----------------
// Per-lane 32 values in 4 groups of 8 with cached group maxima. After the butterfly the
// winner is identical in all lanes -> readfirstlane makes the group id SCALAR -> uniform
// branch: only the affected group of 8 is rescanned (~85 inst/round vs ~170 full rescan).
#define KNN_RESCAN(G) { \
    _Pragma("unroll") \
    for (int q = (G) * 8; q < (G) * 8 + 8; q++) \
        if (own && q == qw) v[q] = -3.4e38f; \
    float m = v[(G) * 8]; int qi = (G) * 8; \
    _Pragma("unroll") \
    for (int q = (G) * 8 + 1; q < (G) * 8 + 8; q++) \
        if (v[q] > m) { m = v[q]; qi = q; } \
    gm[G] = m; gq[G] = qi; }

__launch_bounds__(256)
__global__ void knn_k(const float* __restrict__ xt, const float* __restrict__ xx, int* __restrict__ idx) {
    int tid = threadIdx.x;
    int l = tid & 63;
    int pid = blockIdx.x * 4 + (tid >> 6);
    int b = pid >> 11;
    const float* xb  = xt + (size_t)b * NPTS * 3;
    const float* xxb = xx + (size_t)b * NPTS;
    int i = pid & 2047;
    float xi0 = xb[i * 3 + 0], xi1 = xb[i * 3 + 1], xi2 = xb[i * 3 + 2];
    float xxi = xxb[i];
    float v[32];
#pragma unroll
    for (int q = 0; q < 32; q++) {
        int j = l + q * 64;
        float dot = __fadd_rn(__fadd_rn(__fmul_rn(xi0, xb[j * 3 + 0]),
                                        __fmul_rn(xi1, xb[j * 3 + 1])),
                              __fmul_rn(xi2, xb[j * 3 + 2]));
        v[q] = __fsub_rn(__fsub_rn(-xxi, __fmul_rn(-2.0f, dot)), xxb[j]);
    }
    // group maxima (ascending q, strict > -> lowest j on ties; j = l + q*64 rises with q)
    float gm[4]; int gq[4];
#pragma unroll
    for (int g = 0; g < 4; g++) {
        float m = v[g * 8]; int qi = g * 8;
#pragma unroll
        for (int q = g * 8 + 1; q < g * 8 + 8; q++)
            if (v[q] > m) { m = v[q]; qi = q; }
        gm[g] = m; gq[g] = qi;
    }
    int* out = idx + (size_t)pid * KNN;
    for (int t = 0; t < KNN; t++) {
        float bv = gm[0]; int bq = gq[0];
        if (gm[1] > bv) { bv = gm[1]; bq = gq[1]; }
        if (gm[2] > bv) { bv = gm[2]; bq = gq[2]; }
        if (gm[3] > bv) { bv = gm[3]; bq = gq[3]; }
        int bj = l + bq * 64;
#pragma unroll
        for (int off = 1; off < 64; off <<= 1) {
            float ov = __shfl_xor(bv, off);
            int   oj = __shfl_xor(bj, off);
            if (ov > bv || (ov == bv && oj < bj)) { bv = ov; bj = oj; }
        }
        int bju = __builtin_amdgcn_readfirstlane(bj);  // all lanes equal -> scalar
        if (l == 0) out[t] = bju;
        int qw = bju >> 6;                 // scalar slot index
        bool own = (l == (bju & 63));
        int gw = qw >> 3;                  // scalar group -> uniform branch
        if (gw == 0)      { KNN_RESCAN(0) }
        else if (gw == 1) { KNN_RESCAN(1) }
        else if (gw == 2) { KNN_RESCAN(2) }
        else              { KNN_RESCAN(3) }
    }
}

// ---------------- conv1: graph feature (6ch) x w1(64x6) -> y1 NHWC [m][64] bf16 ----------------
__launch_bounds__(256)
__global__ void conv1_k(const float* __restrict__ xt, const int* __restrict__ idx,
                        const float* __restrict__ w1, ushort_t* __restrict__ y1) {
    __shared__ float w[384];
    int tid = threadIdx.x;
    for (int t = tid; t < 384; t += 256) w[t] = w1[t];
    __syncthreads();
    int m = blockIdx.x * 256 + tid;        // < M1; idx flat index == m
    int nb = m / KNN;                      // b*N + n
    int b = nb >> 11;
    int j = idx[m];
    const float* pi = xt + (size_t)nb * 3;
    const float* pj = xt + ((size_t)(b * NPTS + j)) * 3;
    float f0 = pj[0] - pi[0], f1 = pj[1] - pi[1], f2 = pj[2] - pi[2];
    float f3 = pi[0], f4 = pi[1], f5 = pi[2];
#pragma unroll
    for (int o8 = 0; o8 < 8; o8++) {
        uint4 u;
        unsigned int* up = (unsigned int*)&u;
#pragma unroll
        for (int e2 = 0; e2 < 4; e2++) {
            const float* wa = w + (o8 * 8 + e2 * 2) * 6;
            const float* wb = wa + 6;
            float r0 = wa[0]*f0 + wa[1]*f1 + wa[2]*f2 + wa[3]*f3 + wa[4]*f4 + wa[5]*f5;
            float r1 = wb[0]*f0 + wb[1]*f1 + wb[2]*f2 + wb[3]*f3 + wb[4]*f4 + wb[5]*f5;
            up[e2] = pack2(r0, r1);
        }
        *(uint4*)(y1 + (size_t)m * 64 + o8 * 8) = u;
    }
}

// ---------------- generic MFMA conv (layer 5) ----------------
template<int CIN, int COUT, bool BN>
__launch_bounds__(256)
__global__ void conv_mfma_k(const ushort_t* __restrict__ yin,
                            const ushort_t* __restrict__ whi,
                            const ushort_t* __restrict__ wlo,
                            const float* __restrict__ scale,
                            const float* __restrict__ shift,
                            ushort_t* __restrict__ yout) {
    constexpr int SMEM = 28672 + (BN ? CIN * 8 : 0);
    __shared__ char smem[SMEM];
    ushort_t* hA = (ushort_t*)smem;             // [128][56]
    ushort_t* wH = (ushort_t*)(smem + 14336);   // [64][56]
    ushort_t* wL = (ushort_t*)(smem + 21504);   // [64][56]
    float* scl = (float*)(smem + 28672);
    float* shf = scl + CIN;
    const int tid = threadIdx.x;
    const int m0 = blockIdx.x * 128;
    const int o0 = blockIdx.y * 64;
    if constexpr (BN) {
        for (int c = tid; c < CIN; c += 256) { scl[c] = scale[c]; shf[c] = shift[c]; }
    }
    f32x4 acc[2][4];
#pragma unroll
    for (int mt = 0; mt < 2; mt++)
#pragma unroll
        for (int ot = 0; ot < 4; ot++) acc[mt][ot] = (f32x4){0.f, 0.f, 0.f, 0.f};
    const int lane = tid & 63, wv = tid >> 6;
    const int l15 = lane & 15, quad = lane >> 4;
    for (int kc = 0; kc < CIN; kc += 32) {
        __syncthreads();
#pragma unroll
        for (int i = 0; i < 2; i++) {
            int tt = tid + 256 * i;
            int mr = tt >> 2, cq = (tt & 3) * 8;
            uint4 u = *(const uint4*)(yin + (size_t)(m0 + mr) * CIN + kc + cq);
            if constexpr (BN) {
                float vv[8]; unpack8(u, vv);
#pragma unroll
                for (int e = 0; e < 8; e++)
                    vv[e] = fmaxf(fmaf(vv[e], scl[kc + cq + e], shf[kc + cq + e]), 0.0f);
                u.x = pack2(vv[0], vv[1]); u.y = pack2(vv[2], vv[3]);
                u.z = pack2(vv[4], vv[5]); u.w = pack2(vv[6], vv[7]);
            }
            *(uint4*)&hA[mr * 56 + cq] = u;
        }
        {
            int orow = tid >> 2, cq = (tid & 3) * 8;
            *(uint4*)&wH[orow * 56 + cq] = *(const uint4*)(whi + (size_t)(o0 + orow) * CIN + kc + cq);
            *(uint4*)&wL[orow * 56 + cq] = *(const uint4*)(wlo + (size_t)(o0 + orow) * CIN + kc + cq);
        }
        __syncthreads();
        bf16x8 a0 = *(bf16x8*)&hA[(wv * 32 + l15) * 56 + quad * 8];
        bf16x8 a1 = *(bf16x8*)&hA[(wv * 32 + 16 + l15) * 56 + quad * 8];
#pragma unroll
        for (int ot = 0; ot < 4; ot++) {
            bf16x8 bh = *(bf16x8*)&wH[(ot * 16 + l15) * 56 + quad * 8];
            bf16x8 bl = *(bf16x8*)&wL[(ot * 16 + l15) * 56 + quad * 8];
            acc[0][ot] = __builtin_amdgcn_mfma_f32_16x16x32_bf16(a0, bh, acc[0][ot], 0, 0, 0);
            acc[0][ot] = __builtin_amdgcn_mfma_f32_16x16x32_bf16(a0, bl, acc[0][ot], 0, 0, 0);
            acc[1][ot] = __builtin_amdgcn_mfma_f32_16x16x32_bf16(a1, bh, acc[1][ot], 0, 0, 0);
            acc[1][ot] = __builtin_amdgcn_mfma_f32_16x16x32_bf16(a1, bl, acc[1][ot], 0, 0, 0);
        }
    }
    __syncthreads();
    ushort_t* outT = (ushort_t*)smem;   // [128][72]
#pragma unroll
    for (int mt = 0; mt < 2; mt++)
#pragma unroll
        for (int ot = 0; ot < 4; ot++)
#pragma unroll
            for (int r = 0; r < 4; r++)
                outT[(wv * 32 + mt * 16 + quad * 4 + r) * 72 + ot * 16 + l15] = f2bf(acc[mt][ot][r]);
    __syncthreads();
    int row = tid >> 1, half = tid & 1;
#pragma unroll
    for (int g = 0; g < 4; g++) {
        uint4 u = *(uint4*)&outT[row * 72 + half * 32 + g * 8];
        *(uint4*)(yout + (size_t)(m0 + row) * COUT + o0 + half * 32 + g * 8) = u;
    }
}

// ---------------- fused conv (layers 2,3,4): 320m (16 k-windows) x 64o tiles.
// Epilogue: per-window raw max/min + per-block f32 stats partials; optional y write.
// LESSONS: (r5/r6) runtime acc index -> scratch demotion (1.67GB phantom traffic): keep
// all acc indexing static (full unroll). (r7) cross-lane LDS round-trip needs
// __syncthreads() between write and read phases (per-lane alias analysis misses it).
template<int CIN, int COUT, bool WRITEY>
__launch_bounds__(256, 2)
__global__ void conv_fused_k(const ushort_t* __restrict__ yin,
                             const ushort_t* __restrict__ whi,
                             const ushort_t* __restrict__ wlo,
                             const float* __restrict__ scale,
                             const float* __restrict__ shift,
                             ushort_t* __restrict__ yout,
                             float* __restrict__ rawmax, float* __restrict__ rawmin,
                             float* __restrict__ sp) {
    __shared__ char smem[53248];
    ushort_t* hA = (ushort_t*)smem;             // [320][56] = 35840
    ushort_t* wH = (ushort_t*)(smem + 35840);   // [64][56]  = 7168
    ushort_t* wL = (ushort_t*)(smem + 43008);   // [64][56]  = 7168
    float* scl = (float*)(smem + 50176);        // [<=128]
    float* shf = (float*)(smem + 50688);        // [<=128]
    float* sw  = (float*)(smem + 51200);        // [4][64][2]
    const int tid = threadIdx.x;
    const int m0 = blockIdx.x * 320;            // 1024 m-tiles
    const int o0 = blockIdx.y * 64;
    for (int c = tid; c < CIN; c += 256) { scl[c] = scale[c]; shf[c] = shift[c]; }
    for (int i = tid; i < 512; i += 256) sw[i] = 0.0f;
    f32x4 acc[5][4];
#pragma unroll
    for (int mt = 0; mt < 5; mt++)
#pragma unroll
        for (int ot = 0; ot < 4; ot++) acc[mt][ot] = (f32x4){0.f, 0.f, 0.f, 0.f};
    const int lane = tid & 63, wv = tid >> 6;
    const int l15 = lane & 15, quad = lane >> 4;
    for (int kc = 0; kc < CIN; kc += 32) {
        __syncthreads();
        // stage activations: 320 rows x 32c (BN+ReLU applied)
#pragma unroll
        for (int i = 0; i < 5; i++) {
            int tt = tid + 256 * i;
            int mr = tt >> 2, cq = (tt & 3) * 8;
            uint4 u = *(const uint4*)(yin + (size_t)(m0 + mr) * CIN + kc + cq);
            float vv[8]; unpack8(u, vv);
#pragma unroll
            for (int e = 0; e < 8; e++)
                vv[e] = fmaxf(fmaf(vv[e], scl[kc + cq + e], shf[kc + cq + e]), 0.0f);
            u.x = pack2(vv[0], vv[1]); u.y = pack2(vv[2], vv[3]);
            u.z = pack2(vv[4], vv[5]); u.w = pack2(vv[6], vv[7]);
            *(uint4*)&hA[mr * 56 + cq] = u;
        }
        // stage weights hi/lo: 64 rows x 32c
        {
            int row = tid >> 2, cq = (tid & 3) * 8;
            *(uint4*)&wH[row * 56 + cq] = *(const uint4*)(whi + (size_t)(o0 + row) * CIN + kc + cq);
            *(uint4*)&wL[row * 56 + cq] = *(const uint4*)(wlo + (size_t)(o0 + row) * CIN + kc + cq);
        }
        __syncthreads();
        bf16x8 a[5];
#pragma unroll
        for (int mt = 0; mt < 5; mt++)
            a[mt] = *(bf16x8*)&hA[(wv * 80 + mt * 16 + l15) * 56 + quad * 8];
#pragma unroll
        for (int ot = 0; ot < 4; ot++) {
            bf16x8 bh = *(bf16x8*)&wH[(ot * 16 + l15) * 56 + quad * 8];
            bf16x8 bl = *(bf16x8*)&wL[(ot * 16 + l15) * 56 + quad * 8];
#pragma unroll
            for (int mt = 0; mt < 5; mt++) {
                acc[mt][ot] = __builtin_amdgcn_mfma_f32_16x16x32_bf16(a[mt], bh, acc[mt][ot], 0, 0, 0);
                acc[mt][ot] = __builtin_amdgcn_mfma_f32_16x16x32_bf16(a[mt], bl, acc[mt][ot], 0, 0, 0);
            }
        }
    }
    __syncthreads();   // waves may still read hA/wH/wL; wreg below overlays hA
    // epilogue: per wave, 80m x 16o f32 scratch ([80][20]: 80B rows, 16B aligned)
    float* wreg = (float*)(smem + wv * 6400);
#pragma unroll
    for (int ot = 0; ot < 4; ot++) {
#pragma unroll
        for (int mt = 0; mt < 5; mt++)
#pragma unroll
            for (int r = 0; r < 4; r++)
                wreg[(mt * 16 + quad * 4 + r) * 20 + l15] = acc[mt][ot][r];
        __syncthreads();   // cross-lane round-trip (r7 lesson)
        {
            int pp = quad;                      // 4 points per wave (80m = 4x20)
            const float* rr = wreg + (pp * 20) * 20 + l15;
            float mx = rr[0], mn = rr[0], sm = 0.0f, ss = 0.0f;
#pragma unroll
            for (int q = 0; q < 20; q++) {
                float vv = rr[q * 20];
                mx = fmaxf(mx, vv); mn = fminf(mn, vv);
                sm += vv; ss = fmaf(vv, vv, ss);
            }
            int pt = blockIdx.x * 16 + wv * 4 + pp;
            int o = o0 + ot * 16 + l15;
            rawmax[(size_t)pt * COUT + o] = mx;
            rawmin[(size_t)pt * COUT + o] = mn;
            sm += __shfl_xor(sm, 16); sm += __shfl_xor(sm, 32);
            ss += __shfl_xor(ss, 16); ss += __shfl_xor(ss, 32);
            if (lane < 16) {
                sw[(wv * 64 + ot * 16 + l15) * 2 + 0] += sm;
                sw[(wv * 64 + ot * 16 + l15) * 2 + 1] += ss;
            }
        }
        if constexpr (WRITEY) {
            // 80 rows x 16 o's = 160 chunks of 8 bf16 (16B stores)
#pragma unroll
            for (int it = 0; it < 3; it++) {
                int t = lane + it * 64;
                if (t < 160) {
                    int row = t >> 1, half = t & 1;
                    float4 f0 = *(float4*)&wreg[row * 20 + half * 8];
                    float4 f1 = *(float4*)&wreg[row * 20 + half * 8 + 4];
                    uint4 u;
                    u.x = pack2(f0.x, f0.y); u.y = pack2(f0.z, f0.w);
                    u.z = pack2(f1.x, f1.y); u.w = pack2(f1.z, f1.w);
                    *(uint4*)(yout + (size_t)(m0 + wv * 80 + row) * COUT + o0 + ot * 16 + half * 8) = u;
                }
            }
        }
        __syncthreads();   // reads done before next ot overwrites wreg
    }
    if (tid < 128) {
        int ol = tid >> 1, st = tid & 1;
        float v = 0.0f;
#pragma unroll
        for (int w2 = 0; w2 < 4; w2++) v += sw[(w2 * 64 + ol) * 2 + st];
        size_t bid = (size_t)blockIdx.y * 1024 + blockIdx.x;
        sp[bid * 128 + ol * 2 + st] = v;
    }
}

// ---------------- reduce fused-conv stat partials -> sum/sumsq doubles ----------------
__launch_bounds__(256)
__global__ void stats4red_k(const float* __restrict__ sp, double* __restrict__ sum,
                            double* __restrict__ sumsq) {
    __shared__ double rs[256], rss[256];
    int o = blockIdx.x, tid = threadIdx.x;
    int oy = o >> 6, ol = o & 63;
    double s = 0.0, ss = 0.0;
    for (int mb = tid; mb < 1024; mb += 256) {
        size_t bid = (size_t)oy * 1024 + mb;
        s  += (double)sp[bid * 128 + ol * 2 + 0];
        ss += (double)sp[bid * 128 + ol * 2 + 1];
    }
    rs[tid] = s; rss[tid] = ss;
    __syncthreads();
    for (int st = 128; st; st >>= 1) {
        if (tid < st) { rs[tid] += rs[tid + st]; rss[tid] += rss[tid + st]; }
        __syncthreads();
    }
    if (tid == 0) { sum[o] = rs[0]; sumsq[o] = rss[0]; }
}

// ---------------- per-channel sum/sumsq over NHWC y (layers 1,5) ----------------
template<int C8>
__launch_bounds__(256)
__global__ void stats_nhwc_k(const ushort_t* __restrict__ y, double* __restrict__ sum,
                             double* __restrict__ sumsq, int rpb) {
    constexpr int C = C8 * 8;
    constexpr int STRIDE = 256 / C8;
    __shared__ float ls[C][2];
    int tid = threadIdx.x;
    for (int i = tid; i < C * 2; i += 256) ((float*)ls)[i] = 0.0f;
    int cg = tid % C8, mr = tid / C8;
    size_t r0 = (size_t)blockIdx.x * rpb;
    float s[8], ss[8];
#pragma unroll
    for (int e = 0; e < 8; e++) { s[e] = 0.0f; ss[e] = 0.0f; }
    for (int r = mr; r < rpb; r += STRIDE) {
        uint4 u = *(const uint4*)(y + (r0 + r) * C + cg * 8);
        float vv[8]; unpack8(u, vv);
#pragma unroll
        for (int e = 0; e < 8; e++) { s[e] += vv[e]; ss[e] = fmaf(vv[e], vv[e], ss[e]); }
    }
    __syncthreads();
#pragma unroll
    for (int e = 0; e < 8; e++) {
        atomicAdd(&ls[cg * 8 + e][0], s[e]);
        atomicAdd(&ls[cg * 8 + e][1], ss[e]);
    }
    __syncthreads();
    // strided (C can exceed blockDim; round-4 bug)
    for (int c = tid; c < C; c += 256) {
        atomicAdd(&sum[c], (double)ls[c][0]);
        atomicAdd(&sumsq[c], (double)ls[c][1]);
    }
}

// ---------------- finalize BN ----------------
__global__ void fin_k(const double* __restrict__ sum, const double* __restrict__ sumsq,
                      const float* __restrict__ g, const float* __restrict__ bb,
                      float* __restrict__ scale, float* __restrict__ shift, int C, double invcnt) {
    int c = blockIdx.x * blockDim.x + threadIdx.x;
    if (c < C) {
        double m = sum[c] * invcnt;
        double v = sumsq[c] * invcnt - m * m;
        if (v < 0.0) v = 0.0;
        float sc = g[c] / sqrtf((float)v + 1e-5f);
        scale[c] = sc;
        shift[c] = bb[c] - (float)m * sc;
    }
}

// ---------------- maxpool over k (BN+ReLU) NHWC -> xcat (layer 1) ----------------
template<int C8>
__launch_bounds__(256)
__global__ void maxpool_nhwc_k(const ushort_t* __restrict__ y, const float* __restrict__ scale,
                               const float* __restrict__ shift, ushort_t* __restrict__ xcat,
                               int coff) {
    constexpr int C = C8 * 8;
    constexpr int PB = 256 / C8;
    int tid = threadIdx.x;
    int cg = tid % C8, pl = tid / C8;
    int p = blockIdx.x * PB + pl;
    float sc[8], sh[8];
    *(float4*)&sc[0] = *(const float4*)(scale + cg * 8);
    *(float4*)&sc[4] = *(const float4*)(scale + cg * 8 + 4);
    *(float4*)&sh[0] = *(const float4*)(shift + cg * 8);
    *(float4*)&sh[4] = *(const float4*)(shift + cg * 8 + 4);
    float mx[8];
#pragma unroll
    for (int e = 0; e < 8; e++) mx[e] = 0.0f;   // relu floor
    size_t base = (size_t)p * KNN * C + cg * 8;
#pragma unroll
    for (int q = 0; q < KNN; q++) {
        uint4 u = *(const uint4*)(y + base + (size_t)q * C);
        float vv[8]; unpack8(u, vv);
#pragma unroll
        for (int e = 0; e < 8; e++) mx[e] = fmaxf(mx[e], fmaf(vv[e], sc[e], sh[e]));
    }
    uint4 u;
    u.x = pack2(mx[0], mx[1]); u.y = pack2(mx[2], mx[3]);
    u.z = pack2(mx[4], mx[5]); u.w = pack2(mx[6], mx[7]);
    *(uint4*)(xcat + (size_t)p * 512 + coff + cg * 8) = u;
}

// ---------------- pool finalize from raw max/min (BN monotone) -> xcat (layers 2,3,4) ----------------
template<int C8>
__launch_bounds__(256)
__global__ void pool_raw_k(const float* __restrict__ rawmax, const float* __restrict__ rawmin,
                           const float* __restrict__ scale, const float* __restrict__ shift,
                           ushort_t* __restrict__ xcat, int coff) {
    constexpr int COUT = C8 * 8;
    int gid = blockIdx.x * 256 + threadIdx.x;   // 16384 * C8
    int p = gid / C8, og = gid % C8;
    float sc[8], sh[8], mxv[8], mnv[8];
    *(float4*)&sc[0]  = *(const float4*)(scale + og * 8);
    *(float4*)&sc[4]  = *(const float4*)(scale + og * 8 + 4);
    *(float4*)&sh[0]  = *(const float4*)(shift + og * 8);
    *(float4*)&sh[4]  = *(const float4*)(shift + og * 8 + 4);
    *(float4*)&mxv[0] = *(const float4*)(rawmax + (size_t)p * COUT + og * 8);
    *(float4*)&mxv[4] = *(const float4*)(rawmax + (size_t)p * COUT + og * 8 + 4);
    *(float4*)&mnv[0] = *(const float4*)(rawmin + (size_t)p * COUT + og * 8);
    *(float4*)&mnv[4] = *(const float4*)(rawmin + (size_t)p * COUT + og * 8 + 4);
    float v[8];
#pragma unroll
    for (int e = 0; e < 8; e++) {
        float raw = (sc[e] >= 0.0f) ? mxv[e] : mnv[e];
        v[e] = fmaxf(fmaf(raw, sc[e], sh[e]), 0.0f);
    }
    uint4 u;
    u.x = pack2(v[0], v[1]); u.y = pack2(v[2], v[3]);
    u.z = pack2(v[4], v[5]); u.w = pack2(v[6], v[7]);
    *(uint4*)(xcat + (size_t)p * 512 + coff + og * 8) = u;
}

// ---------------- output: BN5+ReLU + transpose NHWC -> [b][c][n] fp32 ----------------
__launch_bounds__(256)
__global__ void out_k(const ushort_t* __restrict__ y5, const float* __restrict__ scale,
                      const float* __restrict__ shift, float* __restrict__ out) {
    __shared__ float tr[64 * 65];
    int tid = threadIdx.x;
    int n0 = blockIdx.x * 64, c0 = blockIdx.y * 64, b = blockIdx.z;
    int nl = tid >> 2, cq = (tid & 3) * 16;
    const ushort_t* src = y5 + (size_t)(b * 2048 + n0 + nl) * 512 + c0 + cq;
#pragma unroll
    for (int h = 0; h < 2; h++) {
        uint4 u = *(const uint4*)(src + h * 8);
        float vv[8]; unpack8(u, vv);
#pragma unroll
        for (int e = 0; e < 8; e++) {
            int c = cq + h * 8 + e;
            tr[c * 65 + nl] = fmaxf(fmaf(vv[e], scale[c0 + c], shift[c0 + c]), 0.0f);
        }
    }
    __syncthreads();
    int cl = tid >> 2, ng = (tid & 3) * 16;
#pragma unroll
    for (int g = 0; g < 4; g++) {
        float4 v = *(float4*)&tr[cl * 65 + ng + g * 4];
        *(float4*)(out + ((size_t)b * 512 + c0 + cl) * 2048 + n0 + ng + g * 4) = v;
    }
}

// ---------------- host ----------------
extern "C" void kernel_launch(void* const* d_in, const int* in_sizes, int n_in,
                              void* d_out, int out_size, void* d_ws, size_t ws_size,
                              hipStream_t stream) {
    (void)in_sizes; (void)n_in; (void)out_size;
    if (ws_size < WS_NEEDED) return;
    const float* x  = (const float*)d_in[0];
    const float* w1 = (const float*)d_in[1];
    const float* g1 = (const float*)d_in[2];
    const float* b1 = (const float*)d_in[3];
    const float* w2 = (const float*)d_in[4];
    const float* g2 = (const float*)d_in[5];
    const float* b2 = (const float*)d_in[6];
    const float* w3 = (const float*)d_in[7];
    const float* g3 = (const float*)d_in[8];
    const float* b3 = (const float*)d_in[9];
    const float* w4 = (const float*)d_in[10];
    const float* g4 = (const float*)d_in[11];
    const float* b4 = (const float*)d_in[12];
    const float* w5 = (const float*)d_in[13];
    const float* g5 = (const float*)d_in[14];
    const float* b5 = (const float*)d_in[15];

    char* ws = (char*)d_ws;
    float* xt  = (float*)(ws + OFF_XT);
    float* xx  = (float*)(ws + OFF_XX);
    int*   idx = (int*)(ws + OFF_IDX);
    ushort_t* wh2 = (ushort_t*)(ws + OFF_WH2); ushort_t* wl2 = (ushort_t*)(ws + OFF_WL2);
    ushort_t* wh3 = (ushort_t*)(ws + OFF_WH3); ushort_t* wl3 = (ushort_t*)(ws + OFF_WL3);
    ushort_t* wh4 = (ushort_t*)(ws + OFF_WH4); ushort_t* wl4 = (ushort_t*)(ws + OFF_WL4);
    ushort_t* wh5 = (ushort_t*)(ws + OFF_WH5); ushort_t* wl5 = (ushort_t*)(ws + OFF_WL5);
    ushort_t* y1 = (ushort_t*)(ws + OFF_REG0);
    ushort_t* y2 = (ushort_t*)(ws + OFF_REG1);
    ushort_t* y3 = (ushort_t*)(ws + OFF_REG0);
    ushort_t* y5 = (ushort_t*)(ws + OFF_REG0);
    ushort_t* xcat = (ushort_t*)(ws + OFF_XCAT);
    float* rawmax = (float*)(ws + OFF_RAWMAX);
    float* rawmin = (float*)(ws + OFF_RAWMIN);
    float* sp     = (float*)(ws + OFF_SP);

    double* sum[5]; double* sumsq[5]; float* scl[5]; float* shf[5];
    for (int l = 0; l < 5; l++) {
        sum[l]   = (double*)(ws + OFF_STATS + (size_t)l * 8192);
        sumsq[l] = sum[l] + 512;
        scl[l]   = (float*)(ws + OFF_SS + (size_t)l * 4096);
        shf[l]   = scl[l] + 512;
    }

    hipMemsetAsync(ws + OFF_STATS, 0, 40960, stream);
    prep_k<<<64, 256, 0, stream>>>(x, xt, xx);
    wsplit_k<<<16,   256, 0, stream>>>(w2, wh2, wl2, 4096);
    wsplit_k<<<32,   256, 0, stream>>>(w3, wh3, wl3, 8192);
    wsplit_k<<<128,  256, 0, stream>>>(w4, wh4, wl4, 32768);
    wsplit_k<<<1024, 256, 0, stream>>>(w5, wh5, wl5, 262144);
    knn_k<<<4096, 256, 0, stream>>>(xt, xx, idx);

    // layer 1
    conv1_k<<<1280, 256, 0, stream>>>(xt, idx, w1, y1);
    stats_nhwc_k<8><<<160, 256, 0, stream>>>(y1, sum[0], sumsq[0], 2048);
    fin_k<<<1, 512, 0, stream>>>(sum[0], sumsq[0], g1, b1, scl[0], shf[0], 64, 1.0 / 327680.0);
    maxpool_nhwc_k<8><<<512, 256, 0, stream>>>(y1, scl[0], shf[0], xcat, 0);

    // layer 2: 64 -> 64 fused (y2 + rawmax/min + stats partials)
    conv_fused_k<64, 64, true><<<dim3(1024, 1), 256, 0, stream>>>(
        y1, wh2, wl2, scl[0], shf[0], y2, rawmax, rawmin, sp);
    stats4red_k<<<64, 256, 0, stream>>>(sp, sum[1], sumsq[1]);
    fin_k<<<1, 512, 0, stream>>>(sum[1], sumsq[1], g2, b2, scl[1], shf[1], 64, 1.0 / 327680.0);
    pool_raw_k<8><<<512, 256, 0, stream>>>(rawmax, rawmin, scl[1], shf[1], xcat, 64);

    // layer 3: 64 -> 128 fused
    conv_fused_k<64, 128, true><<<dim3(1024, 2), 256, 0, stream>>>(
        y2, wh3, wl3, scl[1], shf[1], y3, rawmax, rawmin, sp);
    stats4red_k<<<128, 256, 0, stream>>>(sp, sum[2], sumsq[2]);
    fin_k<<<1, 512, 0, stream>>>(sum[2], sumsq[2], g3, b3, scl[2], shf[2], 128, 1.0 / 327680.0);
    pool_raw_k<16><<<1024, 256, 0, stream>>>(rawmax, rawmin, scl[2], shf[2], xcat, 128);

    // layer 4: 128 -> 256 fused (no y4)
    conv_fused_k<128, 256, false><<<dim3(1024, 4), 256, 0, stream>>>(
        y3, wh4, wl4, scl[2], shf[2], nullptr, rawmax, rawmin, sp);
    stats4red_k<<<256, 256, 0, stream>>>(sp, sum[3], sumsq[3]);
    fin_k<<<1, 512, 0, stream>>>(sum[3], sumsq[3], g4, b4, scl[3], shf[3], 256, 1.0 / 327680.0);
    pool_raw_k<32><<<2048, 256, 0, stream>>>(rawmax, rawmin, scl[3], shf[3], xcat, 256);

    // layer 5: 512 -> 512 (input already activated)
    conv_mfma_k<512, 512, false><<<dim3(128, 8), 256, 0, stream>>>(xcat, wh5, wl5,
                                                                   nullptr, nullptr, y5);
    stats_nhwc_k<64><<<128, 256, 0, stream>>>(y5, sum[4], sumsq[4], 128);
    fin_k<<<1, 512, 0, stream>>>(sum[4], sumsq[4], g5, b5, scl[4], shf[4], 512, 1.0 / 16384.0);
    out_k<<<dim3(32, 8, 8), 256, 0, stream>>>(y5, scl[4], shf[4], (float*)d_out);
}

// Round 10
// 563.003 us; speedup vs baseline: 1.7599x; 1.0042x over previous
//
#include <hip/hip_runtime.h>
#include <cstdint>
#include <cstddef>

// ---------------- constants ----------------
#define BATCH 8
#define NPTS 2048
#define KNN 20
#define M1 327680   // BATCH*NPTS*KNN
#define M2 16384    // BATCH*NPTS

typedef unsigned short ushort_t;
typedef __attribute__((ext_vector_type(8))) short bf16x8;   // 8 bf16 = 4 VGPRs
typedef __attribute__((ext_vector_type(4))) float f32x4;    // MFMA acc

// ws layout (bytes) — total 181,121,024
#define OFF_XT    0UL          // 196608   float xt[b*n][3]
#define OFF_XX    196608UL     // 65536    float xx[b*n]
#define OFF_IDX   262144UL     // 1310720  int idx[b*n][20]
#define OFF_WH2   1572864UL    // 8192   bf16 [64][64]
#define OFF_WL2   1581056UL    // 8192
#define OFF_WH3   1589248UL    // 16384  bf16 [128][64]
#define OFF_WL3   1605632UL    // 16384
#define OFF_WH4   1622016UL    // 65536  bf16 [256][128]
#define OFF_WL4   1687552UL    // 65536
#define OFF_WH5   1753088UL    // 524288 bf16 [512][512]
#define OFF_WL5   2277376UL    // 524288
#define OFF_STATS 2801664UL    // 40960   5 x (512 sum + 512 sumsq) double
#define OFF_SS    2842624UL    // 20480   5 x (512 scale + 512 shift) float
// REG0: y1 [M1][64] (41.9MB) -> y3 [M1][128] (83.9MB) -> y5 [M2][512] (16.8MB)
#define OFF_REG0  2863104UL    // 83886080
// REG1: y2 [M1][64] (41.9MB)
#define OFF_REG1  86749184UL   // 41943040
#define OFF_XCAT  128692224UL  // 16777216 xcat[M2][512] bf16
#define OFF_RAWMAX 145469440UL // 16777216 f32 [16384][<=256]
#define OFF_RAWMIN 162246656UL // 16777216
#define OFF_SP     179023872UL // 2097152  f32 partials [<=4096 blocks][128]
#define WS_NEEDED  181121024UL

// ---------------- helpers ----------------
__device__ __forceinline__ float bf2f(unsigned short u) {
    union { unsigned int i; float f; } c; c.i = ((unsigned int)u) << 16; return c.f;
}
__device__ __forceinline__ unsigned short f2bf(float f) {
    union { float f; unsigned int i; } c; c.f = f;
    unsigned int x = c.i;
    unsigned int r = (x + 0x7fffu + ((x >> 16) & 1u)) >> 16;  // RNE
    return (unsigned short)r;
}
__device__ __forceinline__ unsigned int pack2(float a, float b) {
    return (unsigned int)f2bf(a) | ((unsigned int)f2bf(b) << 16);
}
__device__ __forceinline__ void unpack8(uint4 u, float* v) {
    v[0] = bf2f((unsigned short)(u.x & 0xffffu)); v[1] = bf2f((unsigned short)(u.x >> 16));
    v[2] = bf2f((unsigned short)(u.y & 0xffffu)); v[3] = bf2f((unsigned short)(u.y >> 16));
    v[4] = bf2f((unsigned short)(u.z & 0xffffu)); v[5] = bf2f((unsigned short)(u.z >> 16));
    v[6] = bf2f((unsigned short)(u.w & 0xffffu)); v[7] = bf2f((unsigned short)(u.w >> 16));
}

// ---------------- prep: transpose x, compute xx ----------------
__global__ void prep_k(const float* __restrict__ x, float* __restrict__ xt, float* __restrict__ xx) {
    int t = blockIdx.x * 256 + threadIdx.x;   // 16384
    int b = t >> 11, n = t & 2047;
    float v0 = x[((size_t)b * 3 + 0) * NPTS + n];
    float v1 = x[((size_t)b * 3 + 1) * NPTS + n];
    float v2 = x[((size_t)b * 3 + 2) * NPTS + n];
    xt[(size_t)t * 3 + 0] = v0; xt[(size_t)t * 3 + 1] = v1; xt[(size_t)t * 3 + 2] = v2;
    xx[t] = __fadd_rn(__fadd_rn(__fmul_rn(v0, v0), __fmul_rn(v1, v1)), __fmul_rn(v2, v2));
}

// ---------------- weight split: fp32 -> bf16 hi + bf16 lo ----------------
__global__ void wsplit_k(const float* __restrict__ w, ushort_t* __restrict__ hi,
                         ushort_t* __restrict__ lo, int n) {
    int t = blockIdx.x * 256 + threadIdx.x;
    if (t < n) {
        float f = w[t];
        ushort_t h = f2bf(f);
        hi[t] = h;
        lo[t] = f2bf(f - bf2f(h));
    }
}

// ---------------- knn: 2 points per wave, tournament selection ----------------
// Two independent selection chains per wave interleave -> fills the butterfly
// latency bubbles (r9: VALUBusy 58%, serial chain bound). Neighbor loads shared.
template<int G>
__device__ __forceinline__ void knn_rescan(float (&v)[32], float (&gm)[4], int (&gq)[4],
                                           bool own, int qw) {
#pragma unroll
    for (int q = G * 8; q < G * 8 + 8; q++)
        if (own && q == qw) v[q] = -3.4e38f;
    float m = v[G * 8]; int qi = G * 8;
#pragma unroll
    for (int q = G * 8 + 1; q < G * 8 + 8; q++)
        if (v[q] > m) { m = v[q]; qi = q; }
    gm[G] = m; gq[G] = qi;
}

__device__ __forceinline__ void knn_round(float (&v)[32], float (&gm)[4], int (&gq)[4],
                                          int* __restrict__ out, int t, int l) {
    float bv = gm[0]; int bq = gq[0];
    if (gm[1] > bv) { bv = gm[1]; bq = gq[1]; }
    if (gm[2] > bv) { bv = gm[2]; bq = gq[2]; }
    if (gm[3] > bv) { bv = gm[3]; bq = gq[3]; }
    int bj = l + bq * 64;
#pragma unroll
    for (int off = 1; off < 64; off <<= 1) {
        float ov = __shfl_xor(bv, off);
        int   oj = __shfl_xor(bj, off);
        if (ov > bv || (ov == bv && oj < bj)) { bv = ov; bj = oj; }
    }
    int bju = __builtin_amdgcn_readfirstlane(bj);  // winner identical in all lanes
    if (l == 0) out[t] = bju;
    int qw = bju >> 6;                  // scalar slot
    bool own = (l == (bju & 63));
    int gw = qw >> 3;                   // scalar group -> uniform branch
    if (gw == 0)      knn_rescan<0>(v, gm, gq, own, qw);
    else if (gw == 1) knn_rescan<1>(v, gm, gq, own, qw);
    else if (gw == 2) knn_rescan<2>(v, gm, gq, own, qw);
    else              knn_rescan<3>(v, gm, gq, own, qw);
}

__launch_bounds__(256)
__global__ void knn_k(const float* __restrict__ xt, const float* __restrict__ xx, int* __restrict__ idx) {
    int tid = threadIdx.x;
    int l = tid & 63, wv = tid >> 6;
    int pidA = blockIdx.x * 8 + wv * 2;   // 2048 blocks x 4 waves x 2 points
    int pidB = pidA + 1;                  // same batch (8 | 2048)
    int b = pidA >> 11;
    const float* xb  = xt + (size_t)b * NPTS * 3;
    const float* xxb = xx + (size_t)b * NPTS;
    int iA = pidA & 2047, iB = pidB & 2047;
    float xA0 = xb[iA * 3 + 0], xA1 = xb[iA * 3 + 1], xA2 = xb[iA * 3 + 2];
    float xB0 = xb[iB * 3 + 0], xB1 = xb[iB * 3 + 1], xB2 = xb[iB * 3 + 2];
    float xxA = xxb[iA], xxB = xxb[iB];
    float vA[32], vB[32];
#pragma unroll
    for (int q = 0; q < 32; q++) {
        int j = l + q * 64;
        float p0 = xb[j * 3 + 0], p1 = xb[j * 3 + 1], p2 = xb[j * 3 + 2];
        float xxj = xxb[j];
        float dA = __fadd_rn(__fadd_rn(__fmul_rn(xA0, p0), __fmul_rn(xA1, p1)), __fmul_rn(xA2, p2));
        float dB = __fadd_rn(__fadd_rn(__fmul_rn(xB0, p0), __fmul_rn(xB1, p1)), __fmul_rn(xB2, p2));
        vA[q] = __fsub_rn(__fsub_rn(-xxA, __fmul_rn(-2.0f, dA)), xxj);
        vB[q] = __fsub_rn(__fsub_rn(-xxB, __fmul_rn(-2.0f, dB)), xxj);
    }
    float gmA[4], gmB[4]; int gqA[4], gqB[4];
#pragma unroll
    for (int g = 0; g < 4; g++) {
        float mA = vA[g * 8]; int qA = g * 8;
        float mB = vB[g * 8]; int qB = g * 8;
#pragma unroll
        for (int q = g * 8 + 1; q < g * 8 + 8; q++) {
            if (vA[q] > mA) { mA = vA[q]; qA = q; }
            if (vB[q] > mB) { mB = vB[q]; qB = q; }
        }
        gmA[g] = mA; gqA[g] = qA;
        gmB[g] = mB; gqB[g] = qB;
    }
    int* outA = idx + (size_t)pidA * KNN;
    int* outB = idx + (size_t)pidB * KNN;
    for (int t = 0; t < KNN; t++) {
        knn_round(vA, gmA, gqA, outA, t, l);
        knn_round(vB, gmB, gqB, outB, t, l);
    }
}

// ---------------- conv1: graph feature (6ch) x w1(64x6) -> y1 NHWC [m][64] bf16 ----------------
__launch_bounds__(256)
__global__ void conv1_k(const float* __restrict__ xt, const int* __restrict__ idx,
                        const float* __restrict__ w1, ushort_t* __restrict__ y1) {
    __shared__ float w[384];
    int tid = threadIdx.x;
    for (int t = tid; t < 384; t += 256) w[t] = w1[t];
    __syncthreads();
    int m = blockIdx.x * 256 + tid;        // < M1; idx flat index == m
    int nb = m / KNN;                      // b*N + n
    int b = nb >> 11;
    int j = idx[m];
    const float* pi = xt + (size_t)nb * 3;
    const float* pj = xt + ((size_t)(b * NPTS + j)) * 3;
    float f0 = pj[0] - pi[0], f1 = pj[1] - pi[1], f2 = pj[2] - pi[2];
    float f3 = pi[0], f4 = pi[1], f5 = pi[2];
#pragma unroll
    for (int o8 = 0; o8 < 8; o8++) {
        uint4 u;
        unsigned int* up = (unsigned int*)&u;
#pragma unroll
        for (int e2 = 0; e2 < 4; e2++) {
            const float* wa = w + (o8 * 8 + e2 * 2) * 6;
            const float* wb = wa + 6;
            float r0 = wa[0]*f0 + wa[1]*f1 + wa[2]*f2 + wa[3]*f3 + wa[4]*f4 + wa[5]*f5;
            float r1 = wb[0]*f0 + wb[1]*f1 + wb[2]*f2 + wb[3]*f3 + wb[4]*f4 + wb[5]*f5;
            up[e2] = pack2(r0, r1);
        }
        *(uint4*)(y1 + (size_t)m * 64 + o8 * 8) = u;
    }
}

// ---------------- generic MFMA conv (layer 5) ----------------
// Grid: x = o-tile (fastest-varying -> consecutive blocks share the activation
// tile in L2), y = m-tile.
template<int CIN, int COUT, bool BN>
__launch_bounds__(256)
__global__ void conv_mfma_k(const ushort_t* __restrict__ yin,
                            const ushort_t* __restrict__ whi,
                            const ushort_t* __restrict__ wlo,
                            const float* __restrict__ scale,
                            const float* __restrict__ shift,
                            ushort_t* __restrict__ yout) {
    constexpr int SMEM = 28672 + (BN ? CIN * 8 : 0);
    __shared__ char smem[SMEM];
    ushort_t* hA = (ushort_t*)smem;             // [128][56]
    ushort_t* wH = (ushort_t*)(smem + 14336);   // [64][56]
    ushort_t* wL = (ushort_t*)(smem + 21504);   // [64][56]
    float* scl = (float*)(smem + 28672);
    float* shf = scl + CIN;
    const int tid = threadIdx.x;
    const int m0 = blockIdx.y * 128;
    const int o0 = blockIdx.x * 64;
    if constexpr (BN) {
        for (int c = tid; c < CIN; c += 256) { scl[c] = scale[c]; shf[c] = shift[c]; }
    }
    f32x4 acc[2][4];
#pragma unroll
    for (int mt = 0; mt < 2; mt++)
#pragma unroll
        for (int ot = 0; ot < 4; ot++) acc[mt][ot] = (f32x4){0.f, 0.f, 0.f, 0.f};
    const int lane = tid & 63, wv = tid >> 6;
    const int l15 = lane & 15, quad = lane >> 4;
    for (int kc = 0; kc < CIN; kc += 32) {
        __syncthreads();
#pragma unroll
        for (int i = 0; i < 2; i++) {
            int tt = tid + 256 * i;
            int mr = tt >> 2, cq = (tt & 3) * 8;
            uint4 u = *(const uint4*)(yin + (size_t)(m0 + mr) * CIN + kc + cq);
            if constexpr (BN) {
                float vv[8]; unpack8(u, vv);
#pragma unroll
                for (int e = 0; e < 8; e++)
                    vv[e] = fmaxf(fmaf(vv[e], scl[kc + cq + e], shf[kc + cq + e]), 0.0f);
                u.x = pack2(vv[0], vv[1]); u.y = pack2(vv[2], vv[3]);
                u.z = pack2(vv[4], vv[5]); u.w = pack2(vv[6], vv[7]);
            }
            *(uint4*)&hA[mr * 56 + cq] = u;
        }
        {
            int orow = tid >> 2, cq = (tid & 3) * 8;
            *(uint4*)&wH[orow * 56 + cq] = *(const uint4*)(whi + (size_t)(o0 + orow) * CIN + kc + cq);
            *(uint4*)&wL[orow * 56 + cq] = *(const uint4*)(wlo + (size_t)(o0 + orow) * CIN + kc + cq);
        }
        __syncthreads();
        bf16x8 a0 = *(bf16x8*)&hA[(wv * 32 + l15) * 56 + quad * 8];
        bf16x8 a1 = *(bf16x8*)&hA[(wv * 32 + 16 + l15) * 56 + quad * 8];
#pragma unroll
        for (int ot = 0; ot < 4; ot++) {
            bf16x8 bh = *(bf16x8*)&wH[(ot * 16 + l15) * 56 + quad * 8];
            bf16x8 bl = *(bf16x8*)&wL[(ot * 16 + l15) * 56 + quad * 8];
            acc[0][ot] = __builtin_amdgcn_mfma_f32_16x16x32_bf16(a0, bh, acc[0][ot], 0, 0, 0);
            acc[0][ot] = __builtin_amdgcn_mfma_f32_16x16x32_bf16(a0, bl, acc[0][ot], 0, 0, 0);
            acc[1][ot] = __builtin_amdgcn_mfma_f32_16x16x32_bf16(a1, bh, acc[1][ot], 0, 0, 0);
            acc[1][ot] = __builtin_amdgcn_mfma_f32_16x16x32_bf16(a1, bl, acc[1][ot], 0, 0, 0);
        }
    }
    __syncthreads();
    ushort_t* outT = (ushort_t*)smem;   // [128][72]
#pragma unroll
    for (int mt = 0; mt < 2; mt++)
#pragma unroll
        for (int ot = 0; ot < 4; ot++)
#pragma unroll
            for (int r = 0; r < 4; r++)
                outT[(wv * 32 + mt * 16 + quad * 4 + r) * 72 + ot * 16 + l15] = f2bf(acc[mt][ot][r]);
    __syncthreads();
    int row = tid >> 1, half = tid & 1;
#pragma unroll
    for (int g = 0; g < 4; g++) {
        uint4 u = *(uint4*)&outT[row * 72 + half * 32 + g * 8];
        *(uint4*)(yout + (size_t)(m0 + row) * COUT + o0 + half * 32 + g * 8) = u;
    }
}

// ---------------- fused conv (layers 2,3,4): 320m (16 k-windows) x 64o tiles.
// Grid: x = o-tile (fastest -> blocks sharing an m-tile are adjacent -> L2 reuse),
// y = m-tile (1024). Epilogue: raw max/min per k-window + per-block f32 stats
// partials; optional y write.
// LESSONS: (r5/r6) runtime acc index -> scratch demotion (1.67GB phantom traffic):
// keep all acc indexing static (full unroll). (r7) cross-lane LDS round-trip needs
// __syncthreads() between write and read phases.
template<int CIN, int COUT, bool WRITEY>
__launch_bounds__(256, 2)
__global__ void conv_fused_k(const ushort_t* __restrict__ yin,
                             const ushort_t* __restrict__ whi,
                             const ushort_t* __restrict__ wlo,
                             const float* __restrict__ scale,
                             const float* __restrict__ shift,
                             ushort_t* __restrict__ yout,
                             float* __restrict__ rawmax, float* __restrict__ rawmin,
                             float* __restrict__ sp) {
    __shared__ char smem[53248];
    ushort_t* hA = (ushort_t*)smem;             // [320][56] = 35840
    ushort_t* wH = (ushort_t*)(smem + 35840);   // [64][56]  = 7168
    ushort_t* wL = (ushort_t*)(smem + 43008);   // [64][56]  = 7168
    float* scl = (float*)(smem + 50176);        // [<=128]
    float* shf = (float*)(smem + 50688);        // [<=128]
    float* sw  = (float*)(smem + 51200);        // [4][64][2]
    const int tid = threadIdx.x;
    const int m0 = blockIdx.y * 320;            // 1024 m-tiles
    const int o0 = blockIdx.x * 64;
    for (int c = tid; c < CIN; c += 256) { scl[c] = scale[c]; shf[c] = shift[c]; }
    for (int i = tid; i < 512; i += 256) sw[i] = 0.0f;
    f32x4 acc[5][4];
#pragma unroll
    for (int mt = 0; mt < 5; mt++)
#pragma unroll
        for (int ot = 0; ot < 4; ot++) acc[mt][ot] = (f32x4){0.f, 0.f, 0.f, 0.f};
    const int lane = tid & 63, wv = tid >> 6;
    const int l15 = lane & 15, quad = lane >> 4;
    for (int kc = 0; kc < CIN; kc += 32) {
        __syncthreads();
        // stage activations: 320 rows x 32c (BN+ReLU applied)
#pragma unroll
        for (int i = 0; i < 5; i++) {
            int tt = tid + 256 * i;
            int mr = tt >> 2, cq = (tt & 3) * 8;
            uint4 u = *(const uint4*)(yin + (size_t)(m0 + mr) * CIN + kc + cq);
            float vv[8]; unpack8(u, vv);
#pragma unroll
            for (int e = 0; e < 8; e++)
                vv[e] = fmaxf(fmaf(vv[e], scl[kc + cq + e], shf[kc + cq + e]), 0.0f);
            u.x = pack2(vv[0], vv[1]); u.y = pack2(vv[2], vv[3]);
            u.z = pack2(vv[4], vv[5]); u.w = pack2(vv[6], vv[7]);
            *(uint4*)&hA[mr * 56 + cq] = u;
        }
        // stage weights hi/lo: 64 rows x 32c
        {
            int row = tid >> 2, cq = (tid & 3) * 8;
            *(uint4*)&wH[row * 56 + cq] = *(const uint4*)(whi + (size_t)(o0 + row) * CIN + kc + cq);
            *(uint4*)&wL[row * 56 + cq] = *(const uint4*)(wlo + (size_t)(o0 + row) * CIN + kc + cq);
        }
        __syncthreads();
        bf16x8 a[5];
#pragma unroll
        for (int mt = 0; mt < 5; mt++)
            a[mt] = *(bf16x8*)&hA[(wv * 80 + mt * 16 + l15) * 56 + quad * 8];
#pragma unroll
        for (int ot = 0; ot < 4; ot++) {
            bf16x8 bh = *(bf16x8*)&wH[(ot * 16 + l15) * 56 + quad * 8];
            bf16x8 bl = *(bf16x8*)&wL[(ot * 16 + l15) * 56 + quad * 8];
#pragma unroll
            for (int mt = 0; mt < 5; mt++) {
                acc[mt][ot] = __builtin_amdgcn_mfma_f32_16x16x32_bf16(a[mt], bh, acc[mt][ot], 0, 0, 0);
                acc[mt][ot] = __builtin_amdgcn_mfma_f32_16x16x32_bf16(a[mt], bl, acc[mt][ot], 0, 0, 0);
            }
        }
    }
    __syncthreads();   // waves may still read hA/wH/wL; wreg below overlays hA
    // epilogue: per wave, 80m x 16o f32 scratch ([80][20]: 80B rows, 16B aligned)
    float* wreg = (float*)(smem + wv * 6400);
#pragma unroll
    for (int ot = 0; ot < 4; ot++) {
#pragma unroll
        for (int mt = 0; mt < 5; mt++)
#pragma unroll
            for (int r = 0; r < 4; r++)
                wreg[(mt * 16 + quad * 4 + r) * 20 + l15] = acc[mt][ot][r];
        __syncthreads();   // cross-lane round-trip (r7 lesson)
        {
            int pp = quad;                      // 4 points per wave (80m = 4x20)
            const float* rr = wreg + (pp * 20) * 20 + l15;
            float mx = rr[0], mn = rr[0], sm = 0.0f, ss = 0.0f;
#pragma unroll
            for (int q = 0; q < 20; q++) {
                float vv = rr[q * 20];
                mx = fmaxf(mx, vv); mn = fminf(mn, vv);
                sm += vv; ss = fmaf(vv, vv, ss);
            }
            int pt = blockIdx.y * 16 + wv * 4 + pp;
            int o = o0 + ot * 16 + l15;
            rawmax[(size_t)pt * COUT + o] = mx;
            rawmin[(size_t)pt * COUT + o] = mn;
            sm += __shfl_xor(sm, 16); sm += __shfl_xor(sm, 32);
            ss += __shfl_xor(ss, 16); ss += __shfl_xor(ss, 32);
            if (lane < 16) {
                sw[(wv * 64 + ot * 16 + l15) * 2 + 0] += sm;
                sw[(wv * 64 + ot * 16 + l15) * 2 + 1] += ss;
            }
        }
        if constexpr (WRITEY) {
            // 80 rows x 16 o's = 160 chunks of 8 bf16 (16B stores)
#pragma unroll
            for (int it = 0; it < 3; it++) {
                int t = lane + it * 64;
                if (t < 160) {
                    int row = t >> 1, half = t & 1;
                    float4 f0 = *(float4*)&wreg[row * 20 + half * 8];
                    float4 f1 = *(float4*)&wreg[row * 20 + half * 8 + 4];
                    uint4 u;
                    u.x = pack2(f0.x, f0.y); u.y = pack2(f0.z, f0.w);
                    u.z = pack2(f1.x, f1.y); u.w = pack2(f1.z, f1.w);
                    *(uint4*)(yout + (size_t)(m0 + wv * 80 + row) * COUT + o0 + ot * 16 + half * 8) = u;
                }
            }
        }
        __syncthreads();   // reads done before next ot overwrites wreg
    }
    if (tid < 128) {
        int ol = tid >> 1, st = tid & 1;
        float v = 0.0f;
#pragma unroll
        for (int w2 = 0; w2 < 4; w2++) v += sw[(w2 * 64 + ol) * 2 + st];
        size_t bid = (size_t)blockIdx.x * 1024 + blockIdx.y;   // o-major, matches stats4red
        sp[bid * 128 + ol * 2 + st] = v;
    }
}

// ---------------- reduce fused-conv stat partials -> sum/sumsq doubles ----------------
__launch_bounds__(256)
__global__ void stats4red_k(const float* __restrict__ sp, double* __restrict__ sum,
                            double* __restrict__ sumsq) {
    __shared__ double rs[256], rss[256];
    int o = blockIdx.x, tid = threadIdx.x;
    int oy = o >> 6, ol = o & 63;
    double s = 0.0, ss = 0.0;
    for (int mb = tid; mb < 1024; mb += 256) {
        size_t bid = (size_t)oy * 1024 + mb;
        s  += (double)sp[bid * 128 + ol * 2 + 0];
        ss += (double)sp[bid * 128 + ol * 2 + 1];
    }
    rs[tid] = s; rss[tid] = ss;
    __syncthreads();
    for (int st = 128; st; st >>= 1) {
        if (tid < st) { rs[tid] += rs[tid + st]; rss[tid] += rss[tid + st]; }
        __syncthreads();
    }
    if (tid == 0) { sum[o] = rs[0]; sumsq[o] = rss[0]; }
}

// ---------------- per-channel sum/sumsq over NHWC y (layers 1,5) ----------------
template<int C8>
__launch_bounds__(256)
__global__ void stats_nhwc_k(const ushort_t* __restrict__ y, double* __restrict__ sum,
                             double* __restrict__ sumsq, int rpb) {
    constexpr int C = C8 * 8;
    constexpr int STRIDE = 256 / C8;
    __shared__ float ls[C][2];
    int tid = threadIdx.x;
    for (int i = tid; i < C * 2; i += 256) ((float*)ls)[i] = 0.0f;
    int cg = tid % C8, mr = tid / C8;
    size_t r0 = (size_t)blockIdx.x * rpb;
    float s[8], ss[8];
#pragma unroll
    for (int e = 0; e < 8; e++) { s[e] = 0.0f; ss[e] = 0.0f; }
    for (int r = mr; r < rpb; r += STRIDE) {
        uint4 u = *(const uint4*)(y + (r0 + r) * C + cg * 8);
        float vv[8]; unpack8(u, vv);
#pragma unroll
        for (int e = 0; e < 8; e++) { s[e] += vv[e]; ss[e] = fmaf(vv[e], vv[e], ss[e]); }
    }
    __syncthreads();
#pragma unroll
    for (int e = 0; e < 8; e++) {
        atomicAdd(&ls[cg * 8 + e][0], s[e]);
        atomicAdd(&ls[cg * 8 + e][1], ss[e]);
    }
    __syncthreads();
    // strided (C can exceed blockDim; round-4 bug)
    for (int c = tid; c < C; c += 256) {
        atomicAdd(&sum[c], (double)ls[c][0]);
        atomicAdd(&sumsq[c], (double)ls[c][1]);
    }
}

// ---------------- finalize BN ----------------
__global__ void fin_k(const double* __restrict__ sum, const double* __restrict__ sumsq,
                      const float* __restrict__ g, const float* __restrict__ bb,
                      float* __restrict__ scale, float* __restrict__ shift, int C, double invcnt) {
    int c = blockIdx.x * blockDim.x + threadIdx.x;
    if (c < C) {
        double m = sum[c] * invcnt;
        double v = sumsq[c] * invcnt - m * m;
        if (v < 0.0) v = 0.0;
        float sc = g[c] / sqrtf((float)v + 1e-5f);
        scale[c] = sc;
        shift[c] = bb[c] - (float)m * sc;
    }
}

// ---------------- maxpool over k (BN+ReLU) NHWC -> xcat (layer 1) ----------------
template<int C8>
__launch_bounds__(256)
__global__ void maxpool_nhwc_k(const ushort_t* __restrict__ y, const float* __restrict__ scale,
                               const float* __restrict__ shift, ushort_t* __restrict__ xcat,
                               int coff) {
    constexpr int C = C8 * 8;
    constexpr int PB = 256 / C8;
    int tid = threadIdx.x;
    int cg = tid % C8, pl = tid / C8;
    int p = blockIdx.x * PB + pl;
    float sc[8], sh[8];
    *(float4*)&sc[0] = *(const float4*)(scale + cg * 8);
    *(float4*)&sc[4] = *(const float4*)(scale + cg * 8 + 4);
    *(float4*)&sh[0] = *(const float4*)(shift + cg * 8);
    *(float4*)&sh[4] = *(const float4*)(shift + cg * 8 + 4);
    float mx[8];
#pragma unroll
    for (int e = 0; e < 8; e++) mx[e] = 0.0f;   // relu floor
    size_t base = (size_t)p * KNN * C + cg * 8;
#pragma unroll
    for (int q = 0; q < KNN; q++) {
        uint4 u = *(const uint4*)(y + base + (size_t)q * C);
        float vv[8]; unpack8(u, vv);
#pragma unroll
        for (int e = 0; e < 8; e++) mx[e] = fmaxf(mx[e], fmaf(vv[e], sc[e], sh[e]));
    }
    uint4 u;
    u.x = pack2(mx[0], mx[1]); u.y = pack2(mx[2], mx[3]);
    u.z = pack2(mx[4], mx[5]); u.w = pack2(mx[6], mx[7]);
    *(uint4*)(xcat + (size_t)p * 512 + coff + cg * 8) = u;
}

// ---------------- pool finalize from raw max/min (BN monotone) -> xcat (layers 2,3,4) ----------------
template<int C8>
__launch_bounds__(256)
__global__ void pool_raw_k(const float* __restrict__ rawmax, const float* __restrict__ rawmin,
                           const float* __restrict__ scale, const float* __restrict__ shift,
                           ushort_t* __restrict__ xcat, int coff) {
    constexpr int COUT = C8 * 8;
    int gid = blockIdx.x * 256 + threadIdx.x;   // 16384 * C8
    int p = gid / C8, og = gid % C8;
    float sc[8], sh[8], mxv[8], mnv[8];
    *(float4*)&sc[0]  = *(const float4*)(scale + og * 8);
    *(float4*)&sc[4]  = *(const float4*)(scale + og * 8 + 4);
    *(float4*)&sh[0]  = *(const float4*)(shift + og * 8);
    *(float4*)&sh[4]  = *(const float4*)(shift + og * 8 + 4);
    *(float4*)&mxv[0] = *(const float4*)(rawmax + (size_t)p * COUT + og * 8);
    *(float4*)&mxv[4] = *(const float4*)(rawmax + (size_t)p * COUT + og * 8 + 4);
    *(float4*)&mnv[0] = *(const float4*)(rawmin + (size_t)p * COUT + og * 8);
    *(float4*)&mnv[4] = *(const float4*)(rawmin + (size_t)p * COUT + og * 8 + 4);
    float v[8];
#pragma unroll
    for (int e = 0; e < 8; e++) {
        float raw = (sc[e] >= 0.0f) ? mxv[e] : mnv[e];
        v[e] = fmaxf(fmaf(raw, sc[e], sh[e]), 0.0f);
    }
    uint4 u;
    u.x = pack2(v[0], v[1]); u.y = pack2(v[2], v[3]);
    u.z = pack2(v[4], v[5]); u.w = pack2(v[6], v[7]);
    *(uint4*)(xcat + (size_t)p * 512 + coff + og * 8) = u;
}

// ---------------- output: BN5+ReLU + transpose NHWC -> [b][c][n] fp32 ----------------
__launch_bounds__(256)
__global__ void out_k(const ushort_t* __restrict__ y5, const float* __restrict__ scale,
                      const float* __restrict__ shift, float* __restrict__ out) {
    __shared__ float tr[64 * 65];
    int tid = threadIdx.x;
    int n0 = blockIdx.x * 64, c0 = blockIdx.y * 64, b = blockIdx.z;
    int nl = tid >> 2, cq = (tid & 3) * 16;
    const ushort_t* src = y5 + (size_t)(b * 2048 + n0 + nl) * 512 + c0 + cq;
#pragma unroll
    for (int h = 0; h < 2; h++) {
        uint4 u = *(const uint4*)(src + h * 8);
        float vv[8]; unpack8(u, vv);
#pragma unroll
        for (int e = 0; e < 8; e++) {
            int c = cq + h * 8 + e;
            tr[c * 65 + nl] = fmaxf(fmaf(vv[e], scale[c0 + c], shift[c0 + c]), 0.0f);
        }
    }
    __syncthreads();
    int cl = tid >> 2, ng = (tid & 3) * 16;
#pragma unroll
    for (int g = 0; g < 4; g++) {
        float4 v = *(float4*)&tr[cl * 65 + ng + g * 4];
        *(float4*)(out + ((size_t)b * 512 + c0 + cl) * 2048 + n0 + ng + g * 4) = v;
    }
}

// ---------------- host ----------------
extern "C" void kernel_launch(void* const* d_in, const int* in_sizes, int n_in,
                              void* d_out, int out_size, void* d_ws, size_t ws_size,
                              hipStream_t stream) {
    (void)in_sizes; (void)n_in; (void)out_size;
    if (ws_size < WS_NEEDED) return;
    const float* x  = (const float*)d_in[0];
    const float* w1 = (const float*)d_in[1];
    const float* g1 = (const float*)d_in[2];
    const float* b1 = (const float*)d_in[3];
    const float* w2 = (const float*)d_in[4];
    const float* g2 = (const float*)d_in[5];
    const float* b2 = (const float*)d_in[6];
    const float* w3 = (const float*)d_in[7];
    const float* g3 = (const float*)d_in[8];
    const float* b3 = (const float*)d_in[9];
    const float* w4 = (const float*)d_in[10];
    const float* g4 = (const float*)d_in[11];
    const float* b4 = (const float*)d_in[12];
    const float* w5 = (const float*)d_in[13];
    const float* g5 = (const float*)d_in[14];
    const float* b5 = (const float*)d_in[15];

    char* ws = (char*)d_ws;
    float* xt  = (float*)(ws + OFF_XT);
    float* xx  = (float*)(ws + OFF_XX);
    int*   idx = (int*)(ws + OFF_IDX);
    ushort_t* wh2 = (ushort_t*)(ws + OFF_WH2); ushort_t* wl2 = (ushort_t*)(ws + OFF_WL2);
    ushort_t* wh3 = (ushort_t*)(ws + OFF_WH3); ushort_t* wl3 = (ushort_t*)(ws + OFF_WL3);
    ushort_t* wh4 = (ushort_t*)(ws + OFF_WH4); ushort_t* wl4 = (ushort_t*)(ws + OFF_WL4);
    ushort_t* wh5 = (ushort_t*)(ws + OFF_WH5); ushort_t* wl5 = (ushort_t*)(ws + OFF_WL5);
    ushort_t* y1 = (ushort_t*)(ws + OFF_REG0);
    ushort_t* y2 = (ushort_t*)(ws + OFF_REG1);
    ushort_t* y3 = (ushort_t*)(ws + OFF_REG0);
    ushort_t* y5 = (ushort_t*)(ws + OFF_REG0);
    ushort_t* xcat = (ushort_t*)(ws + OFF_XCAT);
    float* rawmax = (float*)(ws + OFF_RAWMAX);
    float* rawmin = (float*)(ws + OFF_RAWMIN);
    float* sp     = (float*)(ws + OFF_SP);

    double* sum[5]; double* sumsq[5]; float* scl[5]; float* shf[5];
    for (int l = 0; l < 5; l++) {
        sum[l]   = (double*)(ws + OFF_STATS + (size_t)l * 8192);
        sumsq[l] = sum[l] + 512;
        scl[l]   = (float*)(ws + OFF_SS + (size_t)l * 4096);
        shf[l]   = scl[l] + 512;
    }

    hipMemsetAsync(ws + OFF_STATS, 0, 40960, stream);
    prep_k<<<64, 256, 0, stream>>>(x, xt, xx);
    wsplit_k<<<16,   256, 0, stream>>>(w2, wh2, wl2, 4096);
    wsplit_k<<<32,   256, 0, stream>>>(w3, wh3, wl3, 8192);
    wsplit_k<<<128,  256, 0, stream>>>(w4, wh4, wl4, 32768);
    wsplit_k<<<1024, 256, 0, stream>>>(w5, wh5, wl5, 262144);
    knn_k<<<2048, 256, 0, stream>>>(xt, xx, idx);

    // layer 1
    conv1_k<<<1280, 256, 0, stream>>>(xt, idx, w1, y1);
    stats_nhwc_k<8><<<160, 256, 0, stream>>>(y1, sum[0], sumsq[0], 2048);
    fin_k<<<1, 512, 0, stream>>>(sum[0], sumsq[0], g1, b1, scl[0], shf[0], 64, 1.0 / 327680.0);
    maxpool_nhwc_k<8><<<512, 256, 0, stream>>>(y1, scl[0], shf[0], xcat, 0);

    // layer 2: 64 -> 64 fused (y2 + rawmax/min + stats partials)
    conv_fused_k<64, 64, true><<<dim3(1, 1024), 256, 0, stream>>>(
        y1, wh2, wl2, scl[0], shf[0], y2, rawmax, rawmin, sp);
    stats4red_k<<<64, 256, 0, stream>>>(sp, sum[1], sumsq[1]);
    fin_k<<<1, 512, 0, stream>>>(sum[1], sumsq[1], g2, b2, scl[1], shf[1], 64, 1.0 / 327680.0);
    pool_raw_k<8><<<512, 256, 0, stream>>>(rawmax, rawmin, scl[1], shf[1], xcat, 64);

    // layer 3: 64 -> 128 fused
    conv_fused_k<64, 128, true><<<dim3(2, 1024), 256, 0, stream>>>(
        y2, wh3, wl3, scl[1], shf[1], y3, rawmax, rawmin, sp);
    stats4red_k<<<128, 256, 0, stream>>>(sp, sum[2], sumsq[2]);
    fin_k<<<1, 512, 0, stream>>>(sum[2], sumsq[2], g3, b3, scl[2], shf[2], 128, 1.0 / 327680.0);
    pool_raw_k<16><<<1024, 256, 0, stream>>>(rawmax, rawmin, scl[2], shf[2], xcat, 128);

    // layer 4: 128 -> 256 fused (no y4)
    conv_fused_k<128, 256, false><<<dim3(4, 1024), 256, 0, stream>>>(
        y3, wh4, wl4, scl[2], shf[2], nullptr, rawmax, rawmin, sp);
    stats4red_k<<<256, 256, 0, stream>>>(sp, sum[3], sumsq[3]);
    fin_k<<<1, 512, 0, stream>>>(sum[3], sumsq[3], g4, b4, scl[3], shf[3], 256, 1.0 / 327680.0);
    pool_raw_k<32><<<2048, 256, 0, stream>>>(rawmax, rawmin, scl[3], shf[3], xcat, 256);

    // layer 5: 512 -> 512 (input already activated)
    conv_mfma_k<512, 512, false><<<dim3(8, 128), 256, 0, stream>>>(xcat, wh5, wl5,
                                                                   nullptr, nullptr, y5);
    stats_nhwc_k<64><<<128, 256, 0, stream>>>(y5, sum[4], sumsq[4], 128);
    fin_k<<<1, 512, 0, stream>>>(sum[4], sumsq[4], g5, b5, scl[4], shf[4], 512, 1.0 / 16384.0);
    out_k<<<dim3(32, 8, 8), 256, 0, stream>>>(y5, scl[4], shf[4], (float*)d_out);
}

// Round 11
// 541.249 us; speedup vs baseline: 1.8306x; 1.0402x over previous
//
#include <hip/hip_runtime.h>
#include <cstdint>
#include <cstddef>

// ---------------- constants ----------------
#define BATCH 8
#define NPTS 2048
#define KNN 20
#define M1 327680   // BATCH*NPTS*KNN
#define M2 16384    // BATCH*NPTS

typedef unsigned short ushort_t;
typedef __attribute__((ext_vector_type(8))) short bf16x8;   // 8 bf16 = 4 VGPRs
typedef __attribute__((ext_vector_type(4))) float f32x4;    // MFMA acc

// ws layout (bytes) — total 181,121,024
#define OFF_XT    0UL          // 196608   float xt[b*n][3]
#define OFF_XX    196608UL     // 65536    float xx[b*n]
#define OFF_IDX   262144UL     // 1310720  int idx[b*n][20]
#define OFF_WH2   1572864UL    // 8192   bf16 [64][64]
#define OFF_WL2   1581056UL    // 8192
#define OFF_WH3   1589248UL    // 16384  bf16 [128][64]
#define OFF_WL3   1605632UL    // 16384
#define OFF_WH4   1622016UL    // 65536  bf16 [256][128]
#define OFF_WL4   1687552UL    // 65536
#define OFF_WH5   1753088UL    // 524288 bf16 [512][512]
#define OFF_WL5   2277376UL    // 524288
#define OFF_STATS 2801664UL    // 40960   5 x (512 sum + 512 sumsq) double (layers 1,5)
#define OFF_SS    2842624UL    // 20480   5 x (512 scale + 512 shift) float
// REG0: y1 [M1][64] (41.9MB) -> y3 [M1][128] (83.9MB) -> y5 [M2][512] (16.8MB)
#define OFF_REG0  2863104UL    // 83886080
// REG1: y2 [M1][64] (41.9MB)
#define OFF_REG1  86749184UL   // 41943040
#define OFF_XCAT  128692224UL  // 16777216 xcat[M2][512] bf16
#define OFF_RAWMAX 145469440UL // 16777216 f32 [16384][<=256]
#define OFF_RAWMIN 162246656UL // 16777216
#define OFF_SP     179023872UL // 2097152  f32 partials [<=2048 blocks][<=256]
#define WS_NEEDED  181121024UL

// ---------------- helpers ----------------
__device__ __forceinline__ float bf2f(unsigned short u) {
    union { unsigned int i; float f; } c; c.i = ((unsigned int)u) << 16; return c.f;
}
__device__ __forceinline__ unsigned short f2bf(float f) {
    union { float f; unsigned int i; } c; c.f = f;
    unsigned int x = c.i;
    unsigned int r = (x + 0x7fffu + ((x >> 16) & 1u)) >> 16;  // RNE
    return (unsigned short)r;
}
__device__ __forceinline__ unsigned int pack2(float a, float b) {
    return (unsigned int)f2bf(a) | ((unsigned int)f2bf(b) << 16);
}
__device__ __forceinline__ void unpack8(uint4 u, float* v) {
    v[0] = bf2f((unsigned short)(u.x & 0xffffu)); v[1] = bf2f((unsigned short)(u.x >> 16));
    v[2] = bf2f((unsigned short)(u.y & 0xffffu)); v[3] = bf2f((unsigned short)(u.y >> 16));
    v[4] = bf2f((unsigned short)(u.z & 0xffffu)); v[5] = bf2f((unsigned short)(u.z >> 16));
    v[6] = bf2f((unsigned short)(u.w & 0xffffu)); v[7] = bf2f((unsigned short)(u.w >> 16));
}

// ---------------- prep: transpose x, compute xx ----------------
__global__ void prep_k(const float* __restrict__ x, float* __restrict__ xt, float* __restrict__ xx) {
    int t = blockIdx.x * 256 + threadIdx.x;   // 16384
    int b = t >> 11, n = t & 2047;
    float v0 = x[((size_t)b * 3 + 0) * NPTS + n];
    float v1 = x[((size_t)b * 3 + 1) * NPTS + n];
    float v2 = x[((size_t)b * 3 + 2) * NPTS + n];
    xt[(size_t)t * 3 + 0] = v0; xt[(size_t)t * 3 + 1] = v1; xt[(size_t)t * 3 + 2] = v2;
    xx[t] = __fadd_rn(__fadd_rn(__fmul_rn(v0, v0), __fmul_rn(v1, v1)), __fmul_rn(v2, v2));
}

// ---------------- weight split (all 4 layers in one dispatch) ----------------
__global__ void wsplit_all_k(const float* __restrict__ w2, ushort_t* __restrict__ wh2, ushort_t* __restrict__ wl2,
                             const float* __restrict__ w3, ushort_t* __restrict__ wh3, ushort_t* __restrict__ wl3,
                             const float* __restrict__ w4, ushort_t* __restrict__ wh4, ushort_t* __restrict__ wl4,
                             const float* __restrict__ w5, ushort_t* __restrict__ wh5, ushort_t* __restrict__ wl5) {
    int t = blockIdx.x * 256 + threadIdx.x;   // 307200 total
    const float* w; ushort_t* hi; ushort_t* lo; int off;
    if (t < 4096)        { w = w2; hi = wh2; lo = wl2; off = t; }
    else if (t < 12288)  { w = w3; hi = wh3; lo = wl3; off = t - 4096; }
    else if (t < 45056)  { w = w4; hi = wh4; lo = wl4; off = t - 12288; }
    else                 { w = w5; hi = wh5; lo = wl5; off = t - 45056; }
    float f = w[off];
    ushort_t h = f2bf(f);
    hi[off] = h;
    lo[off] = f2bf(f - bf2f(h));
}

// ---------------- knn: 2 points per wave, tournament + short butterfly ----------------
// r10 lesson: 6-step butterfly's xor-16/xor-32 are ds_swizzle/ds_bpermute with lgkm
// waits on the serial chain. New: 4 xor steps (1,2,4,8 -> 16-lane groups converge),
// then resolve the 4 group winners via readlane(0/16/32/48) + uniform VALU tree.
template<int G>
__device__ __forceinline__ void knn_rescan(float (&v)[32], float (&gm)[4], int (&gq)[4],
                                           bool own, int qw) {
#pragma unroll
    for (int q = G * 8; q < G * 8 + 8; q++)
        if (own && q == qw) v[q] = -3.4e38f;
    float m = v[G * 8]; int qi = G * 8;
#pragma unroll
    for (int q = G * 8 + 1; q < G * 8 + 8; q++)
        if (v[q] > m) { m = v[q]; qi = q; }
    gm[G] = m; gq[G] = qi;
}

__device__ __forceinline__ void knn_round(float (&v)[32], float (&gm)[4], int (&gq)[4],
                                          int* __restrict__ out, int t, int l) {
    float bv = gm[0]; int bq = gq[0];
    if (gm[1] > bv) { bv = gm[1]; bq = gq[1]; }
    if (gm[2] > bv) { bv = gm[2]; bq = gq[2]; }
    if (gm[3] > bv) { bv = gm[3]; bq = gq[3]; }
    int bj = l + bq * 64;
#pragma unroll
    for (int off = 1; off <= 8; off <<= 1) {
        float ov = __shfl_xor(bv, off);
        int   oj = __shfl_xor(bj, off);
        if (ov > bv || (ov == bv && oj < bj)) { bv = ov; bj = oj; }
    }
    // each 16-lane group converged; resolve 4 candidates (uniform values)
    int ib = __float_as_int(bv);
    float w0 = __int_as_float(__builtin_amdgcn_readlane(ib, 0));
    float w1 = __int_as_float(__builtin_amdgcn_readlane(ib, 16));
    float w2 = __int_as_float(__builtin_amdgcn_readlane(ib, 32));
    float w3 = __int_as_float(__builtin_amdgcn_readlane(ib, 48));
    int u0 = __builtin_amdgcn_readlane(bj, 0);
    int u1 = __builtin_amdgcn_readlane(bj, 16);
    int u2 = __builtin_amdgcn_readlane(bj, 32);
    int u3 = __builtin_amdgcn_readlane(bj, 48);
    float Bv = w0; int Bj = u0;
    if (w1 > Bv || (w1 == Bv && u1 < Bj)) { Bv = w1; Bj = u1; }
    if (w2 > Bv || (w2 == Bv && u2 < Bj)) { Bv = w2; Bj = u2; }
    if (w3 > Bv || (w3 == Bv && u3 < Bj)) { Bv = w3; Bj = u3; }
    int bju = __builtin_amdgcn_readfirstlane(Bj);  // force scalar
    if (l == 0) out[t] = bju;
    int qw = bju >> 6;                  // scalar slot
    bool own = (l == (bju & 63));
    int gw = qw >> 3;                   // scalar group -> uniform branch
    if (gw == 0)      knn_rescan<0>(v, gm, gq, own, qw);
    else if (gw == 1) knn_rescan<1>(v, gm, gq, own, qw);
    else if (gw == 2) knn_rescan<2>(v, gm, gq, own, qw);
    else              knn_rescan<3>(v, gm, gq, own, qw);
}

__launch_bounds__(256)
__global__ void knn_k(const float* __restrict__ xt, const float* __restrict__ xx, int* __restrict__ idx) {
    int tid = threadIdx.x;
    int l = tid & 63, wv = tid >> 6;
    int pidA = blockIdx.x * 8 + wv * 2;   // 2048 blocks x 4 waves x 2 points
    int pidB = pidA + 1;
    int b = pidA >> 11;
    const float* xb  = xt + (size_t)b * NPTS * 3;
    const float* xxb = xx + (size_t)b * NPTS;
    int iA = pidA & 2047, iB = pidB & 2047;
    float xA0 = xb[iA * 3 + 0], xA1 = xb[iA * 3 + 1], xA2 = xb[iA * 3 + 2];
    float xB0 = xb[iB * 3 + 0], xB1 = xb[iB * 3 + 1], xB2 = xb[iB * 3 + 2];
    float xxA = xxb[iA], xxB = xxb[iB];
    float vA[32], vB[32];
#pragma unroll
    for (int q = 0; q < 32; q++) {
        int j = l + q * 64;
        float p0 = xb[j * 3 + 0], p1 = xb[j * 3 + 1], p2 = xb[j * 3 + 2];
        float xxj = xxb[j];
        float dA = __fadd_rn(__fadd_rn(__fmul_rn(xA0, p0), __fmul_rn(xA1, p1)), __fmul_rn(xA2, p2));
        float dB = __fadd_rn(__fadd_rn(__fmul_rn(xB0, p0), __fmul_rn(xB1, p1)), __fmul_rn(xB2, p2));
        vA[q] = __fsub_rn(__fsub_rn(-xxA, __fmul_rn(-2.0f, dA)), xxj);
        vB[q] = __fsub_rn(__fsub_rn(-xxB, __fmul_rn(-2.0f, dB)), xxj);
    }
    float gmA[4], gmB[4]; int gqA[4], gqB[4];
#pragma unroll
    for (int g = 0; g < 4; g++) {
        float mA = vA[g * 8]; int qA = g * 8;
        float mB = vB[g * 8]; int qB = g * 8;
#pragma unroll
        for (int q = g * 8 + 1; q < g * 8 + 8; q++) {
            if (vA[q] > mA) { mA = vA[q]; qA = q; }
            if (vB[q] > mB) { mB = vB[q]; qB = q; }
        }
        gmA[g] = mA; gqA[g] = qA;
        gmB[g] = mB; gqB[g] = qB;
    }
    int* outA = idx + (size_t)pidA * KNN;
    int* outB = idx + (size_t)pidB * KNN;
    for (int t = 0; t < KNN; t++) {
        knn_round(vA, gmA, gqA, outA, t, l);
        knn_round(vB, gmB, gqB, outB, t, l);
    }
}

// ---------------- conv1: graph feature (6ch) x w1(64x6) -> y1 NHWC [m][64] bf16 ----------------
__launch_bounds__(256)
__global__ void conv1_k(const float* __restrict__ xt, const int* __restrict__ idx,
                        const float* __restrict__ w1, ushort_t* __restrict__ y1) {
    __shared__ float w[384];
    int tid = threadIdx.x;
    for (int t = tid; t < 384; t += 256) w[t] = w1[t];
    __syncthreads();
    int m = blockIdx.x * 256 + tid;        // < M1; idx flat index == m
    int nb = m / KNN;                      // b*N + n
    int b = nb >> 11;
    int j = idx[m];
    const float* pi = xt + (size_t)nb * 3;
    const float* pj = xt + ((size_t)(b * NPTS + j)) * 3;
    float f0 = pj[0] - pi[0], f1 = pj[1] - pi[1], f2 = pj[2] - pi[2];
    float f3 = pi[0], f4 = pi[1], f5 = pi[2];
#pragma unroll
    for (int o8 = 0; o8 < 8; o8++) {
        uint4 u;
        unsigned int* up = (unsigned int*)&u;
#pragma unroll
        for (int e2 = 0; e2 < 4; e2++) {
            const float* wa = w + (o8 * 8 + e2 * 2) * 6;
            const float* wb = wa + 6;
            float r0 = wa[0]*f0 + wa[1]*f1 + wa[2]*f2 + wa[3]*f3 + wa[4]*f4 + wa[5]*f5;
            float r1 = wb[0]*f0 + wb[1]*f1 + wb[2]*f2 + wb[3]*f3 + wb[4]*f4 + wb[5]*f5;
            up[e2] = pack2(r0, r1);
        }
        *(uint4*)(y1 + (size_t)m * 64 + o8 * 8) = u;
    }
}

// ---------------- generic MFMA conv (layer 5) ----------------
template<int CIN, int COUT, bool BN>
__launch_bounds__(256)
__global__ void conv_mfma_k(const ushort_t* __restrict__ yin,
                            const ushort_t* __restrict__ whi,
                            const ushort_t* __restrict__ wlo,
                            const float* __restrict__ scale,
                            const float* __restrict__ shift,
                            ushort_t* __restrict__ yout) {
    constexpr int SMEM = 28672 + (BN ? CIN * 8 : 0);
    __shared__ char smem[SMEM];
    ushort_t* hA = (ushort_t*)smem;             // [128][56]
    ushort_t* wH = (ushort_t*)(smem + 14336);   // [64][56]
    ushort_t* wL = (ushort_t*)(smem + 21504);   // [64][56]
    float* scl = (float*)(smem + 28672);
    float* shf = scl + CIN;
    const int tid = threadIdx.x;
    const int m0 = blockIdx.y * 128;
    const int o0 = blockIdx.x * 64;
    if constexpr (BN) {
        for (int c = tid; c < CIN; c += 256) { scl[c] = scale[c]; shf[c] = shift[c]; }
    }
    f32x4 acc[2][4];
#pragma unroll
    for (int mt = 0; mt < 2; mt++)
#pragma unroll
        for (int ot = 0; ot < 4; ot++) acc[mt][ot] = (f32x4){0.f, 0.f, 0.f, 0.f};
    const int lane = tid & 63, wv = tid >> 6;
    const int l15 = lane & 15, quad = lane >> 4;
    for (int kc = 0; kc < CIN; kc += 32) {
        __syncthreads();
#pragma unroll
        for (int i = 0; i < 2; i++) {
            int tt = tid + 256 * i;
            int mr = tt >> 2, cq = (tt & 3) * 8;
            uint4 u = *(const uint4*)(yin + (size_t)(m0 + mr) * CIN + kc + cq);
            if constexpr (BN) {
                float vv[8]; unpack8(u, vv);
#pragma unroll
                for (int e = 0; e < 8; e++)
                    vv[e] = fmaxf(fmaf(vv[e], scl[kc + cq + e], shf[kc + cq + e]), 0.0f);
                u.x = pack2(vv[0], vv[1]); u.y = pack2(vv[2], vv[3]);
                u.z = pack2(vv[4], vv[5]); u.w = pack2(vv[6], vv[7]);
            }
            *(uint4*)&hA[mr * 56 + cq] = u;
        }
        {
            int orow = tid >> 2, cq = (tid & 3) * 8;
            *(uint4*)&wH[orow * 56 + cq] = *(const uint4*)(whi + (size_t)(o0 + orow) * CIN + kc + cq);
            *(uint4*)&wL[orow * 56 + cq] = *(const uint4*)(wlo + (size_t)(o0 + orow) * CIN + kc + cq);
        }
        __syncthreads();
        bf16x8 a0 = *(bf16x8*)&hA[(wv * 32 + l15) * 56 + quad * 8];
        bf16x8 a1 = *(bf16x8*)&hA[(wv * 32 + 16 + l15) * 56 + quad * 8];
#pragma unroll
        for (int ot = 0; ot < 4; ot++) {
            bf16x8 bh = *(bf16x8*)&wH[(ot * 16 + l15) * 56 + quad * 8];
            bf16x8 bl = *(bf16x8*)&wL[(ot * 16 + l15) * 56 + quad * 8];
            acc[0][ot] = __builtin_amdgcn_mfma_f32_16x16x32_bf16(a0, bh, acc[0][ot], 0, 0, 0);
            acc[0][ot] = __builtin_amdgcn_mfma_f32_16x16x32_bf16(a0, bl, acc[0][ot], 0, 0, 0);
            acc[1][ot] = __builtin_amdgcn_mfma_f32_16x16x32_bf16(a1, bh, acc[1][ot], 0, 0, 0);
            acc[1][ot] = __builtin_amdgcn_mfma_f32_16x16x32_bf16(a1, bl, acc[1][ot], 0, 0, 0);
        }
    }
    __syncthreads();
    ushort_t* outT = (ushort_t*)smem;   // [128][72]
#pragma unroll
    for (int mt = 0; mt < 2; mt++)
#pragma unroll
        for (int ot = 0; ot < 4; ot++)
#pragma unroll
            for (int r = 0; r < 4; r++)
                outT[(wv * 32 + mt * 16 + quad * 4 + r) * 72 + ot * 16 + l15] = f2bf(acc[mt][ot][r]);
    __syncthreads();
    int row = tid >> 1, half = tid & 1;
#pragma unroll
    for (int g = 0; g < 4; g++) {
        uint4 u = *(uint4*)&outT[row * 72 + half * 32 + g * 8];
        *(uint4*)(yout + (size_t)(m0 + row) * COUT + o0 + half * 32 + g * 8) = u;
    }
}

// ---------------- fused conv (layers 2,3,4): 320m (16 k-windows) x BOo tiles.
// Grid: x = o-tile (fastest), y = m-tile (1024). Epilogue: raw max/min per k-window
// + per-block f32 stats partials; optional y write.
// LESSONS: (r5/r6) runtime acc index -> scratch demotion: keep acc indexing static.
// (r7) cross-lane LDS round-trip needs __syncthreads() between write/read phases.
template<int CIN, int COUT, int BO, bool WRITEY>
__launch_bounds__(256, 2)
__global__ void conv_fused_k(const ushort_t* __restrict__ yin,
                             const ushort_t* __restrict__ whi,
                             const ushort_t* __restrict__ wlo,
                             const float* __restrict__ scale,
                             const float* __restrict__ shift,
                             ushort_t* __restrict__ yout,
                             float* __restrict__ rawmax, float* __restrict__ rawmin,
                             float* __restrict__ sp) {
    constexpr int NOT = BO / 16;
    __shared__ ushort_t hA[320 * 56];           // 35840 B; wreg overlays this
    __shared__ ushort_t wHs[BO * 56];
    __shared__ ushort_t wLs[BO * 56];
    __shared__ float scl[CIN], shf[CIN];
    __shared__ float sw[4 * BO * 2];
    const int tid = threadIdx.x;
    const int m0 = blockIdx.y * 320;            // 1024 m-tiles
    const int o0 = blockIdx.x * BO;
    for (int c = tid; c < CIN; c += 256) { scl[c] = scale[c]; shf[c] = shift[c]; }
    for (int i = tid; i < 4 * BO * 2; i += 256) sw[i] = 0.0f;
    f32x4 acc[5][NOT];
#pragma unroll
    for (int mt = 0; mt < 5; mt++)
#pragma unroll
        for (int ot = 0; ot < NOT; ot++) acc[mt][ot] = (f32x4){0.f, 0.f, 0.f, 0.f};
    const int lane = tid & 63, wv = tid >> 6;
    const int l15 = lane & 15, quad = lane >> 4;
    for (int kc = 0; kc < CIN; kc += 32) {
        __syncthreads();
        // stage activations: 320 rows x 32c (BN+ReLU applied)
#pragma unroll
        for (int i = 0; i < 5; i++) {
            int tt = tid + 256 * i;
            int mr = tt >> 2, cq = (tt & 3) * 8;
            uint4 u = *(const uint4*)(yin + (size_t)(m0 + mr) * CIN + kc + cq);
            float vv[8]; unpack8(u, vv);
#pragma unroll
            for (int e = 0; e < 8; e++)
                vv[e] = fmaxf(fmaf(vv[e], scl[kc + cq + e], shf[kc + cq + e]), 0.0f);
            u.x = pack2(vv[0], vv[1]); u.y = pack2(vv[2], vv[3]);
            u.z = pack2(vv[4], vv[5]); u.w = pack2(vv[6], vv[7]);
            *(uint4*)&hA[mr * 56 + cq] = u;
        }
        // stage weights hi/lo: BO rows x 32c
        for (int t = tid; t < BO * 4; t += 256) {
            int row = t >> 2, cq = (t & 3) * 8;
            *(uint4*)&wHs[row * 56 + cq] = *(const uint4*)(whi + (size_t)(o0 + row) * CIN + kc + cq);
            *(uint4*)&wLs[row * 56 + cq] = *(const uint4*)(wlo + (size_t)(o0 + row) * CIN + kc + cq);
        }
        __syncthreads();
        bf16x8 a[5];
#pragma unroll
        for (int mt = 0; mt < 5; mt++)
            a[mt] = *(bf16x8*)&hA[(wv * 80 + mt * 16 + l15) * 56 + quad * 8];
#pragma unroll
        for (int ot = 0; ot < NOT; ot++) {
            bf16x8 bh = *(bf16x8*)&wHs[(ot * 16 + l15) * 56 + quad * 8];
            bf16x8 bl = *(bf16x8*)&wLs[(ot * 16 + l15) * 56 + quad * 8];
#pragma unroll
            for (int mt = 0; mt < 5; mt++) {
                acc[mt][ot] = __builtin_amdgcn_mfma_f32_16x16x32_bf16(a[mt], bh, acc[mt][ot], 0, 0, 0);
                acc[mt][ot] = __builtin_amdgcn_mfma_f32_16x16x32_bf16(a[mt], bl, acc[mt][ot], 0, 0, 0);
            }
        }
    }
    __syncthreads();   // waves may still read hA/wHs/wLs; wreg overlays hA
    // epilogue: per wave, 80m x 16o f32 scratch ([80][20] rows, 16B aligned)
    float* wreg = (float*)((char*)hA + wv * 6400);
#pragma unroll
    for (int ot = 0; ot < NOT; ot++) {
#pragma unroll
        for (int mt = 0; mt < 5; mt++)
#pragma unroll
            for (int r = 0; r < 4; r++)
                wreg[(mt * 16 + quad * 4 + r) * 20 + l15] = acc[mt][ot][r];
        __syncthreads();   // cross-lane round-trip (r7 lesson)
        {
            int pp = quad;                      // 4 points per wave (80m = 4x20)
            const float* rr = wreg + (pp * 20) * 20 + l15;
            float mx = rr[0], mn = rr[0], sm = 0.0f, ss = 0.0f;
#pragma unroll
            for (int q = 0; q < 20; q++) {
                float vv = rr[q * 20];
                mx = fmaxf(mx, vv); mn = fminf(mn, vv);
                sm += vv; ss = fmaf(vv, vv, ss);
            }
            int pt = blockIdx.y * 16 + wv * 4 + pp;
            int o = o0 + ot * 16 + l15;
            rawmax[(size_t)pt * COUT + o] = mx;
            rawmin[(size_t)pt * COUT + o] = mn;
            sm += __shfl_xor(sm, 16); sm += __shfl_xor(sm, 32);
            ss += __shfl_xor(ss, 16); ss += __shfl_xor(ss, 32);
            if (lane < 16) {
                sw[(wv * BO + ot * 16 + l15) * 2 + 0] += sm;
                sw[(wv * BO + ot * 16 + l15) * 2 + 1] += ss;
            }
        }
        if constexpr (WRITEY) {
            // 80 rows x 16 o's = 160 chunks of 8 bf16 (16B stores)
#pragma unroll
            for (int it = 0; it < 3; it++) {
                int t = lane + it * 64;
                if (t < 160) {
                    int row = t >> 1, half = t & 1;
                    float4 f0 = *(float4*)&wreg[row * 20 + half * 8];
                    float4 f1 = *(float4*)&wreg[row * 20 + half * 8 + 4];
                    uint4 u;
                    u.x = pack2(f0.x, f0.y); u.y = pack2(f0.z, f0.w);
                    u.z = pack2(f1.x, f1.y); u.w = pack2(f1.z, f1.w);
                    *(uint4*)(yout + (size_t)(m0 + wv * 80 + row) * COUT + o0 + ot * 16 + half * 8) = u;
                }
            }
        }
        __syncthreads();   // reads done before next ot overwrites wreg
    }
    for (int t2 = tid; t2 < BO * 2; t2 += 256) {
        int ol = t2 >> 1, st = t2 & 1;
        float v = 0.0f;
#pragma unroll
        for (int w2 = 0; w2 < 4; w2++) v += sw[(w2 * BO + ol) * 2 + st];
        size_t bid = (size_t)blockIdx.x * 1024 + blockIdx.y;   // o-major
        sp[bid * (2 * BO) + ol * 2 + st] = v;
    }
}

// ---------------- reduce fused-conv stat partials + finalize BN in one pass ----------------
template<int BO>
__launch_bounds__(256)
__global__ void stats4red_fin_k(const float* __restrict__ sp,
                                const float* __restrict__ g, const float* __restrict__ bb,
                                float* __restrict__ scale, float* __restrict__ shift,
                                double invcnt) {
    __shared__ double rs[256], rss[256];
    int o = blockIdx.x, tid = threadIdx.x;
    int oy = o / BO, ol = o % BO;
    double s = 0.0, ss = 0.0;
    for (int mb = tid; mb < 1024; mb += 256) {
        size_t bid = (size_t)oy * 1024 + mb;
        s  += (double)sp[bid * (2 * BO) + ol * 2 + 0];
        ss += (double)sp[bid * (2 * BO) + ol * 2 + 1];
    }
    rs[tid] = s; rss[tid] = ss;
    __syncthreads();
    for (int st = 128; st; st >>= 1) {
        if (tid < st) { rs[tid] += rs[tid + st]; rss[tid] += rss[tid + st]; }
        __syncthreads();
    }
    if (tid == 0) {
        double m = rs[0] * invcnt;
        double v = rss[0] * invcnt - m * m;
        if (v < 0.0) v = 0.0;
        float sc = g[o] / sqrtf((float)v + 1e-5f);
        scale[o] = sc;
        shift[o] = bb[o] - (float)m * sc;
    }
}

// ---------------- per-channel sum/sumsq over NHWC y (layers 1,5) ----------------
template<int C8>
__launch_bounds__(256)
__global__ void stats_nhwc_k(const ushort_t* __restrict__ y, double* __restrict__ sum,
                             double* __restrict__ sumsq, int rpb) {
    constexpr int C = C8 * 8;
    constexpr int STRIDE = 256 / C8;
    __shared__ float ls[C][2];
    int tid = threadIdx.x;
    for (int i = tid; i < C * 2; i += 256) ((float*)ls)[i] = 0.0f;
    int cg = tid % C8, mr = tid / C8;
    size_t r0 = (size_t)blockIdx.x * rpb;
    float s[8], ss[8];
#pragma unroll
    for (int e = 0; e < 8; e++) { s[e] = 0.0f; ss[e] = 0.0f; }
    for (int r = mr; r < rpb; r += STRIDE) {
        uint4 u = *(const uint4*)(y + (r0 + r) * C + cg * 8);
        float vv[8]; unpack8(u, vv);
#pragma unroll
        for (int e = 0; e < 8; e++) { s[e] += vv[e]; ss[e] = fmaf(vv[e], vv[e], ss[e]); }
    }
    __syncthreads();
#pragma unroll
    for (int e = 0; e < 8; e++) {
        atomicAdd(&ls[cg * 8 + e][0], s[e]);
        atomicAdd(&ls[cg * 8 + e][1], ss[e]);
    }
    __syncthreads();
    // strided (C can exceed blockDim; round-4 bug)
    for (int c = tid; c < C; c += 256) {
        atomicAdd(&sum[c], (double)ls[c][0]);
        atomicAdd(&sumsq[c], (double)ls[c][1]);
    }
}

// ---------------- finalize BN (layers 1,5) ----------------
__global__ void fin_k(const double* __restrict__ sum, const double* __restrict__ sumsq,
                      const float* __restrict__ g, const float* __restrict__ bb,
                      float* __restrict__ scale, float* __restrict__ shift, int C, double invcnt) {
    int c = blockIdx.x * blockDim.x + threadIdx.x;
    if (c < C) {
        double m = sum[c] * invcnt;
        double v = sumsq[c] * invcnt - m * m;
        if (v < 0.0) v = 0.0;
        float sc = g[c] / sqrtf((float)v + 1e-5f);
        scale[c] = sc;
        shift[c] = bb[c] - (float)m * sc;
    }
}

// ---------------- maxpool over k (BN+ReLU) NHWC -> xcat (layer 1) ----------------
template<int C8>
__launch_bounds__(256)
__global__ void maxpool_nhwc_k(const ushort_t* __restrict__ y, const float* __restrict__ scale,
                               const float* __restrict__ shift, ushort_t* __restrict__ xcat,
                               int coff) {
    constexpr int C = C8 * 8;
    constexpr int PB = 256 / C8;
    int tid = threadIdx.x;
    int cg = tid % C8, pl = tid / C8;
    int p = blockIdx.x * PB + pl;
    float sc[8], sh[8];
    *(float4*)&sc[0] = *(const float4*)(scale + cg * 8);
    *(float4*)&sc[4] = *(const float4*)(scale + cg * 8 + 4);
    *(float4*)&sh[0] = *(const float4*)(shift + cg * 8);
    *(float4*)&sh[4] = *(const float4*)(shift + cg * 8 + 4);
    float mx[8];
#pragma unroll
    for (int e = 0; e < 8; e++) mx[e] = 0.0f;   // relu floor
    size_t base = (size_t)p * KNN * C + cg * 8;
#pragma unroll
    for (int q = 0; q < KNN; q++) {
        uint4 u = *(const uint4*)(y + base + (size_t)q * C);
        float vv[8]; unpack8(u, vv);
#pragma unroll
        for (int e = 0; e < 8; e++) mx[e] = fmaxf(mx[e], fmaf(vv[e], sc[e], sh[e]));
    }
    uint4 u;
    u.x = pack2(mx[0], mx[1]); u.y = pack2(mx[2], mx[3]);
    u.z = pack2(mx[4], mx[5]); u.w = pack2(mx[6], mx[7]);
    *(uint4*)(xcat + (size_t)p * 512 + coff + cg * 8) = u;
}

// ---------------- pool finalize from raw max/min (BN monotone) -> xcat (layers 2,3,4) ----------------
template<int C8>
__launch_bounds__(256)
__global__ void pool_raw_k(const float* __restrict__ rawmax, const float* __restrict__ rawmin,
                           const float* __restrict__ scale, const float* __restrict__ shift,
                           ushort_t* __restrict__ xcat, int coff) {
    constexpr int COUT = C8 * 8;
    int gid = blockIdx.x * 256 + threadIdx.x;   // 16384 * C8
    int p = gid / C8, og = gid % C8;
    float sc[8], sh[8], mxv[8], mnv[8];
    *(float4*)&sc[0]  = *(const float4*)(scale + og * 8);
    *(float4*)&sc[4]  = *(const float4*)(scale + og * 8 + 4);
    *(float4*)&sh[0]  = *(const float4*)(shift + og * 8);
    *(float4*)&sh[4]  = *(const float4*)(shift + og * 8 + 4);
    *(float4*)&mxv[0] = *(const float4*)(rawmax + (size_t)p * COUT + og * 8);
    *(float4*)&mxv[4] = *(const float4*)(rawmax + (size_t)p * COUT + og * 8 + 4);
    *(float4*)&mnv[0] = *(const float4*)(rawmin + (size_t)p * COUT + og * 8);
    *(float4*)&mnv[4] = *(const float4*)(rawmin + (size_t)p * COUT + og * 8 + 4);
    float v[8];
#pragma unroll
    for (int e = 0; e < 8; e++) {
        float raw = (sc[e] >= 0.0f) ? mxv[e] : mnv[e];
        v[e] = fmaxf(fmaf(raw, sc[e], sh[e]), 0.0f);
    }
    uint4 u;
    u.x = pack2(v[0], v[1]); u.y = pack2(v[2], v[3]);
    u.z = pack2(v[4], v[5]); u.w = pack2(v[6], v[7]);
    *(uint4*)(xcat + (size_t)p * 512 + coff + og * 8) = u;
}

// ---------------- output: BN5+ReLU + transpose NHWC -> [b][c][n] fp32 ----------------
__launch_bounds__(256)
__global__ void out_k(const ushort_t* __restrict__ y5, const float* __restrict__ scale,
                      const float* __restrict__ shift, float* __restrict__ out) {
    __shared__ float tr[64 * 65];
    int tid = threadIdx.x;
    int n0 = blockIdx.x * 64, c0 = blockIdx.y * 64, b = blockIdx.z;
    int nl = tid >> 2, cq = (tid & 3) * 16;
    const ushort_t* src = y5 + (size_t)(b * 2048 + n0 + nl) * 512 + c0 + cq;
#pragma unroll
    for (int h = 0; h < 2; h++) {
        uint4 u = *(const uint4*)(src + h * 8);
        float vv[8]; unpack8(u, vv);
#pragma unroll
        for (int e = 0; e < 8; e++) {
            int c = cq + h * 8 + e;
            tr[c * 65 + nl] = fmaxf(fmaf(vv[e], scale[c0 + c], shift[c0 + c]), 0.0f);
        }
    }
    __syncthreads();
    int cl = tid >> 2, ng = (tid & 3) * 16;
#pragma unroll
    for (int g = 0; g < 4; g++) {
        float4 v = *(float4*)&tr[cl * 65 + ng + g * 4];
        *(float4*)(out + ((size_t)b * 512 + c0 + cl) * 2048 + n0 + ng + g * 4) = v;
    }
}

// ---------------- host ----------------
extern "C" void kernel_launch(void* const* d_in, const int* in_sizes, int n_in,
                              void* d_out, int out_size, void* d_ws, size_t ws_size,
                              hipStream_t stream) {
    (void)in_sizes; (void)n_in; (void)out_size;
    if (ws_size < WS_NEEDED) return;
    const float* x  = (const float*)d_in[0];
    const float* w1 = (const float*)d_in[1];
    const float* g1 = (const float*)d_in[2];
    const float* b1 = (const float*)d_in[3];
    const float* w2 = (const float*)d_in[4];
    const float* g2 = (const float*)d_in[5];
    const float* b2 = (const float*)d_in[6];
    const float* w3 = (const float*)d_in[7];
    const float* g3 = (const float*)d_in[8];
    const float* b3 = (const float*)d_in[9];
    const float* w4 = (const float*)d_in[10];
    const float* g4 = (const float*)d_in[11];
    const float* b4 = (const float*)d_in[12];
    const float* w5 = (const float*)d_in[13];
    const float* g5 = (const float*)d_in[14];
    const float* b5 = (const float*)d_in[15];

    char* ws = (char*)d_ws;
    float* xt  = (float*)(ws + OFF_XT);
    float* xx  = (float*)(ws + OFF_XX);
    int*   idx = (int*)(ws + OFF_IDX);
    ushort_t* wh2 = (ushort_t*)(ws + OFF_WH2); ushort_t* wl2 = (ushort_t*)(ws + OFF_WL2);
    ushort_t* wh3 = (ushort_t*)(ws + OFF_WH3); ushort_t* wl3 = (ushort_t*)(ws + OFF_WL3);
    ushort_t* wh4 = (ushort_t*)(ws + OFF_WH4); ushort_t* wl4 = (ushort_t*)(ws + OFF_WL4);
    ushort_t* wh5 = (ushort_t*)(ws + OFF_WH5); ushort_t* wl5 = (ushort_t*)(ws + OFF_WL5);
    ushort_t* y1 = (ushort_t*)(ws + OFF_REG0);
    ushort_t* y2 = (ushort_t*)(ws + OFF_REG1);
    ushort_t* y3 = (ushort_t*)(ws + OFF_REG0);
    ushort_t* y5 = (ushort_t*)(ws + OFF_REG0);
    ushort_t* xcat = (ushort_t*)(ws + OFF_XCAT);
    float* rawmax = (float*)(ws + OFF_RAWMAX);
    float* rawmin = (float*)(ws + OFF_RAWMIN);
    float* sp     = (float*)(ws + OFF_SP);

    double* sum[5]; double* sumsq[5]; float* scl[5]; float* shf[5];
    for (int l = 0; l < 5; l++) {
        sum[l]   = (double*)(ws + OFF_STATS + (size_t)l * 8192);
        sumsq[l] = sum[l] + 512;
        scl[l]   = (float*)(ws + OFF_SS + (size_t)l * 4096);
        shf[l]   = scl[l] + 512;
    }

    hipMemsetAsync(ws + OFF_STATS, 0, 40960, stream);
    prep_k<<<64, 256, 0, stream>>>(x, xt, xx);
    wsplit_all_k<<<1200, 256, 0, stream>>>(w2, wh2, wl2, w3, wh3, wl3,
                                           w4, wh4, wl4, w5, wh5, wl5);
    knn_k<<<2048, 256, 0, stream>>>(xt, xx, idx);

    // layer 1
    conv1_k<<<1280, 256, 0, stream>>>(xt, idx, w1, y1);
    stats_nhwc_k<8><<<160, 256, 0, stream>>>(y1, sum[0], sumsq[0], 2048);
    fin_k<<<1, 512, 0, stream>>>(sum[0], sumsq[0], g1, b1, scl[0], shf[0], 64, 1.0 / 327680.0);
    maxpool_nhwc_k<8><<<512, 256, 0, stream>>>(y1, scl[0], shf[0], xcat, 0);

    // layer 2: 64 -> 64 fused (BO=64, 1 o-tile)
    conv_fused_k<64, 64, 64, true><<<dim3(1, 1024), 256, 0, stream>>>(
        y1, wh2, wl2, scl[0], shf[0], y2, rawmax, rawmin, sp);
    stats4red_fin_k<64><<<64, 256, 0, stream>>>(sp, g2, b2, scl[1], shf[1], 1.0 / 327680.0);
    pool_raw_k<8><<<512, 256, 0, stream>>>(rawmax, rawmin, scl[1], shf[1], xcat, 64);

    // layer 3: 64 -> 128 fused (BO=128, 1 o-tile: y2 read once)
    conv_fused_k<64, 128, 128, true><<<dim3(1, 1024), 256, 0, stream>>>(
        y2, wh3, wl3, scl[1], shf[1], y3, rawmax, rawmin, sp);
    stats4red_fin_k<128><<<128, 256, 0, stream>>>(sp, g3, b3, scl[2], shf[2], 1.0 / 327680.0);
    pool_raw_k<16><<<1024, 256, 0, stream>>>(rawmax, rawmin, scl[2], shf[2], xcat, 128);

    // layer 4: 128 -> 256 fused (BO=128, 2 o-tiles: y3 read 2x, was 4x)
    conv_fused_k<128, 256, 128, false><<<dim3(2, 1024), 256, 0, stream>>>(
        y3, wh4, wl4, scl[2], shf[2], nullptr, rawmax, rawmin, sp);
    stats4red_fin_k<128><<<256, 256, 0, stream>>>(sp, g4, b4, scl[3], shf[3], 1.0 / 327680.0);
    pool_raw_k<32><<<2048, 256, 0, stream>>>(rawmax, rawmin, scl[3], shf[3], xcat, 256);

    // layer 5: 512 -> 512 (input already activated)
    conv_mfma_k<512, 512, false><<<dim3(8, 128), 256, 0, stream>>>(xcat, wh5, wl5,
                                                                   nullptr, nullptr, y5);
    stats_nhwc_k<64><<<128, 256, 0, stream>>>(y5, sum[4], sumsq[4], 128);
    fin_k<<<1, 512, 0, stream>>>(sum[4], sumsq[4], g5, b5, scl[4], shf[4], 512, 1.0 / 16384.0);
    out_k<<<dim3(32, 8, 8), 256, 0, stream>>>(y5, scl[4], shf[4], (float*)d_out);
}

// Round 12
// 513.874 us; speedup vs baseline: 1.9282x; 1.0533x over previous
//
#include <hip/hip_runtime.h>
#include <cstdint>
#include <cstddef>

// ---------------- constants ----------------
#define BATCH 8
#define NPTS 2048
#define KNN 20
#define M1 327680   // BATCH*NPTS*KNN
#define M2 16384    // BATCH*NPTS

typedef unsigned short ushort_t;
typedef __attribute__((ext_vector_type(8))) short bf16x8;   // 8 bf16 = 4 VGPRs
typedef __attribute__((ext_vector_type(4))) float f32x4;    // MFMA acc

// ws layout (bytes) — total 181,121,024
#define OFF_XT    0UL          // 196608   float xt[b*n][3]
#define OFF_XX    196608UL     // 65536    float xx[b*n]
#define OFF_IDX   262144UL     // 1310720  int idx[b*n][20]
#define OFF_WH2   1572864UL    // 8192   bf16 [64][64]
#define OFF_WL2   1581056UL    // 8192   (unused since r12: layers 2-4 single-bf16)
#define OFF_WH3   1589248UL    // 16384  bf16 [128][64]
#define OFF_WL3   1605632UL    // 16384  (unused)
#define OFF_WH4   1622016UL    // 65536  bf16 [256][128]
#define OFF_WL4   1687552UL    // 65536  (unused)
#define OFF_WH5   1753088UL    // 524288 bf16 [512][512]
#define OFF_WL5   2277376UL    // 524288 (kept: conv5 K=512 feeds output directly)
#define OFF_STATS 2801664UL    // 40960   5 x (512 sum + 512 sumsq) double (layers 1,5)
#define OFF_SS    2842624UL    // 20480   5 x (512 scale + 512 shift) float
// REG0: y1 [M1][64] (41.9MB) -> y3 [M1][128] (83.9MB) -> y5 [M2][512] (16.8MB)
#define OFF_REG0  2863104UL    // 83886080
// REG1: y2 [M1][64] (41.9MB)
#define OFF_REG1  86749184UL   // 41943040
#define OFF_XCAT  128692224UL  // 16777216 xcat[M2][512] bf16
#define OFF_RAWMAX 145469440UL // 16777216 f32 [16384][<=256]
#define OFF_RAWMIN 162246656UL // 16777216
#define OFF_SP     179023872UL // 2097152  f32 partials [<=2048 blocks][<=256]
#define WS_NEEDED  181121024UL

// ---------------- helpers ----------------
__device__ __forceinline__ float bf2f(unsigned short u) {
    union { unsigned int i; float f; } c; c.i = ((unsigned int)u) << 16; return c.f;
}
__device__ __forceinline__ unsigned short f2bf(float f) {
    union { float f; unsigned int i; } c; c.f = f;
    unsigned int x = c.i;
    unsigned int r = (x + 0x7fffu + ((x >> 16) & 1u)) >> 16;  // RNE
    return (unsigned short)r;
}
__device__ __forceinline__ unsigned int pack2(float a, float b) {
    return (unsigned int)f2bf(a) | ((unsigned int)f2bf(b) << 16);
}
__device__ __forceinline__ void unpack8(uint4 u, float* v) {
    v[0] = bf2f((unsigned short)(u.x & 0xffffu)); v[1] = bf2f((unsigned short)(u.x >> 16));
    v[2] = bf2f((unsigned short)(u.y & 0xffffu)); v[3] = bf2f((unsigned short)(u.y >> 16));
    v[4] = bf2f((unsigned short)(u.z & 0xffffu)); v[5] = bf2f((unsigned short)(u.z >> 16));
    v[6] = bf2f((unsigned short)(u.w & 0xffffu)); v[7] = bf2f((unsigned short)(u.w >> 16));
}

// ---------------- prep: transpose x, compute xx ----------------
__global__ void prep_k(const float* __restrict__ x, float* __restrict__ xt, float* __restrict__ xx) {
    int t = blockIdx.x * 256 + threadIdx.x;   // 16384
    int b = t >> 11, n = t & 2047;
    float v0 = x[((size_t)b * 3 + 0) * NPTS + n];
    float v1 = x[((size_t)b * 3 + 1) * NPTS + n];
    float v2 = x[((size_t)b * 3 + 2) * NPTS + n];
    xt[(size_t)t * 3 + 0] = v0; xt[(size_t)t * 3 + 1] = v1; xt[(size_t)t * 3 + 2] = v2;
    xx[t] = __fadd_rn(__fadd_rn(__fmul_rn(v0, v0), __fmul_rn(v1, v1)), __fmul_rn(v2, v2));
}

// ---------------- weight prep: layers 2-4 single bf16; layer 5 hi/lo split ----------------
__global__ void wsplit_all_k(const float* __restrict__ w2, ushort_t* __restrict__ wh2,
                             const float* __restrict__ w3, ushort_t* __restrict__ wh3,
                             const float* __restrict__ w4, ushort_t* __restrict__ wh4,
                             const float* __restrict__ w5, ushort_t* __restrict__ wh5,
                             ushort_t* __restrict__ wl5) {
    int t = blockIdx.x * 256 + threadIdx.x;   // 307200 total
    if (t < 4096)        { wh2[t] = f2bf(w2[t]); }
    else if (t < 12288)  { int o = t - 4096;  wh3[o] = f2bf(w3[o]); }
    else if (t < 45056)  { int o = t - 12288; wh4[o] = f2bf(w4[o]); }
    else {
        int o = t - 45056;
        float f = w5[o];
        ushort_t h = f2bf(f);
        wh5[o] = h;
        wl5[o] = f2bf(f - bf2f(h));
    }
}

// ---------------- knn: 2 points per wave, tournament + short butterfly ----------------
template<int G>
__device__ __forceinline__ void knn_rescan(float (&v)[32], float (&gm)[4], int (&gq)[4],
                                           bool own, int qw) {
#pragma unroll
    for (int q = G * 8; q < G * 8 + 8; q++)
        if (own && q == qw) v[q] = -3.4e38f;
    float m = v[G * 8]; int qi = G * 8;
#pragma unroll
    for (int q = G * 8 + 1; q < G * 8 + 8; q++)
        if (v[q] > m) { m = v[q]; qi = q; }
    gm[G] = m; gq[G] = qi;
}

__device__ __forceinline__ void knn_round(float (&v)[32], float (&gm)[4], int (&gq)[4],
                                          int* __restrict__ out, int t, int l) {
    float bv = gm[0]; int bq = gq[0];
    if (gm[1] > bv) { bv = gm[1]; bq = gq[1]; }
    if (gm[2] > bv) { bv = gm[2]; bq = gq[2]; }
    if (gm[3] > bv) { bv = gm[3]; bq = gq[3]; }
    int bj = l + bq * 64;
#pragma unroll
    for (int off = 1; off <= 8; off <<= 1) {
        float ov = __shfl_xor(bv, off);
        int   oj = __shfl_xor(bj, off);
        if (ov > bv || (ov == bv && oj < bj)) { bv = ov; bj = oj; }
    }
    // each 16-lane group converged; resolve 4 candidates (uniform values)
    int ib = __float_as_int(bv);
    float w0 = __int_as_float(__builtin_amdgcn_readlane(ib, 0));
    float w1 = __int_as_float(__builtin_amdgcn_readlane(ib, 16));
    float w2 = __int_as_float(__builtin_amdgcn_readlane(ib, 32));
    float w3 = __int_as_float(__builtin_amdgcn_readlane(ib, 48));
    int u0 = __builtin_amdgcn_readlane(bj, 0);
    int u1 = __builtin_amdgcn_readlane(bj, 16);
    int u2 = __builtin_amdgcn_readlane(bj, 32);
    int u3 = __builtin_amdgcn_readlane(bj, 48);
    float Bv = w0; int Bj = u0;
    if (w1 > Bv || (w1 == Bv && u1 < Bj)) { Bv = w1; Bj = u1; }
    if (w2 > Bv || (w2 == Bv && u2 < Bj)) { Bv = w2; Bj = u2; }
    if (w3 > Bv || (w3 == Bv && u3 < Bj)) { Bv = w3; Bj = u3; }
    int bju = __builtin_amdgcn_readfirstlane(Bj);  // force scalar
    if (l == 0) out[t] = bju;
    int qw = bju >> 6;                  // scalar slot
    bool own = (l == (bju & 63));
    int gw = qw >> 3;                   // scalar group -> uniform branch
    if (gw == 0)      knn_rescan<0>(v, gm, gq, own, qw);
    else if (gw == 1) knn_rescan<1>(v, gm, gq, own, qw);
    else if (gw == 2) knn_rescan<2>(v, gm, gq, own, qw);
    else              knn_rescan<3>(v, gm, gq, own, qw);
}

__launch_bounds__(256)
__global__ void knn_k(const float* __restrict__ xt, const float* __restrict__ xx, int* __restrict__ idx) {
    int tid = threadIdx.x;
    int l = tid & 63, wv = tid >> 6;
    int pidA = blockIdx.x * 8 + wv * 2;   // 2048 blocks x 4 waves x 2 points
    int pidB = pidA + 1;
    int b = pidA >> 11;
    const float* xb  = xt + (size_t)b * NPTS * 3;
    const float* xxb = xx + (size_t)b * NPTS;
    int iA = pidA & 2047, iB = pidB & 2047;
    float xA0 = xb[iA * 3 + 0], xA1 = xb[iA * 3 + 1], xA2 = xb[iA * 3 + 2];
    float xB0 = xb[iB * 3 + 0], xB1 = xb[iB * 3 + 1], xB2 = xb[iB * 3 + 2];
    float xxA = xxb[iA], xxB = xxb[iB];
    float vA[32], vB[32];
#pragma unroll
    for (int q = 0; q < 32; q++) {
        int j = l + q * 64;
        float p0 = xb[j * 3 + 0], p1 = xb[j * 3 + 1], p2 = xb[j * 3 + 2];
        float xxj = xxb[j];
        float dA = __fadd_rn(__fadd_rn(__fmul_rn(xA0, p0), __fmul_rn(xA1, p1)), __fmul_rn(xA2, p2));
        float dB = __fadd_rn(__fadd_rn(__fmul_rn(xB0, p0), __fmul_rn(xB1, p1)), __fmul_rn(xB2, p2));
        vA[q] = __fsub_rn(__fsub_rn(-xxA, __fmul_rn(-2.0f, dA)), xxj);
        vB[q] = __fsub_rn(__fsub_rn(-xxB, __fmul_rn(-2.0f, dB)), xxj);
    }
    float gmA[4], gmB[4]; int gqA[4], gqB[4];
#pragma unroll
    for (int g = 0; g < 4; g++) {
        float mA = vA[g * 8]; int qA = g * 8;
        float mB = vB[g * 8]; int qB = g * 8;
#pragma unroll
        for (int q = g * 8 + 1; q < g * 8 + 8; q++) {
            if (vA[q] > mA) { mA = vA[q]; qA = q; }
            if (vB[q] > mB) { mB = vB[q]; qB = q; }
        }
        gmA[g] = mA; gqA[g] = qA;
        gmB[g] = mB; gqB[g] = qB;
    }
    int* outA = idx + (size_t)pidA * KNN;
    int* outB = idx + (size_t)pidB * KNN;
    for (int t = 0; t < KNN; t++) {
        knn_round(vA, gmA, gqA, outA, t, l);
        knn_round(vB, gmB, gqB, outB, t, l);
    }
}

// ---------------- conv1: graph feature (6ch) x w1(64x6) -> y1 NHWC [m][64] bf16 ----------------
__launch_bounds__(256)
__global__ void conv1_k(const float* __restrict__ xt, const int* __restrict__ idx,
                        const float* __restrict__ w1, ushort_t* __restrict__ y1) {
    __shared__ float w[384];
    int tid = threadIdx.x;
    for (int t = tid; t < 384; t += 256) w[t] = w1[t];
    __syncthreads();
    int m = blockIdx.x * 256 + tid;        // < M1; idx flat index == m
    int nb = m / KNN;                      // b*N + n
    int b = nb >> 11;
    int j = idx[m];
    const float* pi = xt + (size_t)nb * 3;
    const float* pj = xt + ((size_t)(b * NPTS + j)) * 3;
    float f0 = pj[0] - pi[0], f1 = pj[1] - pi[1], f2 = pj[2] - pi[2];
    float f3 = pi[0], f4 = pi[1], f5 = pi[2];
#pragma unroll
    for (int o8 = 0; o8 < 8; o8++) {
        uint4 u;
        unsigned int* up = (unsigned int*)&u;
#pragma unroll
        for (int e2 = 0; e2 < 4; e2++) {
            const float* wa = w + (o8 * 8 + e2 * 2) * 6;
            const float* wb = wa + 6;
            float r0 = wa[0]*f0 + wa[1]*f1 + wa[2]*f2 + wa[3]*f3 + wa[4]*f4 + wa[5]*f5;
            float r1 = wb[0]*f0 + wb[1]*f1 + wb[2]*f2 + wb[3]*f3 + wb[4]*f4 + wb[5]*f5;
            up[e2] = pack2(r0, r1);
        }
        *(uint4*)(y1 + (size_t)m * 64 + o8 * 8) = u;
    }
}

// ---------------- generic MFMA conv (layer 5, hi/lo weights) ----------------
template<int CIN, int COUT, bool BN>
__launch_bounds__(256)
__global__ void conv_mfma_k(const ushort_t* __restrict__ yin,
                            const ushort_t* __restrict__ whi,
                            const ushort_t* __restrict__ wlo,
                            const float* __restrict__ scale,
                            const float* __restrict__ shift,
                            ushort_t* __restrict__ yout) {
    constexpr int SMEM = 28672 + (BN ? CIN * 8 : 0);
    __shared__ char smem[SMEM];
    ushort_t* hA = (ushort_t*)smem;             // [128][56]
    ushort_t* wH = (ushort_t*)(smem + 14336);   // [64][56]
    ushort_t* wL = (ushort_t*)(smem + 21504);   // [64][56]
    float* scl = (float*)(smem + 28672);
    float* shf = scl + CIN;
    const int tid = threadIdx.x;
    const int m0 = blockIdx.y * 128;
    const int o0 = blockIdx.x * 64;
    if constexpr (BN) {
        for (int c = tid; c < CIN; c += 256) { scl[c] = scale[c]; shf[c] = shift[c]; }
    }
    f32x4 acc[2][4];
#pragma unroll
    for (int mt = 0; mt < 2; mt++)
#pragma unroll
        for (int ot = 0; ot < 4; ot++) acc[mt][ot] = (f32x4){0.f, 0.f, 0.f, 0.f};
    const int lane = tid & 63, wv = tid >> 6;
    const int l15 = lane & 15, quad = lane >> 4;
    for (int kc = 0; kc < CIN; kc += 32) {
        __syncthreads();
#pragma unroll
        for (int i = 0; i < 2; i++) {
            int tt = tid + 256 * i;
            int mr = tt >> 2, cq = (tt & 3) * 8;
            uint4 u = *(const uint4*)(yin + (size_t)(m0 + mr) * CIN + kc + cq);
            if constexpr (BN) {
                float vv[8]; unpack8(u, vv);
#pragma unroll
                for (int e = 0; e < 8; e++)
                    vv[e] = fmaxf(fmaf(vv[e], scl[kc + cq + e], shf[kc + cq + e]), 0.0f);
                u.x = pack2(vv[0], vv[1]); u.y = pack2(vv[2], vv[3]);
                u.z = pack2(vv[4], vv[5]); u.w = pack2(vv[6], vv[7]);
            }
            *(uint4*)&hA[mr * 56 + cq] = u;
        }
        {
            int orow = tid >> 2, cq = (tid & 3) * 8;
            *(uint4*)&wH[orow * 56 + cq] = *(const uint4*)(whi + (size_t)(o0 + orow) * CIN + kc + cq);
            *(uint4*)&wL[orow * 56 + cq] = *(const uint4*)(wlo + (size_t)(o0 + orow) * CIN + kc + cq);
        }
        __syncthreads();
        bf16x8 a0 = *(bf16x8*)&hA[(wv * 32 + l15) * 56 + quad * 8];
        bf16x8 a1 = *(bf16x8*)&hA[(wv * 32 + 16 + l15) * 56 + quad * 8];
#pragma unroll
        for (int ot = 0; ot < 4; ot++) {
            bf16x8 bh = *(bf16x8*)&wH[(ot * 16 + l15) * 56 + quad * 8];
            bf16x8 bl = *(bf16x8*)&wL[(ot * 16 + l15) * 56 + quad * 8];
            acc[0][ot] = __builtin_amdgcn_mfma_f32_16x16x32_bf16(a0, bh, acc[0][ot], 0, 0, 0);
            acc[0][ot] = __builtin_amdgcn_mfma_f32_16x16x32_bf16(a0, bl, acc[0][ot], 0, 0, 0);
            acc[1][ot] = __builtin_amdgcn_mfma_f32_16x16x32_bf16(a1, bh, acc[1][ot], 0, 0, 0);
            acc[1][ot] = __builtin_amdgcn_mfma_f32_16x16x32_bf16(a1, bl, acc[1][ot], 0, 0, 0);
        }
    }
    __syncthreads();
    ushort_t* outT = (ushort_t*)smem;   // [128][72]
#pragma unroll
    for (int mt = 0; mt < 2; mt++)
#pragma unroll
        for (int ot = 0; ot < 4; ot++)
#pragma unroll
            for (int r = 0; r < 4; r++)
                outT[(wv * 32 + mt * 16 + quad * 4 + r) * 72 + ot * 16 + l15] = f2bf(acc[mt][ot][r]);
    __syncthreads();
    int row = tid >> 1, half = tid & 1;
#pragma unroll
    for (int g = 0; g < 4; g++) {
        uint4 u = *(uint4*)&outT[row * 72 + half * 32 + g * 8];
        *(uint4*)(yout + (size_t)(m0 + row) * COUT + o0 + half * 32 + g * 8) = u;
    }
}

// ---------------- fused conv (layers 2,3,4): 320m x BOo tiles, single-bf16 weights.
// r12: dropped the lo-weight term — BN's batch-stat normalization cancels systematic
// weight-rounding error; only decorrelated residual passes (absmax check this round).
// LESSONS: (r5/r6) runtime acc index -> scratch demotion: keep acc indexing static.
// (r7) cross-lane LDS round-trip needs __syncthreads() between write/read phases.
template<int CIN, int COUT, int BO, bool WRITEY>
__launch_bounds__(256, 2)
__global__ void conv_fused_k(const ushort_t* __restrict__ yin,
                             const ushort_t* __restrict__ whi,
                             const float* __restrict__ scale,
                             const float* __restrict__ shift,
                             ushort_t* __restrict__ yout,
                             float* __restrict__ rawmax, float* __restrict__ rawmin,
                             float* __restrict__ sp) {
    constexpr int NOT = BO / 16;
    __shared__ ushort_t hA[320 * 56];           // 35840 B; wreg overlays this
    __shared__ ushort_t wHs[BO * 56];
    __shared__ float scl[CIN], shf[CIN];
    __shared__ float sw[4 * BO * 2];
    const int tid = threadIdx.x;
    const int m0 = blockIdx.y * 320;            // 1024 m-tiles
    const int o0 = blockIdx.x * BO;
    for (int c = tid; c < CIN; c += 256) { scl[c] = scale[c]; shf[c] = shift[c]; }
    for (int i = tid; i < 4 * BO * 2; i += 256) sw[i] = 0.0f;
    f32x4 acc[5][NOT];
#pragma unroll
    for (int mt = 0; mt < 5; mt++)
#pragma unroll
        for (int ot = 0; ot < NOT; ot++) acc[mt][ot] = (f32x4){0.f, 0.f, 0.f, 0.f};
    const int lane = tid & 63, wv = tid >> 6;
    const int l15 = lane & 15, quad = lane >> 4;
    for (int kc = 0; kc < CIN; kc += 32) {
        __syncthreads();
        // stage activations: 320 rows x 32c (BN+ReLU applied)
#pragma unroll
        for (int i = 0; i < 5; i++) {
            int tt = tid + 256 * i;
            int mr = tt >> 2, cq = (tt & 3) * 8;
            uint4 u = *(const uint4*)(yin + (size_t)(m0 + mr) * CIN + kc + cq);
            float vv[8]; unpack8(u, vv);
#pragma unroll
            for (int e = 0; e < 8; e++)
                vv[e] = fmaxf(fmaf(vv[e], scl[kc + cq + e], shf[kc + cq + e]), 0.0f);
            u.x = pack2(vv[0], vv[1]); u.y = pack2(vv[2], vv[3]);
            u.z = pack2(vv[4], vv[5]); u.w = pack2(vv[6], vv[7]);
            *(uint4*)&hA[mr * 56 + cq] = u;
        }
        // stage weights: BO rows x 32c
        for (int t = tid; t < BO * 4; t += 256) {
            int row = t >> 2, cq = (t & 3) * 8;
            *(uint4*)&wHs[row * 56 + cq] = *(const uint4*)(whi + (size_t)(o0 + row) * CIN + kc + cq);
        }
        __syncthreads();
        bf16x8 a[5];
#pragma unroll
        for (int mt = 0; mt < 5; mt++)
            a[mt] = *(bf16x8*)&hA[(wv * 80 + mt * 16 + l15) * 56 + quad * 8];
#pragma unroll
        for (int ot = 0; ot < NOT; ot++) {
            bf16x8 bh = *(bf16x8*)&wHs[(ot * 16 + l15) * 56 + quad * 8];
#pragma unroll
            for (int mt = 0; mt < 5; mt++)
                acc[mt][ot] = __builtin_amdgcn_mfma_f32_16x16x32_bf16(a[mt], bh, acc[mt][ot], 0, 0, 0);
        }
    }
    __syncthreads();   // waves may still read hA/wHs; wreg overlays hA
    // epilogue: per wave, 80m x 16o f32 scratch ([80][20] rows, 16B aligned)
    float* wreg = (float*)((char*)hA + wv * 6400);
#pragma unroll
    for (int ot = 0; ot < NOT; ot++) {
#pragma unroll
        for (int mt = 0; mt < 5; mt++)
#pragma unroll
            for (int r = 0; r < 4; r++)
                wreg[(mt * 16 + quad * 4 + r) * 20 + l15] = acc[mt][ot][r];
        __syncthreads();   // cross-lane round-trip (r7 lesson)
        {
            int pp = quad;                      // 4 points per wave (80m = 4x20)
            const float* rr = wreg + (pp * 20) * 20 + l15;
            float mx = rr[0], mn = rr[0], sm = 0.0f, ss = 0.0f;
#pragma unroll
            for (int q = 0; q < 20; q++) {
                float vv = rr[q * 20];
                mx = fmaxf(mx, vv); mn = fminf(mn, vv);
                sm += vv; ss = fmaf(vv, vv, ss);
            }
            int pt = blockIdx.y * 16 + wv * 4 + pp;
            int o = o0 + ot * 16 + l15;
            rawmax[(size_t)pt * COUT + o] = mx;
            rawmin[(size_t)pt * COUT + o] = mn;
            sm += __shfl_xor(sm, 16); sm += __shfl_xor(sm, 32);
            ss += __shfl_xor(ss, 16); ss += __shfl_xor(ss, 32);
            if (lane < 16) {
                sw[(wv * BO + ot * 16 + l15) * 2 + 0] += sm;
                sw[(wv * BO + ot * 16 + l15) * 2 + 1] += ss;
            }
        }
        if constexpr (WRITEY) {
            // 80 rows x 16 o's = 160 chunks of 8 bf16 (16B stores)
#pragma unroll
            for (int it = 0; it < 3; it++) {
                int t = lane + it * 64;
                if (t < 160) {
                    int row = t >> 1, half = t & 1;
                    float4 f0 = *(float4*)&wreg[row * 20 + half * 8];
                    float4 f1 = *(float4*)&wreg[row * 20 + half * 8 + 4];
                    uint4 u;
                    u.x = pack2(f0.x, f0.y); u.y = pack2(f0.z, f0.w);
                    u.z = pack2(f1.x, f1.y); u.w = pack2(f1.z, f1.w);
                    *(uint4*)(yout + (size_t)(m0 + wv * 80 + row) * COUT + o0 + ot * 16 + half * 8) = u;
                }
            }
        }
        __syncthreads();   // reads done before next ot overwrites wreg
    }
    for (int t2 = tid; t2 < BO * 2; t2 += 256) {
        int ol = t2 >> 1, st = t2 & 1;
        float v = 0.0f;
#pragma unroll
        for (int w2 = 0; w2 < 4; w2++) v += sw[(w2 * BO + ol) * 2 + st];
        size_t bid = (size_t)blockIdx.x * 1024 + blockIdx.y;   // o-major
        sp[bid * (2 * BO) + ol * 2 + st] = v;
    }
}

// ---------------- reduce fused-conv stat partials + finalize BN in one pass ----------------
template<int BO>
__launch_bounds__(256)
__global__ void stats4red_fin_k(const float* __restrict__ sp,
                                const float* __restrict__ g, const float* __restrict__ bb,
                                float* __restrict__ scale, float* __restrict__ shift,
                                double invcnt) {
    __shared__ double rs[256], rss[256];
    int o = blockIdx.x, tid = threadIdx.x;
    int oy = o / BO, ol = o % BO;
    double s = 0.0, ss = 0.0;
    for (int mb = tid; mb < 1024; mb += 256) {
        size_t bid = (size_t)oy * 1024 + mb;
        s  += (double)sp[bid * (2 * BO) + ol * 2 + 0];
        ss += (double)sp[bid * (2 * BO) + ol * 2 + 1];
    }
    rs[tid] = s; rss[tid] = ss;
    __syncthreads();
    for (int st = 128; st; st >>= 1) {
        if (tid < st) { rs[tid] += rs[tid + st]; rss[tid] += rss[tid + st]; }
        __syncthreads();
    }
    if (tid == 0) {
        double m = rs[0] * invcnt;
        double v = rss[0] * invcnt - m * m;
        if (v < 0.0) v = 0.0;
        float sc = g[o] / sqrtf((float)v + 1e-5f);
        scale[o] = sc;
        shift[o] = bb[o] - (float)m * sc;
    }
}

// ---------------- per-channel sum/sumsq over NHWC y (layers 1,5) ----------------
template<int C8>
__launch_bounds__(256)
__global__ void stats_nhwc_k(const ushort_t* __restrict__ y, double* __restrict__ sum,
                             double* __restrict__ sumsq, int rpb) {
    constexpr int C = C8 * 8;
    constexpr int STRIDE = 256 / C8;
    __shared__ float ls[C][2];
    int tid = threadIdx.x;
    for (int i = tid; i < C * 2; i += 256) ((float*)ls)[i] = 0.0f;
    int cg = tid % C8, mr = tid / C8;
    size_t r0 = (size_t)blockIdx.x * rpb;
    float s[8], ss[8];
#pragma unroll
    for (int e = 0; e < 8; e++) { s[e] = 0.0f; ss[e] = 0.0f; }
    for (int r = mr; r < rpb; r += STRIDE) {
        uint4 u = *(const uint4*)(y + (r0 + r) * C + cg * 8);
        float vv[8]; unpack8(u, vv);
#pragma unroll
        for (int e = 0; e < 8; e++) { s[e] += vv[e]; ss[e] = fmaf(vv[e], vv[e], ss[e]); }
    }
    __syncthreads();
#pragma unroll
    for (int e = 0; e < 8; e++) {
        atomicAdd(&ls[cg * 8 + e][0], s[e]);
        atomicAdd(&ls[cg * 8 + e][1], ss[e]);
    }
    __syncthreads();
    // strided (C can exceed blockDim; round-4 bug)
    for (int c = tid; c < C; c += 256) {
        atomicAdd(&sum[c], (double)ls[c][0]);
        atomicAdd(&sumsq[c], (double)ls[c][1]);
    }
}

// ---------------- finalize BN (layers 1,5) ----------------
__global__ void fin_k(const double* __restrict__ sum, const double* __restrict__ sumsq,
                      const float* __restrict__ g, const float* __restrict__ bb,
                      float* __restrict__ scale, float* __restrict__ shift, int C, double invcnt) {
    int c = blockIdx.x * blockDim.x + threadIdx.x;
    if (c < C) {
        double m = sum[c] * invcnt;
        double v = sumsq[c] * invcnt - m * m;
        if (v < 0.0) v = 0.0;
        float sc = g[c] / sqrtf((float)v + 1e-5f);
        scale[c] = sc;
        shift[c] = bb[c] - (float)m * sc;
    }
}

// ---------------- maxpool over k (BN+ReLU) NHWC -> xcat (layer 1) ----------------
template<int C8>
__launch_bounds__(256)
__global__ void maxpool_nhwc_k(const ushort_t* __restrict__ y, const float* __restrict__ scale,
                               const float* __restrict__ shift, ushort_t* __restrict__ xcat,
                               int coff) {
    constexpr int C = C8 * 8;
    constexpr int PB = 256 / C8;
    int tid = threadIdx.x;
    int cg = tid % C8, pl = tid / C8;
    int p = blockIdx.x * PB + pl;
    float sc[8], sh[8];
    *(float4*)&sc[0] = *(const float4*)(scale + cg * 8);
    *(float4*)&sc[4] = *(const float4*)(scale + cg * 8 + 4);
    *(float4*)&sh[0] = *(const float4*)(shift + cg * 8);
    *(float4*)&sh[4] = *(const float4*)(shift + cg * 8 + 4);
    float mx[8];
#pragma unroll
    for (int e = 0; e < 8; e++) mx[e] = 0.0f;   // relu floor
    size_t base = (size_t)p * KNN * C + cg * 8;
#pragma unroll
    for (int q = 0; q < KNN; q++) {
        uint4 u = *(const uint4*)(y + base + (size_t)q * C);
        float vv[8]; unpack8(u, vv);
#pragma unroll
        for (int e = 0; e < 8; e++) mx[e] = fmaxf(mx[e], fmaf(vv[e], sc[e], sh[e]));
    }
    uint4 u;
    u.x = pack2(mx[0], mx[1]); u.y = pack2(mx[2], mx[3]);
    u.z = pack2(mx[4], mx[5]); u.w = pack2(mx[6], mx[7]);
    *(uint4*)(xcat + (size_t)p * 512 + coff + cg * 8) = u;
}

// ---------------- pool finalize from raw max/min (BN monotone) -> xcat (layers 2,3,4) ----------------
template<int C8>
__launch_bounds__(256)
__global__ void pool_raw_k(const float* __restrict__ rawmax, const float* __restrict__ rawmin,
                           const float* __restrict__ scale, const float* __restrict__ shift,
                           ushort_t* __restrict__ xcat, int coff) {
    constexpr int COUT = C8 * 8;
    int gid = blockIdx.x * 256 + threadIdx.x;   // 16384 * C8
    int p = gid / C8, og = gid % C8;
    float sc[8], sh[8], mxv[8], mnv[8];
    *(float4*)&sc[0]  = *(const float4*)(scale + og * 8);
    *(float4*)&sc[4]  = *(const float4*)(scale + og * 8 + 4);
    *(float4*)&sh[0]  = *(const float4*)(shift + og * 8);
    *(float4*)&sh[4]  = *(const float4*)(shift + og * 8 + 4);
    *(float4*)&mxv[0] = *(const float4*)(rawmax + (size_t)p * COUT + og * 8);
    *(float4*)&mxv[4] = *(const float4*)(rawmax + (size_t)p * COUT + og * 8 + 4);
    *(float4*)&mnv[0] = *(const float4*)(rawmin + (size_t)p * COUT + og * 8);
    *(float4*)&mnv[4] = *(const float4*)(rawmin + (size_t)p * COUT + og * 8 + 4);
    float v[8];
#pragma unroll
    for (int e = 0; e < 8; e++) {
        float raw = (sc[e] >= 0.0f) ? mxv[e] : mnv[e];
        v[e] = fmaxf(fmaf(raw, sc[e], sh[e]), 0.0f);
    }
    uint4 u;
    u.x = pack2(v[0], v[1]); u.y = pack2(v[2], v[3]);
    u.z = pack2(v[4], v[5]); u.w = pack2(v[6], v[7]);
    *(uint4*)(xcat + (size_t)p * 512 + coff + og * 8) = u;
}

// ---------------- output: BN5+ReLU + transpose NHWC -> [b][c][n] fp32 ----------------
__launch_bounds__(256)
__global__ void out_k(const ushort_t* __restrict__ y5, const float* __restrict__ scale,
                      const float* __restrict__ shift, float* __restrict__ out) {
    __shared__ float tr[64 * 65];
    int tid = threadIdx.x;
    int n0 = blockIdx.x * 64, c0 = blockIdx.y * 64, b = blockIdx.z;
    int nl = tid >> 2, cq = (tid & 3) * 16;
    const ushort_t* src = y5 + (size_t)(b * 2048 + n0 + nl) * 512 + c0 + cq;
#pragma unroll
    for (int h = 0; h < 2; h++) {
        uint4 u = *(const uint4*)(src + h * 8);
        float vv[8]; unpack8(u, vv);
#pragma unroll
        for (int e = 0; e < 8; e++) {
            int c = cq + h * 8 + e;
            tr[c * 65 + nl] = fmaxf(fmaf(vv[e], scale[c0 + c], shift[c0 + c]), 0.0f);
        }
    }
    __syncthreads();
    int cl = tid >> 2, ng = (tid & 3) * 16;
#pragma unroll
    for (int g = 0; g < 4; g++) {
        float4 v = *(float4*)&tr[cl * 65 + ng + g * 4];
        *(float4*)(out + ((size_t)b * 512 + c0 + cl) * 2048 + n0 + ng + g * 4) = v;
    }
}

// ---------------- host ----------------
extern "C" void kernel_launch(void* const* d_in, const int* in_sizes, int n_in,
                              void* d_out, int out_size, void* d_ws, size_t ws_size,
                              hipStream_t stream) {
    (void)in_sizes; (void)n_in; (void)out_size;
    if (ws_size < WS_NEEDED) return;
    const float* x  = (const float*)d_in[0];
    const float* w1 = (const float*)d_in[1];
    const float* g1 = (const float*)d_in[2];
    const float* b1 = (const float*)d_in[3];
    const float* w2 = (const float*)d_in[4];
    const float* g2 = (const float*)d_in[5];
    const float* b2 = (const float*)d_in[6];
    const float* w3 = (const float*)d_in[7];
    const float* g3 = (const float*)d_in[8];
    const float* b3 = (const float*)d_in[9];
    const float* w4 = (const float*)d_in[10];
    const float* g4 = (const float*)d_in[11];
    const float* b4 = (const float*)d_in[12];
    const float* w5 = (const float*)d_in[13];
    const float* g5 = (const float*)d_in[14];
    const float* b5 = (const float*)d_in[15];

    char* ws = (char*)d_ws;
    float* xt  = (float*)(ws + OFF_XT);
    float* xx  = (float*)(ws + OFF_XX);
    int*   idx = (int*)(ws + OFF_IDX);
    ushort_t* wh2 = (ushort_t*)(ws + OFF_WH2);
    ushort_t* wh3 = (ushort_t*)(ws + OFF_WH3);
    ushort_t* wh4 = (ushort_t*)(ws + OFF_WH4);
    ushort_t* wh5 = (ushort_t*)(ws + OFF_WH5); ushort_t* wl5 = (ushort_t*)(ws + OFF_WL5);
    ushort_t* y1 = (ushort_t*)(ws + OFF_REG0);
    ushort_t* y2 = (ushort_t*)(ws + OFF_REG1);
    ushort_t* y3 = (ushort_t*)(ws + OFF_REG0);
    ushort_t* y5 = (ushort_t*)(ws + OFF_REG0);
    ushort_t* xcat = (ushort_t*)(ws + OFF_XCAT);
    float* rawmax = (float*)(ws + OFF_RAWMAX);
    float* rawmin = (float*)(ws + OFF_RAWMIN);
    float* sp     = (float*)(ws + OFF_SP);

    double* sum[5]; double* sumsq[5]; float* scl[5]; float* shf[5];
    for (int l = 0; l < 5; l++) {
        sum[l]   = (double*)(ws + OFF_STATS + (size_t)l * 8192);
        sumsq[l] = sum[l] + 512;
        scl[l]   = (float*)(ws + OFF_SS + (size_t)l * 4096);
        shf[l]   = scl[l] + 512;
    }

    hipMemsetAsync(ws + OFF_STATS, 0, 40960, stream);
    prep_k<<<64, 256, 0, stream>>>(x, xt, xx);
    wsplit_all_k<<<1200, 256, 0, stream>>>(w2, wh2, w3, wh3, w4, wh4, w5, wh5, wl5);
    knn_k<<<2048, 256, 0, stream>>>(xt, xx, idx);

    // layer 1
    conv1_k<<<1280, 256, 0, stream>>>(xt, idx, w1, y1);
    stats_nhwc_k<8><<<160, 256, 0, stream>>>(y1, sum[0], sumsq[0], 2048);
    fin_k<<<1, 512, 0, stream>>>(sum[0], sumsq[0], g1, b1, scl[0], shf[0], 64, 1.0 / 327680.0);
    maxpool_nhwc_k<8><<<512, 256, 0, stream>>>(y1, scl[0], shf[0], xcat, 0);

    // layer 2: 64 -> 64 fused (BO=64, 1 o-tile)
    conv_fused_k<64, 64, 64, true><<<dim3(1, 1024), 256, 0, stream>>>(
        y1, wh2, scl[0], shf[0], y2, rawmax, rawmin, sp);
    stats4red_fin_k<64><<<64, 256, 0, stream>>>(sp, g2, b2, scl[1], shf[1], 1.0 / 327680.0);
    pool_raw_k<8><<<512, 256, 0, stream>>>(rawmax, rawmin, scl[1], shf[1], xcat, 64);

    // layer 3: 64 -> 128 fused (BO=128, 1 o-tile: y2 read once)
    conv_fused_k<64, 128, 128, true><<<dim3(1, 1024), 256, 0, stream>>>(
        y2, wh3, scl[1], shf[1], y3, rawmax, rawmin, sp);
    stats4red_fin_k<128><<<128, 256, 0, stream>>>(sp, g3, b3, scl[2], shf[2], 1.0 / 327680.0);
    pool_raw_k<16><<<1024, 256, 0, stream>>>(rawmax, rawmin, scl[2], shf[2], xcat, 128);

    // layer 4: 128 -> 256 fused (BO=128, 2 o-tiles)
    conv_fused_k<128, 256, 128, false><<<dim3(2, 1024), 256, 0, stream>>>(
        y3, wh4, scl[2], shf[2], nullptr, rawmax, rawmin, sp);
    stats4red_fin_k<128><<<256, 256, 0, stream>>>(sp, g4, b4, scl[3], shf[3], 1.0 / 327680.0);
    pool_raw_k<32><<<2048, 256, 0, stream>>>(rawmax, rawmin, scl[3], shf[3], xcat, 256);

    // layer 5: 512 -> 512, hi/lo weights (K=512, feeds output directly)
    conv_mfma_k<512, 512, false><<<dim3(8, 128), 256, 0, stream>>>(xcat, wh5, wl5,
                                                                   nullptr, nullptr, y5);
    stats_nhwc_k<64><<<128, 256, 0, stream>>>(y5, sum[4], sumsq[4], 128);
    fin_k<<<1, 512, 0, stream>>>(sum[4], sumsq[4], g5, b5, scl[4], shf[4], 512, 1.0 / 16384.0);
    out_k<<<dim3(32, 8, 8), 256, 0, stream>>>(y5, scl[4], shf[4], (float*)d_out);
}

// Round 13
// 470.933 us; speedup vs baseline: 2.1040x; 1.0912x over previous
//
#include <hip/hip_runtime.h>
#include <cstdint>
#include <cstddef>

// ---------------- constants ----------------
#define BATCH 8
#define NPTS 2048
#define KNN 20
#define M1 327680   // BATCH*NPTS*KNN
#define M2 16384    // BATCH*NPTS

typedef unsigned short ushort_t;
typedef __attribute__((ext_vector_type(8))) short bf16x8;   // 8 bf16 = 4 VGPRs
typedef __attribute__((ext_vector_type(4))) float f32x4;    // MFMA acc

// ws layout (bytes) — total 181,121,024
#define OFF_XT    0UL          // 196608   float xt[b*n][3]
#define OFF_XX    196608UL     // 65536    float xx[b*n]
#define OFF_IDX   262144UL     // 1310720  int idx[b*n][20]
#define OFF_WH2   1572864UL    // 8192   bf16 [64][64]
#define OFF_WH3   1589248UL    // 16384  bf16 [128][64]
#define OFF_WH4   1622016UL    // 65536  bf16 [256][128]
#define OFF_WH5   1753088UL    // 524288 bf16 [512][512]
#define OFF_SS    2842624UL    // 20480   5 x (512 scale + 512 shift) float
// REG0: y1 [M1][64] (41.9MB) -> y3 [M1][128] (83.9MB) -> y5 [M2][512] (16.8MB)
#define OFF_REG0  2863104UL    // 83886080
// REG1: y2 [M1][64] (41.9MB)
#define OFF_REG1  86749184UL   // 41943040
#define OFF_XCAT  128692224UL  // 16777216 xcat[M2][512] bf16
#define OFF_RAWMAX 145469440UL // 16777216 f32 [16384][<=256]
#define OFF_RAWMIN 162246656UL // 16777216
#define OFF_SP     179023872UL // 2097152  f32 partials
#define WS_NEEDED  181121024UL

// ---------------- helpers ----------------
__device__ __forceinline__ float bf2f(unsigned short u) {
    union { unsigned int i; float f; } c; c.i = ((unsigned int)u) << 16; return c.f;
}
__device__ __forceinline__ unsigned short f2bf(float f) {
    union { float f; unsigned int i; } c; c.f = f;
    unsigned int x = c.i;
    unsigned int r = (x + 0x7fffu + ((x >> 16) & 1u)) >> 16;  // RNE
    return (unsigned short)r;
}
__device__ __forceinline__ unsigned int pack2(float a, float b) {
    return (unsigned int)f2bf(a) | ((unsigned int)f2bf(b) << 16);
}
__device__ __forceinline__ void unpack8(uint4 u, float* v) {
    v[0] = bf2f((unsigned short)(u.x & 0xffffu)); v[1] = bf2f((unsigned short)(u.x >> 16));
    v[2] = bf2f((unsigned short)(u.y & 0xffffu)); v[3] = bf2f((unsigned short)(u.y >> 16));
    v[4] = bf2f((unsigned short)(u.z & 0xffffu)); v[5] = bf2f((unsigned short)(u.z >> 16));
    v[6] = bf2f((unsigned short)(u.w & 0xffffu)); v[7] = bf2f((unsigned short)(u.w >> 16));
}

// ---------------- prep: transpose x, compute xx ----------------
__global__ void prep_k(const float* __restrict__ x, float* __restrict__ xt, float* __restrict__ xx) {
    int t = blockIdx.x * 256 + threadIdx.x;   // 16384
    int b = t >> 11, n = t & 2047;
    float v0 = x[((size_t)b * 3 + 0) * NPTS + n];
    float v1 = x[((size_t)b * 3 + 1) * NPTS + n];
    float v2 = x[((size_t)b * 3 + 2) * NPTS + n];
    xt[(size_t)t * 3 + 0] = v0; xt[(size_t)t * 3 + 1] = v1; xt[(size_t)t * 3 + 2] = v2;
    xx[t] = __fadd_rn(__fadd_rn(__fmul_rn(v0, v0), __fmul_rn(v1, v1)), __fmul_rn(v2, v2));
}

// ---------------- weight prep: single bf16 for all MFMA layers ----------------
__global__ void wsplit_all_k(const float* __restrict__ w2, ushort_t* __restrict__ wh2,
                             const float* __restrict__ w3, ushort_t* __restrict__ wh3,
                             const float* __restrict__ w4, ushort_t* __restrict__ wh4,
                             const float* __restrict__ w5, ushort_t* __restrict__ wh5) {
    int t = blockIdx.x * 256 + threadIdx.x;   // 307200 total
    if (t < 4096)        { wh2[t] = f2bf(w2[t]); }
    else if (t < 12288)  { int o = t - 4096;  wh3[o] = f2bf(w3[o]); }
    else if (t < 45056)  { int o = t - 12288; wh4[o] = f2bf(w4[o]); }
    else                 { int o = t - 45056; wh5[o] = f2bf(w5[o]); }
}

// ---------------- knn: 2 points per wave, tournament + short butterfly ----------------
template<int G>
__device__ __forceinline__ void knn_rescan(float (&v)[32], float (&gm)[4], int (&gq)[4],
                                           bool own, int qw) {
#pragma unroll
    for (int q = G * 8; q < G * 8 + 8; q++)
        if (own && q == qw) v[q] = -3.4e38f;
    float m = v[G * 8]; int qi = G * 8;
#pragma unroll
    for (int q = G * 8 + 1; q < G * 8 + 8; q++)
        if (v[q] > m) { m = v[q]; qi = q; }
    gm[G] = m; gq[G] = qi;
}

__device__ __forceinline__ void knn_round(float (&v)[32], float (&gm)[4], int (&gq)[4],
                                          int* __restrict__ out, int t, int l) {
    float bv = gm[0]; int bq = gq[0];
    if (gm[1] > bv) { bv = gm[1]; bq = gq[1]; }
    if (gm[2] > bv) { bv = gm[2]; bq = gq[2]; }
    if (gm[3] > bv) { bv = gm[3]; bq = gq[3]; }
    int bj = l + bq * 64;
#pragma unroll
    for (int off = 1; off <= 8; off <<= 1) {
        float ov = __shfl_xor(bv, off);
        int   oj = __shfl_xor(bj, off);
        if (ov > bv || (ov == bv && oj < bj)) { bv = ov; bj = oj; }
    }
    int ib = __float_as_int(bv);
    float w0 = __int_as_float(__builtin_amdgcn_readlane(ib, 0));
    float w1 = __int_as_float(__builtin_amdgcn_readlane(ib, 16));
    float w2 = __int_as_float(__builtin_amdgcn_readlane(ib, 32));
    float w3 = __int_as_float(__builtin_amdgcn_readlane(ib, 48));
    int u0 = __builtin_amdgcn_readlane(bj, 0);
    int u1 = __builtin_amdgcn_readlane(bj, 16);
    int u2 = __builtin_amdgcn_readlane(bj, 32);
    int u3 = __builtin_amdgcn_readlane(bj, 48);
    float Bv = w0; int Bj = u0;
    if (w1 > Bv || (w1 == Bv && u1 < Bj)) { Bv = w1; Bj = u1; }
    if (w2 > Bv || (w2 == Bv && u2 < Bj)) { Bv = w2; Bj = u2; }
    if (w3 > Bv || (w3 == Bv && u3 < Bj)) { Bv = w3; Bj = u3; }
    int bju = __builtin_amdgcn_readfirstlane(Bj);
    if (l == 0) out[t] = bju;
    int qw = bju >> 6;
    bool own = (l == (bju & 63));
    int gw = qw >> 3;
    if (gw == 0)      knn_rescan<0>(v, gm, gq, own, qw);
    else if (gw == 1) knn_rescan<1>(v, gm, gq, own, qw);
    else if (gw == 2) knn_rescan<2>(v, gm, gq, own, qw);
    else              knn_rescan<3>(v, gm, gq, own, qw);
}

__launch_bounds__(256)
__global__ void knn_k(const float* __restrict__ xt, const float* __restrict__ xx, int* __restrict__ idx) {
    int tid = threadIdx.x;
    int l = tid & 63, wv = tid >> 6;
    int pidA = blockIdx.x * 8 + wv * 2;
    int pidB = pidA + 1;
    int b = pidA >> 11;
    const float* xb  = xt + (size_t)b * NPTS * 3;
    const float* xxb = xx + (size_t)b * NPTS;
    int iA = pidA & 2047, iB = pidB & 2047;
    float xA0 = xb[iA * 3 + 0], xA1 = xb[iA * 3 + 1], xA2 = xb[iA * 3 + 2];
    float xB0 = xb[iB * 3 + 0], xB1 = xb[iB * 3 + 1], xB2 = xb[iB * 3 + 2];
    float xxA = xxb[iA], xxB = xxb[iB];
    float vA[32], vB[32];
#pragma unroll
    for (int q = 0; q < 32; q++) {
        int j = l + q * 64;
        float p0 = xb[j * 3 + 0], p1 = xb[j * 3 + 1], p2 = xb[j * 3 + 2];
        float xxj = xxb[j];
        float dA = __fadd_rn(__fadd_rn(__fmul_rn(xA0, p0), __fmul_rn(xA1, p1)), __fmul_rn(xA2, p2));
        float dB = __fadd_rn(__fadd_rn(__fmul_rn(xB0, p0), __fmul_rn(xB1, p1)), __fmul_rn(xB2, p2));
        vA[q] = __fsub_rn(__fsub_rn(-xxA, __fmul_rn(-2.0f, dA)), xxj);
        vB[q] = __fsub_rn(__fsub_rn(-xxB, __fmul_rn(-2.0f, dB)), xxj);
    }
    float gmA[4], gmB[4]; int gqA[4], gqB[4];
#pragma unroll
    for (int g = 0; g < 4; g++) {
        float mA = vA[g * 8]; int qA = g * 8;
        float mB = vB[g * 8]; int qB = g * 8;
#pragma unroll
        for (int q = g * 8 + 1; q < g * 8 + 8; q++) {
            if (vA[q] > mA) { mA = vA[q]; qA = q; }
            if (vB[q] > mB) { mB = vB[q]; qB = q; }
        }
        gmA[g] = mA; gqA[g] = qA;
        gmB[g] = mB; gqB[g] = qB;
    }
    int* outA = idx + (size_t)pidA * KNN;
    int* outB = idx + (size_t)pidB * KNN;
    for (int t = 0; t < KNN; t++) {
        knn_round(vA, gmA, gqA, outA, t, l);
        knn_round(vB, gmB, gqB, outB, t, l);
    }
}

// ---------------- conv1 fused MFMA: graph-feature stager (K=32 zero-padded) + conv_fused
// epilogue (raw max/min per k-window + fp32 stats partials + y1 write). BO=64.
__launch_bounds__(256, 2)
__global__ void conv1_fused_k(const float* __restrict__ xt, const int* __restrict__ idx,
                              const float* __restrict__ w1, ushort_t* __restrict__ y1,
                              float* __restrict__ rawmax, float* __restrict__ rawmin,
                              float* __restrict__ sp) {
    __shared__ ushort_t hA[320 * 56];           // wreg overlays this in epilogue
    __shared__ ushort_t wHs[64 * 56];
    __shared__ float sw[4 * 64 * 2];
    const int tid = threadIdx.x;
    const int m0 = blockIdx.x * 320;            // 1024 m-tiles
    for (int i = tid; i < 512; i += 256) sw[i] = 0.0f;
    // stage weights: 64 rows x 32 halfwords (6 real bf16 + zero pad)
    {
        int row = tid >> 2, seg = tid & 3;
        uint4 u = make_uint4(0, 0, 0, 0);
        if (seg == 0) {
            const float* wr = w1 + row * 6;
            u.x = pack2(wr[0], wr[1]);
            u.y = pack2(wr[2], wr[3]);
            u.z = pack2(wr[4], wr[5]);
        }
        *(uint4*)&wHs[row * 56 + seg * 8] = u;
    }
    // stage activations: 320 rows, graph feature computed fp32 -> bf16, K-pad zero
    for (int r = tid; r < 320; r += 256) {
        int m = m0 + r;
        int nb = m / KNN;
        int b = nb >> 11;
        int j = idx[m];
        const float* pi = xt + (size_t)nb * 3;
        const float* pj = xt + ((size_t)(b * NPTS + j)) * 3;
        uint4 u;
        u.x = pack2(pj[0] - pi[0], pj[1] - pi[1]);
        u.y = pack2(pj[2] - pi[2], pi[0]);
        u.z = pack2(pi[1], pi[2]);
        u.w = 0;
        uint4 z = make_uint4(0, 0, 0, 0);
        *(uint4*)&hA[r * 56 + 0]  = u;
        *(uint4*)&hA[r * 56 + 8]  = z;
        *(uint4*)&hA[r * 56 + 16] = z;
        *(uint4*)&hA[r * 56 + 24] = z;
    }
    __syncthreads();
    const int lane = tid & 63, wv = tid >> 6;
    const int l15 = lane & 15, quad = lane >> 4;
    f32x4 acc[5][4];
#pragma unroll
    for (int mt = 0; mt < 5; mt++)
#pragma unroll
        for (int ot = 0; ot < 4; ot++) acc[mt][ot] = (f32x4){0.f, 0.f, 0.f, 0.f};
    bf16x8 a[5];
#pragma unroll
    for (int mt = 0; mt < 5; mt++)
        a[mt] = *(bf16x8*)&hA[(wv * 80 + mt * 16 + l15) * 56 + quad * 8];
#pragma unroll
    for (int ot = 0; ot < 4; ot++) {
        bf16x8 bh = *(bf16x8*)&wHs[(ot * 16 + l15) * 56 + quad * 8];
#pragma unroll
        for (int mt = 0; mt < 5; mt++)
            acc[mt][ot] = __builtin_amdgcn_mfma_f32_16x16x32_bf16(a[mt], bh, acc[mt][ot], 0, 0, 0);
    }
    __syncthreads();   // wreg overlays hA
    float* wreg = (float*)((char*)hA + wv * 6400);   // [80][20]
#pragma unroll
    for (int ot = 0; ot < 4; ot++) {
#pragma unroll
        for (int mt = 0; mt < 5; mt++)
#pragma unroll
            for (int r = 0; r < 4; r++)
                wreg[(mt * 16 + quad * 4 + r) * 20 + l15] = acc[mt][ot][r];
        __syncthreads();   // cross-lane round-trip (r7 lesson)
        {
            int pp = quad;
            const float* rr = wreg + (pp * 20) * 20 + l15;
            float mx = rr[0], mn = rr[0], sm = 0.0f, ss = 0.0f;
#pragma unroll
            for (int q = 0; q < 20; q++) {
                float vv = rr[q * 20];
                mx = fmaxf(mx, vv); mn = fminf(mn, vv);
                sm += vv; ss = fmaf(vv, vv, ss);
            }
            int pt = blockIdx.x * 16 + wv * 4 + pp;
            int o = ot * 16 + l15;
            rawmax[(size_t)pt * 64 + o] = mx;
            rawmin[(size_t)pt * 64 + o] = mn;
            sm += __shfl_xor(sm, 16); sm += __shfl_xor(sm, 32);
            ss += __shfl_xor(ss, 16); ss += __shfl_xor(ss, 32);
            if (lane < 16) {
                sw[(wv * 64 + ot * 16 + l15) * 2 + 0] += sm;
                sw[(wv * 64 + ot * 16 + l15) * 2 + 1] += ss;
            }
        }
        // write y1: 80 rows x 16 o's = 160 chunks of 8 bf16
#pragma unroll
        for (int it = 0; it < 3; it++) {
            int t = lane + it * 64;
            if (t < 160) {
                int row = t >> 1, half = t & 1;
                float4 f0 = *(float4*)&wreg[row * 20 + half * 8];
                float4 f1 = *(float4*)&wreg[row * 20 + half * 8 + 4];
                uint4 u;
                u.x = pack2(f0.x, f0.y); u.y = pack2(f0.z, f0.w);
                u.z = pack2(f1.x, f1.y); u.w = pack2(f1.z, f1.w);
                *(uint4*)(y1 + (size_t)(m0 + wv * 80 + row) * 64 + ot * 16 + half * 8) = u;
            }
        }
        __syncthreads();
    }
    if (tid < 128) {
        int ol = tid >> 1, st = tid & 1;
        float v = 0.0f;
#pragma unroll
        for (int w2 = 0; w2 < 4; w2++) v += sw[(w2 * 64 + ol) * 2 + st];
        sp[(size_t)blockIdx.x * 128 + ol * 2 + st] = v;
    }
}

// ---------------- conv5 MFMA (single-bf16 weights) + fused stats partials ----------------
// Block 128m x 64o; grid (8 o-tiles, 128 m-tiles). Epilogue: column-sum partials from
// live accumulators -> sp, then LDS transpose -> coalesced NHWC y5 stores.
template<int CIN, int COUT>
__launch_bounds__(256)
__global__ void conv5_mfma_k(const ushort_t* __restrict__ yin,
                             const ushort_t* __restrict__ whi,
                             ushort_t* __restrict__ yout,
                             float* __restrict__ sp) {
    __shared__ char smem[23552];
    ushort_t* hA = (ushort_t*)smem;             // [128][56] = 14336
    ushort_t* wH = (ushort_t*)(smem + 14336);   // [64][56]  = 7168
    float* sw = (float*)(smem + 21504);         // [4][64][2] = 2048
    const int tid = threadIdx.x;
    const int m0 = blockIdx.y * 128;
    const int o0 = blockIdx.x * 64;
    f32x4 acc[2][4];
#pragma unroll
    for (int mt = 0; mt < 2; mt++)
#pragma unroll
        for (int ot = 0; ot < 4; ot++) acc[mt][ot] = (f32x4){0.f, 0.f, 0.f, 0.f};
    const int lane = tid & 63, wv = tid >> 6;
    const int l15 = lane & 15, quad = lane >> 4;
    for (int kc = 0; kc < CIN; kc += 32) {
        __syncthreads();
#pragma unroll
        for (int i = 0; i < 2; i++) {
            int tt = tid + 256 * i;
            int mr = tt >> 2, cq = (tt & 3) * 8;
            *(uint4*)&hA[mr * 56 + cq] = *(const uint4*)(yin + (size_t)(m0 + mr) * CIN + kc + cq);
        }
        {
            int orow = tid >> 2, cq = (tid & 3) * 8;
            *(uint4*)&wH[orow * 56 + cq] = *(const uint4*)(whi + (size_t)(o0 + orow) * CIN + kc + cq);
        }
        __syncthreads();
        bf16x8 a0 = *(bf16x8*)&hA[(wv * 32 + l15) * 56 + quad * 8];
        bf16x8 a1 = *(bf16x8*)&hA[(wv * 32 + 16 + l15) * 56 + quad * 8];
#pragma unroll
        for (int ot = 0; ot < 4; ot++) {
            bf16x8 bh = *(bf16x8*)&wH[(ot * 16 + l15) * 56 + quad * 8];
            acc[0][ot] = __builtin_amdgcn_mfma_f32_16x16x32_bf16(a0, bh, acc[0][ot], 0, 0, 0);
            acc[1][ot] = __builtin_amdgcn_mfma_f32_16x16x32_bf16(a1, bh, acc[1][ot], 0, 0, 0);
        }
    }
    // stats partials from live acc (before the barrier; sw indices are per-wave unique)
#pragma unroll
    for (int ot = 0; ot < 4; ot++) {
        float sm = 0.0f, ss = 0.0f;
#pragma unroll
        for (int mt = 0; mt < 2; mt++)
#pragma unroll
            for (int r = 0; r < 4; r++) {
                float v = acc[mt][ot][r];
                sm += v; ss = fmaf(v, v, ss);
            }
        sm += __shfl_xor(sm, 16); sm += __shfl_xor(sm, 32);
        ss += __shfl_xor(ss, 16); ss += __shfl_xor(ss, 32);
        if (lane < 16) {
            sw[(wv * 64 + ot * 16 + l15) * 2 + 0] = sm;
            sw[(wv * 64 + ot * 16 + l15) * 2 + 1] = ss;
        }
    }
    __syncthreads();
    ushort_t* outT = (ushort_t*)smem;   // [128][72] = 18432 (< 21504, sw untouched)
#pragma unroll
    for (int mt = 0; mt < 2; mt++)
#pragma unroll
        for (int ot = 0; ot < 4; ot++)
#pragma unroll
            for (int r = 0; r < 4; r++)
                outT[(wv * 32 + mt * 16 + quad * 4 + r) * 72 + ot * 16 + l15] = f2bf(acc[mt][ot][r]);
    __syncthreads();
    int row = tid >> 1, half = tid & 1;
#pragma unroll
    for (int g = 0; g < 4; g++) {
        uint4 u = *(uint4*)&outT[row * 72 + half * 32 + g * 8];
        *(uint4*)(yout + (size_t)(m0 + row) * COUT + o0 + half * 32 + g * 8) = u;
    }
    if (tid < 128) {
        int ol = tid >> 1, st = tid & 1;
        float v = 0.0f;
#pragma unroll
        for (int w2 = 0; w2 < 4; w2++) v += sw[(w2 * 64 + ol) * 2 + st];
        size_t bid = (size_t)blockIdx.x * gridDim.y + blockIdx.y;
        sp[bid * 128 + ol * 2 + st] = v;
    }
}

// ---------------- fused conv (layers 2,3,4): 320m x BOo tiles, single-bf16 weights ----------------
// LESSONS: (r5/r6) runtime acc index -> scratch demotion: keep acc indexing static.
// (r7) cross-lane LDS round-trip needs __syncthreads() between write/read phases.
template<int CIN, int COUT, int BO, bool WRITEY>
__launch_bounds__(256, 2)
__global__ void conv_fused_k(const ushort_t* __restrict__ yin,
                             const ushort_t* __restrict__ whi,
                             const float* __restrict__ scale,
                             const float* __restrict__ shift,
                             ushort_t* __restrict__ yout,
                             float* __restrict__ rawmax, float* __restrict__ rawmin,
                             float* __restrict__ sp) {
    constexpr int NOT = BO / 16;
    __shared__ ushort_t hA[320 * 56];           // 35840 B; wreg overlays this
    __shared__ ushort_t wHs[BO * 56];
    __shared__ float scl[CIN], shf[CIN];
    __shared__ float sw[4 * BO * 2];
    const int tid = threadIdx.x;
    const int m0 = blockIdx.y * 320;            // 1024 m-tiles
    const int o0 = blockIdx.x * BO;
    for (int c = tid; c < CIN; c += 256) { scl[c] = scale[c]; shf[c] = shift[c]; }
    for (int i = tid; i < 4 * BO * 2; i += 256) sw[i] = 0.0f;
    f32x4 acc[5][NOT];
#pragma unroll
    for (int mt = 0; mt < 5; mt++)
#pragma unroll
        for (int ot = 0; ot < NOT; ot++) acc[mt][ot] = (f32x4){0.f, 0.f, 0.f, 0.f};
    const int lane = tid & 63, wv = tid >> 6;
    const int l15 = lane & 15, quad = lane >> 4;
    for (int kc = 0; kc < CIN; kc += 32) {
        __syncthreads();
#pragma unroll
        for (int i = 0; i < 5; i++) {
            int tt = tid + 256 * i;
            int mr = tt >> 2, cq = (tt & 3) * 8;
            uint4 u = *(const uint4*)(yin + (size_t)(m0 + mr) * CIN + kc + cq);
            float vv[8]; unpack8(u, vv);
#pragma unroll
            for (int e = 0; e < 8; e++)
                vv[e] = fmaxf(fmaf(vv[e], scl[kc + cq + e], shf[kc + cq + e]), 0.0f);
            u.x = pack2(vv[0], vv[1]); u.y = pack2(vv[2], vv[3]);
            u.z = pack2(vv[4], vv[5]); u.w = pack2(vv[6], vv[7]);
            *(uint4*)&hA[mr * 56 + cq] = u;
        }
        for (int t = tid; t < BO * 4; t += 256) {
            int row = t >> 2, cq = (t & 3) * 8;
            *(uint4*)&wHs[row * 56 + cq] = *(const uint4*)(whi + (size_t)(o0 + row) * CIN + kc + cq);
        }
        __syncthreads();
        bf16x8 a[5];
#pragma unroll
        for (int mt = 0; mt < 5; mt++)
            a[mt] = *(bf16x8*)&hA[(wv * 80 + mt * 16 + l15) * 56 + quad * 8];
#pragma unroll
        for (int ot = 0; ot < NOT; ot++) {
            bf16x8 bh = *(bf16x8*)&wHs[(ot * 16 + l15) * 56 + quad * 8];
#pragma unroll
            for (int mt = 0; mt < 5; mt++)
                acc[mt][ot] = __builtin_amdgcn_mfma_f32_16x16x32_bf16(a[mt], bh, acc[mt][ot], 0, 0, 0);
        }
    }
    __syncthreads();   // waves may still read hA/wHs; wreg overlays hA
    float* wreg = (float*)((char*)hA + wv * 6400);   // [80][20]
#pragma unroll
    for (int ot = 0; ot < NOT; ot++) {
#pragma unroll
        for (int mt = 0; mt < 5; mt++)
#pragma unroll
            for (int r = 0; r < 4; r++)
                wreg[(mt * 16 + quad * 4 + r) * 20 + l15] = acc[mt][ot][r];
        __syncthreads();   // cross-lane round-trip (r7 lesson)
        {
            int pp = quad;
            const float* rr = wreg + (pp * 20) * 20 + l15;
            float mx = rr[0], mn = rr[0], sm = 0.0f, ss = 0.0f;
#pragma unroll
            for (int q = 0; q < 20; q++) {
                float vv = rr[q * 20];
                mx = fmaxf(mx, vv); mn = fminf(mn, vv);
                sm += vv; ss = fmaf(vv, vv, ss);
            }
            int pt = blockIdx.y * 16 + wv * 4 + pp;
            int o = o0 + ot * 16 + l15;
            rawmax[(size_t)pt * COUT + o] = mx;
            rawmin[(size_t)pt * COUT + o] = mn;
            sm += __shfl_xor(sm, 16); sm += __shfl_xor(sm, 32);
            ss += __shfl_xor(ss, 16); ss += __shfl_xor(ss, 32);
            if (lane < 16) {
                sw[(wv * BO + ot * 16 + l15) * 2 + 0] += sm;
                sw[(wv * BO + ot * 16 + l15) * 2 + 1] += ss;
            }
        }
        if constexpr (WRITEY) {
#pragma unroll
            for (int it = 0; it < 3; it++) {
                int t = lane + it * 64;
                if (t < 160) {
                    int row = t >> 1, half = t & 1;
                    float4 f0 = *(float4*)&wreg[row * 20 + half * 8];
                    float4 f1 = *(float4*)&wreg[row * 20 + half * 8 + 4];
                    uint4 u;
                    u.x = pack2(f0.x, f0.y); u.y = pack2(f0.z, f0.w);
                    u.z = pack2(f1.x, f1.y); u.w = pack2(f1.z, f1.w);
                    *(uint4*)(yout + (size_t)(m0 + wv * 80 + row) * COUT + o0 + ot * 16 + half * 8) = u;
                }
            }
        }
        __syncthreads();
    }
    for (int t2 = tid; t2 < BO * 2; t2 += 256) {
        int ol = t2 >> 1, st = t2 & 1;
        float v = 0.0f;
#pragma unroll
        for (int w2 = 0; w2 < 4; w2++) v += sw[(w2 * BO + ol) * 2 + st];
        size_t bid = (size_t)blockIdx.x * 1024 + blockIdx.y;   // o-major
        sp[bid * (2 * BO) + ol * 2 + st] = v;
    }
}

// ---------------- reduce stats partials + finalize BN (all layers) ----------------
template<int BO, int MB>
__launch_bounds__(256)
__global__ void statsred_fin_k(const float* __restrict__ sp,
                               const float* __restrict__ g, const float* __restrict__ bb,
                               float* __restrict__ scale, float* __restrict__ shift,
                               double invcnt) {
    __shared__ double rs[256], rss[256];
    int o = blockIdx.x, tid = threadIdx.x;
    int oy = o / BO, ol = o % BO;
    double s = 0.0, ss = 0.0;
    for (int mb = tid; mb < MB; mb += 256) {
        size_t bid = (size_t)oy * MB + mb;
        s  += (double)sp[bid * (2 * BO) + ol * 2 + 0];
        ss += (double)sp[bid * (2 * BO) + ol * 2 + 1];
    }
    rs[tid] = s; rss[tid] = ss;
    __syncthreads();
    for (int st = 128; st; st >>= 1) {
        if (tid < st) { rs[tid] += rs[tid + st]; rss[tid] += rss[tid + st]; }
        __syncthreads();
    }
    if (tid == 0) {
        double m = rs[0] * invcnt;
        double v = rss[0] * invcnt - m * m;
        if (v < 0.0) v = 0.0;
        float sc = g[o] / sqrtf((float)v + 1e-5f);
        scale[o] = sc;
        shift[o] = bb[o] - (float)m * sc;
    }
}

// ---------------- pool finalize from raw max/min (BN monotone) -> xcat ----------------
template<int C8>
__launch_bounds__(256)
__global__ void pool_raw_k(const float* __restrict__ rawmax, const float* __restrict__ rawmin,
                           const float* __restrict__ scale, const float* __restrict__ shift,
                           ushort_t* __restrict__ xcat, int coff) {
    constexpr int COUT = C8 * 8;
    int gid = blockIdx.x * 256 + threadIdx.x;   // 16384 * C8
    int p = gid / C8, og = gid % C8;
    float sc[8], sh[8], mxv[8], mnv[8];
    *(float4*)&sc[0]  = *(const float4*)(scale + og * 8);
    *(float4*)&sc[4]  = *(const float4*)(scale + og * 8 + 4);
    *(float4*)&sh[0]  = *(const float4*)(shift + og * 8);
    *(float4*)&sh[4]  = *(const float4*)(shift + og * 8 + 4);
    *(float4*)&mxv[0] = *(const float4*)(rawmax + (size_t)p * COUT + og * 8);
    *(float4*)&mxv[4] = *(const float4*)(rawmax + (size_t)p * COUT + og * 8 + 4);
    *(float4*)&mnv[0] = *(const float4*)(rawmin + (size_t)p * COUT + og * 8);
    *(float4*)&mnv[4] = *(const float4*)(rawmin + (size_t)p * COUT + og * 8 + 4);
    float v[8];
#pragma unroll
    for (int e = 0; e < 8; e++) {
        float raw = (sc[e] >= 0.0f) ? mxv[e] : mnv[e];
        v[e] = fmaxf(fmaf(raw, sc[e], sh[e]), 0.0f);
    }
    uint4 u;
    u.x = pack2(v[0], v[1]); u.y = pack2(v[2], v[3]);
    u.z = pack2(v[4], v[5]); u.w = pack2(v[6], v[7]);
    *(uint4*)(xcat + (size_t)p * 512 + coff + og * 8) = u;
}

// ---------------- output: BN5+ReLU + transpose NHWC -> [b][c][n] fp32 ----------------
__launch_bounds__(256)
__global__ void out_k(const ushort_t* __restrict__ y5, const float* __restrict__ scale,
                      const float* __restrict__ shift, float* __restrict__ out) {
    __shared__ float tr[64 * 65];
    int tid = threadIdx.x;
    int n0 = blockIdx.x * 64, c0 = blockIdx.y * 64, b = blockIdx.z;
    int nl = tid >> 2, cq = (tid & 3) * 16;
    const ushort_t* src = y5 + (size_t)(b * 2048 + n0 + nl) * 512 + c0 + cq;
#pragma unroll
    for (int h = 0; h < 2; h++) {
        uint4 u = *(const uint4*)(src + h * 8);
        float vv[8]; unpack8(u, vv);
#pragma unroll
        for (int e = 0; e < 8; e++) {
            int c = cq + h * 8 + e;
            tr[c * 65 + nl] = fmaxf(fmaf(vv[e], scale[c0 + c], shift[c0 + c]), 0.0f);
        }
    }
    __syncthreads();
    int cl = tid >> 2, ng = (tid & 3) * 16;
#pragma unroll
    for (int g = 0; g < 4; g++) {
        float4 v = *(float4*)&tr[cl * 65 + ng + g * 4];
        *(float4*)(out + ((size_t)b * 512 + c0 + cl) * 2048 + n0 + ng + g * 4) = v;
    }
}

// ---------------- host ----------------
extern "C" void kernel_launch(void* const* d_in, const int* in_sizes, int n_in,
                              void* d_out, int out_size, void* d_ws, size_t ws_size,
                              hipStream_t stream) {
    (void)in_sizes; (void)n_in; (void)out_size;
    if (ws_size < WS_NEEDED) return;
    const float* x  = (const float*)d_in[0];
    const float* w1 = (const float*)d_in[1];
    const float* g1 = (const float*)d_in[2];
    const float* b1 = (const float*)d_in[3];
    const float* w2 = (const float*)d_in[4];
    const float* g2 = (const float*)d_in[5];
    const float* b2 = (const float*)d_in[6];
    const float* w3 = (const float*)d_in[7];
    const float* g3 = (const float*)d_in[8];
    const float* b3 = (const float*)d_in[9];
    const float* w4 = (const float*)d_in[10];
    const float* g4 = (const float*)d_in[11];
    const float* b4 = (const float*)d_in[12];
    const float* w5 = (const float*)d_in[13];
    const float* g5 = (const float*)d_in[14];
    const float* b5 = (const float*)d_in[15];

    char* ws = (char*)d_ws;
    float* xt  = (float*)(ws + OFF_XT);
    float* xx  = (float*)(ws + OFF_XX);
    int*   idx = (int*)(ws + OFF_IDX);
    ushort_t* wh2 = (ushort_t*)(ws + OFF_WH2);
    ushort_t* wh3 = (ushort_t*)(ws + OFF_WH3);
    ushort_t* wh4 = (ushort_t*)(ws + OFF_WH4);
    ushort_t* wh5 = (ushort_t*)(ws + OFF_WH5);
    ushort_t* y1 = (ushort_t*)(ws + OFF_REG0);
    ushort_t* y2 = (ushort_t*)(ws + OFF_REG1);
    ushort_t* y3 = (ushort_t*)(ws + OFF_REG0);
    ushort_t* y5 = (ushort_t*)(ws + OFF_REG0);
    ushort_t* xcat = (ushort_t*)(ws + OFF_XCAT);
    float* rawmax = (float*)(ws + OFF_RAWMAX);
    float* rawmin = (float*)(ws + OFF_RAWMIN);
    float* sp     = (float*)(ws + OFF_SP);

    float* scl[5]; float* shf[5];
    for (int l = 0; l < 5; l++) {
        scl[l] = (float*)(ws + OFF_SS + (size_t)l * 4096);
        shf[l] = scl[l] + 512;
    }

    prep_k<<<64, 256, 0, stream>>>(x, xt, xx);
    wsplit_all_k<<<1200, 256, 0, stream>>>(w2, wh2, w3, wh3, w4, wh4, w5, wh5);
    knn_k<<<2048, 256, 0, stream>>>(xt, xx, idx);

    // layer 1: fused graph-feature + conv + raw pool + stats (BO=64)
    conv1_fused_k<<<1024, 256, 0, stream>>>(xt, idx, w1, y1, rawmax, rawmin, sp);
    statsred_fin_k<64, 1024><<<64, 256, 0, stream>>>(sp, g1, b1, scl[0], shf[0], 1.0 / 327680.0);
    pool_raw_k<8><<<512, 256, 0, stream>>>(rawmax, rawmin, scl[0], shf[0], xcat, 0);

    // layer 2: 64 -> 64 fused (BO=64)
    conv_fused_k<64, 64, 64, true><<<dim3(1, 1024), 256, 0, stream>>>(
        y1, wh2, scl[0], shf[0], y2, rawmax, rawmin, sp);
    statsred_fin_k<64, 1024><<<64, 256, 0, stream>>>(sp, g2, b2, scl[1], shf[1], 1.0 / 327680.0);
    pool_raw_k<8><<<512, 256, 0, stream>>>(rawmax, rawmin, scl[1], shf[1], xcat, 64);

    // layer 3: 64 -> 128 fused (BO=128)
    conv_fused_k<64, 128, 128, true><<<dim3(1, 1024), 256, 0, stream>>>(
        y2, wh3, scl[1], shf[1], y3, rawmax, rawmin, sp);
    statsred_fin_k<128, 1024><<<128, 256, 0, stream>>>(sp, g3, b3, scl[2], shf[2], 1.0 / 327680.0);
    pool_raw_k<16><<<1024, 256, 0, stream>>>(rawmax, rawmin, scl[2], shf[2], xcat, 128);

    // layer 4: 128 -> 256 fused (BO=128, 2 o-tiles)
    conv_fused_k<128, 256, 128, false><<<dim3(2, 1024), 256, 0, stream>>>(
        y3, wh4, scl[2], shf[2], nullptr, rawmax, rawmin, sp);
    statsred_fin_k<128, 1024><<<256, 256, 0, stream>>>(sp, g4, b4, scl[3], shf[3], 1.0 / 327680.0);
    pool_raw_k<32><<<2048, 256, 0, stream>>>(rawmax, rawmin, scl[3], shf[3], xcat, 256);

    // layer 5: 512 -> 512, single-bf16 weights, stats fused
    conv5_mfma_k<512, 512><<<dim3(8, 128), 256, 0, stream>>>(xcat, wh5, y5, sp);
    statsred_fin_k<64, 128><<<512, 256, 0, stream>>>(sp, g5, b5, scl[4], shf[4], 1.0 / 16384.0);
    out_k<<<dim3(32, 8, 8), 256, 0, stream>>>(y5, scl[4], shf[4], (float*)d_out);
}

// Round 14
// 454.147 us; speedup vs baseline: 2.1817x; 1.0370x over previous
//
#include <hip/hip_runtime.h>
#include <cstdint>
#include <cstddef>

// ---------------- constants ----------------
#define BATCH 8
#define NPTS 2048
#define KNN 20
#define M1 327680   // BATCH*NPTS*KNN
#define M2 16384    // BATCH*NPTS

typedef unsigned short ushort_t;
typedef __attribute__((ext_vector_type(8))) short bf16x8;   // 8 bf16 = 4 VGPRs
typedef __attribute__((ext_vector_type(4))) float f32x4;    // MFMA acc

// ws layout (bytes) — total 181,121,024
#define OFF_XT    0UL          // 196608   float xt[b*n][3]
#define OFF_XX    196608UL     // 65536    float xx[b*n]
#define OFF_IDX   262144UL     // 1310720  int idx[b*n][20]
#define OFF_WH2   1572864UL    // 8192   bf16 [64][64]
#define OFF_WH3   1589248UL    // 16384  bf16 [128][64]
#define OFF_WH4   1622016UL    // 65536  bf16 [256][128]
#define OFF_WH5   1753088UL    // 524288 bf16 [512][512]
#define OFF_SS    2842624UL    // 20480   5 x (512 scale + 512 shift) float
// REG0: y1 [M1][64] (41.9MB) -> y3 [M1][128] (83.9MB) -> y5 [M2][512] (16.8MB)
#define OFF_REG0  2863104UL    // 83886080
// REG1: y2 [M1][64] (41.9MB)
#define OFF_REG1  86749184UL   // 41943040
#define OFF_XCAT  128692224UL  // 16777216 xcat[M2][512] bf16
#define OFF_RAWMAX 145469440UL // 16777216 f32 [16384][<=256]
#define OFF_RAWMIN 162246656UL // 16777216
#define OFF_SP     179023872UL // 2097152  f32 partials
#define WS_NEEDED  181121024UL

// ---------------- helpers ----------------
__device__ __forceinline__ float bf2f(unsigned short u) {
    union { unsigned int i; float f; } c; c.i = ((unsigned int)u) << 16; return c.f;
}
__device__ __forceinline__ unsigned short f2bf(float f) {
    union { float f; unsigned int i; } c; c.f = f;
    unsigned int x = c.i;
    unsigned int r = (x + 0x7fffu + ((x >> 16) & 1u)) >> 16;  // RNE
    return (unsigned short)r;
}
__device__ __forceinline__ unsigned int pack2(float a, float b) {
    return (unsigned int)f2bf(a) | ((unsigned int)f2bf(b) << 16);
}
__device__ __forceinline__ void unpack8(uint4 u, float* v) {
    v[0] = bf2f((unsigned short)(u.x & 0xffffu)); v[1] = bf2f((unsigned short)(u.x >> 16));
    v[2] = bf2f((unsigned short)(u.y & 0xffffu)); v[3] = bf2f((unsigned short)(u.y >> 16));
    v[4] = bf2f((unsigned short)(u.z & 0xffffu)); v[5] = bf2f((unsigned short)(u.z >> 16));
    v[6] = bf2f((unsigned short)(u.w & 0xffffu)); v[7] = bf2f((unsigned short)(u.w >> 16));
}

// DPP row_ror:n within 16-lane rows — VALU-pipe lane exchange, no DS traffic.
#define DPP_ROR(x, n) __builtin_amdgcn_update_dpp(0, (x), 0x120 + (n), 0xf, 0xf, true)

// ---------------- prep: transpose x, compute xx ----------------
__global__ void prep_k(const float* __restrict__ x, float* __restrict__ xt, float* __restrict__ xx) {
    int t = blockIdx.x * 256 + threadIdx.x;   // 16384
    int b = t >> 11, n = t & 2047;
    float v0 = x[((size_t)b * 3 + 0) * NPTS + n];
    float v1 = x[((size_t)b * 3 + 1) * NPTS + n];
    float v2 = x[((size_t)b * 3 + 2) * NPTS + n];
    xt[(size_t)t * 3 + 0] = v0; xt[(size_t)t * 3 + 1] = v1; xt[(size_t)t * 3 + 2] = v2;
    xx[t] = __fadd_rn(__fadd_rn(__fmul_rn(v0, v0), __fmul_rn(v1, v1)), __fmul_rn(v2, v2));
}

// ---------------- weight prep: single bf16 for all MFMA layers ----------------
__global__ void wsplit_all_k(const float* __restrict__ w2, ushort_t* __restrict__ wh2,
                             const float* __restrict__ w3, ushort_t* __restrict__ wh3,
                             const float* __restrict__ w4, ushort_t* __restrict__ wh4,
                             const float* __restrict__ w5, ushort_t* __restrict__ wh5) {
    int t = blockIdx.x * 256 + threadIdx.x;   // 307200 total
    if (t < 4096)        { wh2[t] = f2bf(w2[t]); }
    else if (t < 12288)  { int o = t - 4096;  wh3[o] = f2bf(w3[o]); }
    else if (t < 45056)  { int o = t - 12288; wh4[o] = f2bf(w4[o]); }
    else                 { int o = t - 45056; wh5[o] = f2bf(w5[o]); }
}

// ---------------- knn: 2 points per wave, tournament + DPP-rotation reduce ----------------
// r14: __shfl_xor butterfly = ds_swizzle/ds_bpermute -> DS-pipe saturation at ~24
// waves/CU (r9-r11 VALU-side cuts all neutral, VALUBusy stuck at 60%). Replaced with
// DPP row_ror rotation all-reduce (VALU pipe, zero DS) + readlane cross-row tree.
template<int G>
__device__ __forceinline__ void knn_rescan(float (&v)[32], float (&gm)[4], int (&gq)[4],
                                           bool own, int qw) {
#pragma unroll
    for (int q = G * 8; q < G * 8 + 8; q++)
        if (own && q == qw) v[q] = -3.4e38f;
    float m = v[G * 8]; int qi = G * 8;
#pragma unroll
    for (int q = G * 8 + 1; q < G * 8 + 8; q++)
        if (v[q] > m) { m = v[q]; qi = q; }
    gm[G] = m; gq[G] = qi;
}

__device__ __forceinline__ void knn_round(float (&v)[32], float (&gm)[4], int (&gq)[4],
                                          int* __restrict__ out, int t, int l) {
    float bv = gm[0]; int bq = gq[0];
    if (gm[1] > bv) { bv = gm[1]; bq = gq[1]; }
    if (gm[2] > bv) { bv = gm[2]; bq = gq[2]; }
    if (gm[3] > bv) { bv = gm[3]; bq = gq[3]; }
    int bj = l + bq * 64;
    // rotation all-reduce within each 16-lane row (lex max over (value desc, idx asc))
    {
        float ov; int oj;
        ov = __int_as_float(DPP_ROR(__float_as_int(bv), 1)); oj = DPP_ROR(bj, 1);
        if (ov > bv || (ov == bv && oj < bj)) { bv = ov; bj = oj; }
        ov = __int_as_float(DPP_ROR(__float_as_int(bv), 2)); oj = DPP_ROR(bj, 2);
        if (ov > bv || (ov == bv && oj < bj)) { bv = ov; bj = oj; }
        ov = __int_as_float(DPP_ROR(__float_as_int(bv), 4)); oj = DPP_ROR(bj, 4);
        if (ov > bv || (ov == bv && oj < bj)) { bv = ov; bj = oj; }
        ov = __int_as_float(DPP_ROR(__float_as_int(bv), 8)); oj = DPP_ROR(bj, 8);
        if (ov > bv || (ov == bv && oj < bj)) { bv = ov; bj = oj; }
    }
    // rows converged; resolve the 4 row winners via readlane (no DS) + uniform tree
    int ib = __float_as_int(bv);
    float w0 = __int_as_float(__builtin_amdgcn_readlane(ib, 0));
    float w1 = __int_as_float(__builtin_amdgcn_readlane(ib, 16));
    float w2 = __int_as_float(__builtin_amdgcn_readlane(ib, 32));
    float w3 = __int_as_float(__builtin_amdgcn_readlane(ib, 48));
    int u0 = __builtin_amdgcn_readlane(bj, 0);
    int u1 = __builtin_amdgcn_readlane(bj, 16);
    int u2 = __builtin_amdgcn_readlane(bj, 32);
    int u3 = __builtin_amdgcn_readlane(bj, 48);
    float Bv = w0; int Bj = u0;
    if (w1 > Bv || (w1 == Bv && u1 < Bj)) { Bv = w1; Bj = u1; }
    if (w2 > Bv || (w2 == Bv && u2 < Bj)) { Bv = w2; Bj = u2; }
    if (w3 > Bv || (w3 == Bv && u3 < Bj)) { Bv = w3; Bj = u3; }
    int bju = __builtin_amdgcn_readfirstlane(Bj);
    if (l == 0) out[t] = bju;
    int qw = bju >> 6;
    bool own = (l == (bju & 63));
    int gw = qw >> 3;
    if (gw == 0)      knn_rescan<0>(v, gm, gq, own, qw);
    else if (gw == 1) knn_rescan<1>(v, gm, gq, own, qw);
    else if (gw == 2) knn_rescan<2>(v, gm, gq, own, qw);
    else              knn_rescan<3>(v, gm, gq, own, qw);
}

__launch_bounds__(256)
__global__ void knn_k(const float* __restrict__ xt, const float* __restrict__ xx, int* __restrict__ idx) {
    int tid = threadIdx.x;
    int l = tid & 63, wv = tid >> 6;
    int pidA = blockIdx.x * 8 + wv * 2;
    int pidB = pidA + 1;
    int b = pidA >> 11;
    const float* xb  = xt + (size_t)b * NPTS * 3;
    const float* xxb = xx + (size_t)b * NPTS;
    int iA = pidA & 2047, iB = pidB & 2047;
    float xA0 = xb[iA * 3 + 0], xA1 = xb[iA * 3 + 1], xA2 = xb[iA * 3 + 2];
    float xB0 = xb[iB * 3 + 0], xB1 = xb[iB * 3 + 1], xB2 = xb[iB * 3 + 2];
    float xxA = xxb[iA], xxB = xxb[iB];
    float vA[32], vB[32];
#pragma unroll
    for (int q = 0; q < 32; q++) {
        int j = l + q * 64;
        float p0 = xb[j * 3 + 0], p1 = xb[j * 3 + 1], p2 = xb[j * 3 + 2];
        float xxj = xxb[j];
        float dA = __fadd_rn(__fadd_rn(__fmul_rn(xA0, p0), __fmul_rn(xA1, p1)), __fmul_rn(xA2, p2));
        float dB = __fadd_rn(__fadd_rn(__fmul_rn(xB0, p0), __fmul_rn(xB1, p1)), __fmul_rn(xB2, p2));
        vA[q] = __fsub_rn(__fsub_rn(-xxA, __fmul_rn(-2.0f, dA)), xxj);
        vB[q] = __fsub_rn(__fsub_rn(-xxB, __fmul_rn(-2.0f, dB)), xxj);
    }
    float gmA[4], gmB[4]; int gqA[4], gqB[4];
#pragma unroll
    for (int g = 0; g < 4; g++) {
        float mA = vA[g * 8]; int qA = g * 8;
        float mB = vB[g * 8]; int qB = g * 8;
#pragma unroll
        for (int q = g * 8 + 1; q < g * 8 + 8; q++) {
            if (vA[q] > mA) { mA = vA[q]; qA = q; }
            if (vB[q] > mB) { mB = vB[q]; qB = q; }
        }
        gmA[g] = mA; gqA[g] = qA;
        gmB[g] = mB; gqB[g] = qB;
    }
    int* outA = idx + (size_t)pidA * KNN;
    int* outB = idx + (size_t)pidB * KNN;
    for (int t = 0; t < KNN; t++) {
        knn_round(vA, gmA, gqA, outA, t, l);
        knn_round(vB, gmB, gqB, outB, t, l);
    }
}

// ---------------- conv1 fused MFMA: graph-feature stager (K=32 zero-padded) + conv_fused
// epilogue (raw max/min per k-window + fp32 stats partials + y1 write). BO=64.
__launch_bounds__(256, 2)
__global__ void conv1_fused_k(const float* __restrict__ xt, const int* __restrict__ idx,
                              const float* __restrict__ w1, ushort_t* __restrict__ y1,
                              float* __restrict__ rawmax, float* __restrict__ rawmin,
                              float* __restrict__ sp) {
    __shared__ ushort_t hA[320 * 56];           // wreg overlays this in epilogue
    __shared__ ushort_t wHs[64 * 56];
    __shared__ float sw[4 * 64 * 2];
    const int tid = threadIdx.x;
    const int m0 = blockIdx.x * 320;            // 1024 m-tiles
    for (int i = tid; i < 512; i += 256) sw[i] = 0.0f;
    {
        int row = tid >> 2, seg = tid & 3;
        uint4 u = make_uint4(0, 0, 0, 0);
        if (seg == 0) {
            const float* wr = w1 + row * 6;
            u.x = pack2(wr[0], wr[1]);
            u.y = pack2(wr[2], wr[3]);
            u.z = pack2(wr[4], wr[5]);
        }
        *(uint4*)&wHs[row * 56 + seg * 8] = u;
    }
    for (int r = tid; r < 320; r += 256) {
        int m = m0 + r;
        int nb = m / KNN;
        int b = nb >> 11;
        int j = idx[m];
        const float* pi = xt + (size_t)nb * 3;
        const float* pj = xt + ((size_t)(b * NPTS + j)) * 3;
        uint4 u;
        u.x = pack2(pj[0] - pi[0], pj[1] - pi[1]);
        u.y = pack2(pj[2] - pi[2], pi[0]);
        u.z = pack2(pi[1], pi[2]);
        u.w = 0;
        uint4 z = make_uint4(0, 0, 0, 0);
        *(uint4*)&hA[r * 56 + 0]  = u;
        *(uint4*)&hA[r * 56 + 8]  = z;
        *(uint4*)&hA[r * 56 + 16] = z;
        *(uint4*)&hA[r * 56 + 24] = z;
    }
    __syncthreads();
    const int lane = tid & 63, wv = tid >> 6;
    const int l15 = lane & 15, quad = lane >> 4;
    f32x4 acc[5][4];
#pragma unroll
    for (int mt = 0; mt < 5; mt++)
#pragma unroll
        for (int ot = 0; ot < 4; ot++) acc[mt][ot] = (f32x4){0.f, 0.f, 0.f, 0.f};
    bf16x8 a[5];
#pragma unroll
    for (int mt = 0; mt < 5; mt++)
        a[mt] = *(bf16x8*)&hA[(wv * 80 + mt * 16 + l15) * 56 + quad * 8];
#pragma unroll
    for (int ot = 0; ot < 4; ot++) {
        bf16x8 bh = *(bf16x8*)&wHs[(ot * 16 + l15) * 56 + quad * 8];
#pragma unroll
        for (int mt = 0; mt < 5; mt++)
            acc[mt][ot] = __builtin_amdgcn_mfma_f32_16x16x32_bf16(a[mt], bh, acc[mt][ot], 0, 0, 0);
    }
    __syncthreads();   // wreg overlays hA
    float* wreg = (float*)((char*)hA + wv * 6400);   // [80][20]
#pragma unroll
    for (int ot = 0; ot < 4; ot++) {
#pragma unroll
        for (int mt = 0; mt < 5; mt++)
#pragma unroll
            for (int r = 0; r < 4; r++)
                wreg[(mt * 16 + quad * 4 + r) * 20 + l15] = acc[mt][ot][r];
        __syncthreads();   // cross-lane round-trip (r7 lesson)
        {
            int pp = quad;
            const float* rr = wreg + (pp * 20) * 20 + l15;
            float mx = rr[0], mn = rr[0], sm = 0.0f, ss = 0.0f;
#pragma unroll
            for (int q = 0; q < 20; q++) {
                float vv = rr[q * 20];
                mx = fmaxf(mx, vv); mn = fminf(mn, vv);
                sm += vv; ss = fmaf(vv, vv, ss);
            }
            int pt = blockIdx.x * 16 + wv * 4 + pp;
            int o = ot * 16 + l15;
            rawmax[(size_t)pt * 64 + o] = mx;
            rawmin[(size_t)pt * 64 + o] = mn;
            sm += __shfl_xor(sm, 16); sm += __shfl_xor(sm, 32);
            ss += __shfl_xor(ss, 16); ss += __shfl_xor(ss, 32);
            if (lane < 16) {
                sw[(wv * 64 + ot * 16 + l15) * 2 + 0] += sm;
                sw[(wv * 64 + ot * 16 + l15) * 2 + 1] += ss;
            }
        }
#pragma unroll
        for (int it = 0; it < 3; it++) {
            int t = lane + it * 64;
            if (t < 160) {
                int row = t >> 1, half = t & 1;
                float4 f0 = *(float4*)&wreg[row * 20 + half * 8];
                float4 f1 = *(float4*)&wreg[row * 20 + half * 8 + 4];
                uint4 u;
                u.x = pack2(f0.x, f0.y); u.y = pack2(f0.z, f0.w);
                u.z = pack2(f1.x, f1.y); u.w = pack2(f1.z, f1.w);
                *(uint4*)(y1 + (size_t)(m0 + wv * 80 + row) * 64 + ot * 16 + half * 8) = u;
            }
        }
        __syncthreads();
    }
    if (tid < 128) {
        int ol = tid >> 1, st = tid & 1;
        float v = 0.0f;
#pragma unroll
        for (int w2 = 0; w2 < 4; w2++) v += sw[(w2 * 64 + ol) * 2 + st];
        sp[(size_t)blockIdx.x * 128 + ol * 2 + st] = v;
    }
}

// ---------------- conv5 MFMA (single-bf16 weights) + fused stats partials ----------------
template<int CIN, int COUT>
__launch_bounds__(256)
__global__ void conv5_mfma_k(const ushort_t* __restrict__ yin,
                             const ushort_t* __restrict__ whi,
                             ushort_t* __restrict__ yout,
                             float* __restrict__ sp) {
    __shared__ char smem[23552];
    ushort_t* hA = (ushort_t*)smem;             // [128][56] = 14336
    ushort_t* wH = (ushort_t*)(smem + 14336);   // [64][56]  = 7168
    float* sw = (float*)(smem + 21504);         // [4][64][2] = 2048
    const int tid = threadIdx.x;
    const int m0 = blockIdx.y * 128;
    const int o0 = blockIdx.x * 64;
    f32x4 acc[2][4];
#pragma unroll
    for (int mt = 0; mt < 2; mt++)
#pragma unroll
        for (int ot = 0; ot < 4; ot++) acc[mt][ot] = (f32x4){0.f, 0.f, 0.f, 0.f};
    const int lane = tid & 63, wv = tid >> 6;
    const int l15 = lane & 15, quad = lane >> 4;
    for (int kc = 0; kc < CIN; kc += 32) {
        __syncthreads();
#pragma unroll
        for (int i = 0; i < 2; i++) {
            int tt = tid + 256 * i;
            int mr = tt >> 2, cq = (tt & 3) * 8;
            *(uint4*)&hA[mr * 56 + cq] = *(const uint4*)(yin + (size_t)(m0 + mr) * CIN + kc + cq);
        }
        {
            int orow = tid >> 2, cq = (tid & 3) * 8;
            *(uint4*)&wH[orow * 56 + cq] = *(const uint4*)(whi + (size_t)(o0 + orow) * CIN + kc + cq);
        }
        __syncthreads();
        bf16x8 a0 = *(bf16x8*)&hA[(wv * 32 + l15) * 56 + quad * 8];
        bf16x8 a1 = *(bf16x8*)&hA[(wv * 32 + 16 + l15) * 56 + quad * 8];
#pragma unroll
        for (int ot = 0; ot < 4; ot++) {
            bf16x8 bh = *(bf16x8*)&wH[(ot * 16 + l15) * 56 + quad * 8];
            acc[0][ot] = __builtin_amdgcn_mfma_f32_16x16x32_bf16(a0, bh, acc[0][ot], 0, 0, 0);
            acc[1][ot] = __builtin_amdgcn_mfma_f32_16x16x32_bf16(a1, bh, acc[1][ot], 0, 0, 0);
        }
    }
#pragma unroll
    for (int ot = 0; ot < 4; ot++) {
        float sm = 0.0f, ss = 0.0f;
#pragma unroll
        for (int mt = 0; mt < 2; mt++)
#pragma unroll
            for (int r = 0; r < 4; r++) {
                float v = acc[mt][ot][r];
                sm += v; ss = fmaf(v, v, ss);
            }
        sm += __shfl_xor(sm, 16); sm += __shfl_xor(sm, 32);
        ss += __shfl_xor(ss, 16); ss += __shfl_xor(ss, 32);
        if (lane < 16) {
            sw[(wv * 64 + ot * 16 + l15) * 2 + 0] = sm;
            sw[(wv * 64 + ot * 16 + l15) * 2 + 1] = ss;
        }
    }
    __syncthreads();
    ushort_t* outT = (ushort_t*)smem;   // [128][72] = 18432 (< 21504, sw untouched)
#pragma unroll
    for (int mt = 0; mt < 2; mt++)
#pragma unroll
        for (int ot = 0; ot < 4; ot++)
#pragma unroll
            for (int r = 0; r < 4; r++)
                outT[(wv * 32 + mt * 16 + quad * 4 + r) * 72 + ot * 16 + l15] = f2bf(acc[mt][ot][r]);
    __syncthreads();
    int row = tid >> 1, half = tid & 1;
#pragma unroll
    for (int g = 0; g < 4; g++) {
        uint4 u = *(uint4*)&outT[row * 72 + half * 32 + g * 8];
        *(uint4*)(yout + (size_t)(m0 + row) * COUT + o0 + half * 32 + g * 8) = u;
    }
    if (tid < 128) {
        int ol = tid >> 1, st = tid & 1;
        float v = 0.0f;
#pragma unroll
        for (int w2 = 0; w2 < 4; w2++) v += sw[(w2 * 64 + ol) * 2 + st];
        size_t bid = (size_t)blockIdx.x * gridDim.y + blockIdx.y;
        sp[bid * 128 + ol * 2 + st] = v;
    }
}

// ---------------- fused conv (layers 2,3,4): 320m x BOo tiles, single-bf16 weights ----------------
// LESSONS: (r5/r6) runtime acc index -> scratch demotion: keep acc indexing static.
// (r7) cross-lane LDS round-trip needs __syncthreads() between write/read phases.
template<int CIN, int COUT, int BO, bool WRITEY>
__launch_bounds__(256, 2)
__global__ void conv_fused_k(const ushort_t* __restrict__ yin,
                             const ushort_t* __restrict__ whi,
                             const float* __restrict__ scale,
                             const float* __restrict__ shift,
                             ushort_t* __restrict__ yout,
                             float* __restrict__ rawmax, float* __restrict__ rawmin,
                             float* __restrict__ sp) {
    constexpr int NOT = BO / 16;
    __shared__ ushort_t hA[320 * 56];           // 35840 B; wreg overlays this
    __shared__ ushort_t wHs[BO * 56];
    __shared__ float scl[CIN], shf[CIN];
    __shared__ float sw[4 * BO * 2];
    const int tid = threadIdx.x;
    const int m0 = blockIdx.y * 320;            // 1024 m-tiles
    const int o0 = blockIdx.x * BO;
    for (int c = tid; c < CIN; c += 256) { scl[c] = scale[c]; shf[c] = shift[c]; }
    for (int i = tid; i < 4 * BO * 2; i += 256) sw[i] = 0.0f;
    f32x4 acc[5][NOT];
#pragma unroll
    for (int mt = 0; mt < 5; mt++)
#pragma unroll
        for (int ot = 0; ot < NOT; ot++) acc[mt][ot] = (f32x4){0.f, 0.f, 0.f, 0.f};
    const int lane = tid & 63, wv = tid >> 6;
    const int l15 = lane & 15, quad = lane >> 4;
    for (int kc = 0; kc < CIN; kc += 32) {
        __syncthreads();
#pragma unroll
        for (int i = 0; i < 5; i++) {
            int tt = tid + 256 * i;
            int mr = tt >> 2, cq = (tt & 3) * 8;
            uint4 u = *(const uint4*)(yin + (size_t)(m0 + mr) * CIN + kc + cq);
            float vv[8]; unpack8(u, vv);
#pragma unroll
            for (int e = 0; e < 8; e++)
                vv[e] = fmaxf(fmaf(vv[e], scl[kc + cq + e], shf[kc + cq + e]), 0.0f);
            u.x = pack2(vv[0], vv[1]); u.y = pack2(vv[2], vv[3]);
            u.z = pack2(vv[4], vv[5]); u.w = pack2(vv[6], vv[7]);
            *(uint4*)&hA[mr * 56 + cq] = u;
        }
        for (int t = tid; t < BO * 4; t += 256) {
            int row = t >> 2, cq = (t & 3) * 8;
            *(uint4*)&wHs[row * 56 + cq] = *(const uint4*)(whi + (size_t)(o0 + row) * CIN + kc + cq);
        }
        __syncthreads();
        bf16x8 a[5];
#pragma unroll
        for (int mt = 0; mt < 5; mt++)
            a[mt] = *(bf16x8*)&hA[(wv * 80 + mt * 16 + l15) * 56 + quad * 8];
#pragma unroll
        for (int ot = 0; ot < NOT; ot++) {
            bf16x8 bh = *(bf16x8*)&wHs[(ot * 16 + l15) * 56 + quad * 8];
#pragma unroll
            for (int mt = 0; mt < 5; mt++)
                acc[mt][ot] = __builtin_amdgcn_mfma_f32_16x16x32_bf16(a[mt], bh, acc[mt][ot], 0, 0, 0);
        }
    }
    __syncthreads();   // waves may still read hA/wHs; wreg overlays hA
    float* wreg = (float*)((char*)hA + wv * 6400);   // [80][20]
#pragma unroll
    for (int ot = 0; ot < NOT; ot++) {
#pragma unroll
        for (int mt = 0; mt < 5; mt++)
#pragma unroll
            for (int r = 0; r < 4; r++)
                wreg[(mt * 16 + quad * 4 + r) * 20 + l15] = acc[mt][ot][r];
        __syncthreads();   // cross-lane round-trip (r7 lesson)
        {
            int pp = quad;
            const float* rr = wreg + (pp * 20) * 20 + l15;
            float mx = rr[0], mn = rr[0], sm = 0.0f, ss = 0.0f;
#pragma unroll
            for (int q = 0; q < 20; q++) {
                float vv = rr[q * 20];
                mx = fmaxf(mx, vv); mn = fminf(mn, vv);
                sm += vv; ss = fmaf(vv, vv, ss);
            }
            int pt = blockIdx.y * 16 + wv * 4 + pp;
            int o = o0 + ot * 16 + l15;
            rawmax[(size_t)pt * COUT + o] = mx;
            rawmin[(size_t)pt * COUT + o] = mn;
            sm += __shfl_xor(sm, 16); sm += __shfl_xor(sm, 32);
            ss += __shfl_xor(ss, 16); ss += __shfl_xor(ss, 32);
            if (lane < 16) {
                sw[(wv * BO + ot * 16 + l15) * 2 + 0] += sm;
                sw[(wv * BO + ot * 16 + l15) * 2 + 1] += ss;
            }
        }
        if constexpr (WRITEY) {
#pragma unroll
            for (int it = 0; it < 3; it++) {
                int t = lane + it * 64;
                if (t < 160) {
                    int row = t >> 1, half = t & 1;
                    float4 f0 = *(float4*)&wreg[row * 20 + half * 8];
                    float4 f1 = *(float4*)&wreg[row * 20 + half * 8 + 4];
                    uint4 u;
                    u.x = pack2(f0.x, f0.y); u.y = pack2(f0.z, f0.w);
                    u.z = pack2(f1.x, f1.y); u.w = pack2(f1.z, f1.w);
                    *(uint4*)(yout + (size_t)(m0 + wv * 80 + row) * COUT + o0 + ot * 16 + half * 8) = u;
                }
            }
        }
        __syncthreads();
    }
    for (int t2 = tid; t2 < BO * 2; t2 += 256) {
        int ol = t2 >> 1, st = t2 & 1;
        float v = 0.0f;
#pragma unroll
        for (int w2 = 0; w2 < 4; w2++) v += sw[(w2 * BO + ol) * 2 + st];
        size_t bid = (size_t)blockIdx.x * 1024 + blockIdx.y;   // o-major
        sp[bid * (2 * BO) + ol * 2 + st] = v;
    }
}

// ---------------- reduce stats partials + finalize BN (all layers) ----------------
template<int BO, int MB>
__launch_bounds__(256)
__global__ void statsred_fin_k(const float* __restrict__ sp,
                               const float* __restrict__ g, const float* __restrict__ bb,
                               float* __restrict__ scale, float* __restrict__ shift,
                               double invcnt) {
    __shared__ double rs[256], rss[256];
    int o = blockIdx.x, tid = threadIdx.x;
    int oy = o / BO, ol = o % BO;
    double s = 0.0, ss = 0.0;
    for (int mb = tid; mb < MB; mb += 256) {
        size_t bid = (size_t)oy * MB + mb;
        s  += (double)sp[bid * (2 * BO) + ol * 2 + 0];
        ss += (double)sp[bid * (2 * BO) + ol * 2 + 1];
    }
    rs[tid] = s; rss[tid] = ss;
    __syncthreads();
    for (int st = 128; st; st >>= 1) {
        if (tid < st) { rs[tid] += rs[tid + st]; rss[tid] += rss[tid + st]; }
        __syncthreads();
    }
    if (tid == 0) {
        double m = rs[0] * invcnt;
        double v = rss[0] * invcnt - m * m;
        if (v < 0.0) v = 0.0;
        float sc = g[o] / sqrtf((float)v + 1e-5f);
        scale[o] = sc;
        shift[o] = bb[o] - (float)m * sc;
    }
}

// ---------------- pool finalize from raw max/min (BN monotone) -> xcat ----------------
template<int C8>
__launch_bounds__(256)
__global__ void pool_raw_k(const float* __restrict__ rawmax, const float* __restrict__ rawmin,
                           const float* __restrict__ scale, const float* __restrict__ shift,
                           ushort_t* __restrict__ xcat, int coff) {
    constexpr int COUT = C8 * 8;
    int gid = blockIdx.x * 256 + threadIdx.x;   // 16384 * C8
    int p = gid / C8, og = gid % C8;
    float sc[8], sh[8], mxv[8], mnv[8];
    *(float4*)&sc[0]  = *(const float4*)(scale + og * 8);
    *(float4*)&sc[4]  = *(const float4*)(scale + og * 8 + 4);
    *(float4*)&sh[0]  = *(const float4*)(shift + og * 8);
    *(float4*)&sh[4]  = *(const float4*)(shift + og * 8 + 4);
    *(float4*)&mxv[0] = *(const float4*)(rawmax + (size_t)p * COUT + og * 8);
    *(float4*)&mxv[4] = *(const float4*)(rawmax + (size_t)p * COUT + og * 8 + 4);
    *(float4*)&mnv[0] = *(const float4*)(rawmin + (size_t)p * COUT + og * 8);
    *(float4*)&mnv[4] = *(const float4*)(rawmin + (size_t)p * COUT + og * 8 + 4);
    float v[8];
#pragma unroll
    for (int e = 0; e < 8; e++) {
        float raw = (sc[e] >= 0.0f) ? mxv[e] : mnv[e];
        v[e] = fmaxf(fmaf(raw, sc[e], sh[e]), 0.0f);
    }
    uint4 u;
    u.x = pack2(v[0], v[1]); u.y = pack2(v[2], v[3]);
    u.z = pack2(v[4], v[5]); u.w = pack2(v[6], v[7]);
    *(uint4*)(xcat + (size_t)p * 512 + coff + og * 8) = u;
}

// ---------------- output: BN5+ReLU + transpose NHWC -> [b][c][n] fp32 ----------------
__launch_bounds__(256)
__global__ void out_k(const ushort_t* __restrict__ y5, const float* __restrict__ scale,
                      const float* __restrict__ shift, float* __restrict__ out) {
    __shared__ float tr[64 * 65];
    int tid = threadIdx.x;
    int n0 = blockIdx.x * 64, c0 = blockIdx.y * 64, b = blockIdx.z;
    int nl = tid >> 2, cq = (tid & 3) * 16;
    const ushort_t* src = y5 + (size_t)(b * 2048 + n0 + nl) * 512 + c0 + cq;
#pragma unroll
    for (int h = 0; h < 2; h++) {
        uint4 u = *(const uint4*)(src + h * 8);
        float vv[8]; unpack8(u, vv);
#pragma unroll
        for (int e = 0; e < 8; e++) {
            int c = cq + h * 8 + e;
            tr[c * 65 + nl] = fmaxf(fmaf(vv[e], scale[c0 + c], shift[c0 + c]), 0.0f);
        }
    }
    __syncthreads();
    int cl = tid >> 2, ng = (tid & 3) * 16;
#pragma unroll
    for (int g = 0; g < 4; g++) {
        float4 v = *(float4*)&tr[cl * 65 + ng + g * 4];
        *(float4*)(out + ((size_t)b * 512 + c0 + cl) * 2048 + n0 + ng + g * 4) = v;
    }
}

// ---------------- host ----------------
extern "C" void kernel_launch(void* const* d_in, const int* in_sizes, int n_in,
                              void* d_out, int out_size, void* d_ws, size_t ws_size,
                              hipStream_t stream) {
    (void)in_sizes; (void)n_in; (void)out_size;
    if (ws_size < WS_NEEDED) return;
    const float* x  = (const float*)d_in[0];
    const float* w1 = (const float*)d_in[1];
    const float* g1 = (const float*)d_in[2];
    const float* b1 = (const float*)d_in[3];
    const float* w2 = (const float*)d_in[4];
    const float* g2 = (const float*)d_in[5];
    const float* b2 = (const float*)d_in[6];
    const float* w3 = (const float*)d_in[7];
    const float* g3 = (const float*)d_in[8];
    const float* b3 = (const float*)d_in[9];
    const float* w4 = (const float*)d_in[10];
    const float* g4 = (const float*)d_in[11];
    const float* b4 = (const float*)d_in[12];
    const float* w5 = (const float*)d_in[13];
    const float* g5 = (const float*)d_in[14];
    const float* b5 = (const float*)d_in[15];

    char* ws = (char*)d_ws;
    float* xt  = (float*)(ws + OFF_XT);
    float* xx  = (float*)(ws + OFF_XX);
    int*   idx = (int*)(ws + OFF_IDX);
    ushort_t* wh2 = (ushort_t*)(ws + OFF_WH2);
    ushort_t* wh3 = (ushort_t*)(ws + OFF_WH3);
    ushort_t* wh4 = (ushort_t*)(ws + OFF_WH4);
    ushort_t* wh5 = (ushort_t*)(ws + OFF_WH5);
    ushort_t* y1 = (ushort_t*)(ws + OFF_REG0);
    ushort_t* y2 = (ushort_t*)(ws + OFF_REG1);
    ushort_t* y3 = (ushort_t*)(ws + OFF_REG0);
    ushort_t* y5 = (ushort_t*)(ws + OFF_REG0);
    ushort_t* xcat = (ushort_t*)(ws + OFF_XCAT);
    float* rawmax = (float*)(ws + OFF_RAWMAX);
    float* rawmin = (float*)(ws + OFF_RAWMIN);
    float* sp     = (float*)(ws + OFF_SP);

    float* scl[5]; float* shf[5];
    for (int l = 0; l < 5; l++) {
        scl[l] = (float*)(ws + OFF_SS + (size_t)l * 4096);
        shf[l] = scl[l] + 512;
    }

    prep_k<<<64, 256, 0, stream>>>(x, xt, xx);
    wsplit_all_k<<<1200, 256, 0, stream>>>(w2, wh2, w3, wh3, w4, wh4, w5, wh5);
    knn_k<<<2048, 256, 0, stream>>>(xt, xx, idx);

    // layer 1: fused graph-feature + conv + raw pool + stats (BO=64)
    conv1_fused_k<<<1024, 256, 0, stream>>>(xt, idx, w1, y1, rawmax, rawmin, sp);
    statsred_fin_k<64, 1024><<<64, 256, 0, stream>>>(sp, g1, b1, scl[0], shf[0], 1.0 / 327680.0);
    pool_raw_k<8><<<512, 256, 0, stream>>>(rawmax, rawmin, scl[0], shf[0], xcat, 0);

    // layer 2: 64 -> 64 fused (BO=64)
    conv_fused_k<64, 64, 64, true><<<dim3(1, 1024), 256, 0, stream>>>(
        y1, wh2, scl[0], shf[0], y2, rawmax, rawmin, sp);
    statsred_fin_k<64, 1024><<<64, 256, 0, stream>>>(sp, g2, b2, scl[1], shf[1], 1.0 / 327680.0);
    pool_raw_k<8><<<512, 256, 0, stream>>>(rawmax, rawmin, scl[1], shf[1], xcat, 64);

    // layer 3: 64 -> 128 fused (BO=128)
    conv_fused_k<64, 128, 128, true><<<dim3(1, 1024), 256, 0, stream>>>(
        y2, wh3, scl[1], shf[1], y3, rawmax, rawmin, sp);
    statsred_fin_k<128, 1024><<<128, 256, 0, stream>>>(sp, g3, b3, scl[2], shf[2], 1.0 / 327680.0);
    pool_raw_k<16><<<1024, 256, 0, stream>>>(rawmax, rawmin, scl[2], shf[2], xcat, 128);

    // layer 4: 128 -> 256 fused (BO=128, 2 o-tiles)
    conv_fused_k<128, 256, 128, false><<<dim3(2, 1024), 256, 0, stream>>>(
        y3, wh4, scl[2], shf[2], nullptr, rawmax, rawmin, sp);
    statsred_fin_k<128, 1024><<<256, 256, 0, stream>>>(sp, g4, b4, scl[3], shf[3], 1.0 / 327680.0);
    pool_raw_k<32><<<2048, 256, 0, stream>>>(rawmax, rawmin, scl[3], shf[3], xcat, 256);

    // layer 5: 512 -> 512, single-bf16 weights, stats fused
    conv5_mfma_k<512, 512><<<dim3(8, 128), 256, 0, stream>>>(xcat, wh5, y5, sp);
    statsred_fin_k<64, 128><<<512, 256, 0, stream>>>(sp, g5, b5, scl[4], shf[4], 1.0 / 16384.0);
    out_k<<<dim3(32, 8, 8), 256, 0, stream>>>(y5, scl[4], shf[4], (float*)d_out);
}